// Round 2
// baseline (458.110 us; speedup 1.0000x reference)
//
#include <hip/hip_runtime.h>
#include <hip/hip_bf16.h>

typedef __bf16 bf16x8 __attribute__((ext_vector_type(8)));
typedef __bf16 bf16x4 __attribute__((ext_vector_type(4)));
typedef float  f32x4  __attribute__((ext_vector_type(4)));

#define MFMA16(a, b, c) __builtin_amdgcn_mfma_f32_16x16x32_bf16((a), (b), (c), 0, 0, 0)

__device__ __forceinline__ void gload16(const void* g, void* l) {
  __builtin_amdgcn_global_load_lds(
      (const __attribute__((address_space(1))) unsigned int*)g,
      (__attribute__((address_space(3))) unsigned int*)l, 16, 0, 0);
}

// ---------------------------------------------------------------- f32 -> bf16 pack
__global__ __launch_bounds__(256) void cvt_kernel(
    const float* __restrict__ in, __bf16* __restrict__ out, long n) {
  const long i = ((long)blockIdx.x * 256 + threadIdx.x) * 8;
  if (i + 7 < n) {
    float4 a = *(const float4*)&in[i];
    float4 b = *(const float4*)&in[i + 4];
    bf16x8 o;
    o[0] = (__bf16)a.x; o[1] = (__bf16)a.y; o[2] = (__bf16)a.z; o[3] = (__bf16)a.w;
    o[4] = (__bf16)b.x; o[5] = (__bf16)b.y; o[6] = (__bf16)b.z; o[7] = (__bf16)b.w;
    *(bf16x8*)&out[i] = o;
  }
}

// ---------------------------------------------------------------- LayerNorm (f32 in -> bf16 out)
__global__ __launch_bounds__(256) void ln_kernel(
    const float* __restrict__ in, const float* __restrict__ gg,
    const float* __restrict__ bb, __bf16* __restrict__ out) {
  __shared__ float sred[8];
  const long row = blockIdx.x;
  const int tid = threadIdx.x;
  float4 u = *(const float4*)&in[row * 1024 + tid * 4];
  float f[4] = {u.x, u.y, u.z, u.w};
  float s = 0.f, sq = 0.f;
#pragma unroll
  for (int j = 0; j < 4; ++j) { s += f[j]; sq += f[j] * f[j]; }
#pragma unroll
  for (int d = 32; d; d >>= 1) { s += __shfl_xor(s, d); sq += __shfl_xor(sq, d); }
  const int w = tid >> 6;
  if ((tid & 63) == 0) { sred[w * 2] = s; sred[w * 2 + 1] = sq; }
  __syncthreads();
  s  = sred[0] + sred[2] + sred[4] + sred[6];
  sq = sred[1] + sred[3] + sred[5] + sred[7];
  const float mean = s * (1.f / 1024.f);
  const float var  = sq * (1.f / 1024.f) - mean * mean;
  const float rstd = rsqrtf(var + 1e-5f);
  float4 gv = *(const float4*)&gg[tid * 4];
  float4 bv = *(const float4*)&bb[tid * 4];
  bf16x4 ov;
  ov[0] = (__bf16)((f[0] - mean) * rstd * gv.x + bv.x);
  ov[1] = (__bf16)((f[1] - mean) * rstd * gv.y + bv.y);
  ov[2] = (__bf16)((f[2] - mean) * rstd * gv.z + bv.z);
  ov[3] = (__bf16)((f[3] - mean) * rstd * gv.w + bv.w);
  *(bf16x4*)&out[row * 1024 + tid * 4] = ov;
}

// ---------------------------------------------------------------- RoPE (in place on bf16 q,k; f32 freqs)
__global__ __launch_bounds__(256) void rope_kernel(
    __bf16* __restrict__ qb, __bf16* __restrict__ kb, const float* __restrict__ freqs) {
  const long idx = (long)blockIdx.x * 256 + threadIdx.x;  // pair index
  __bf16* p = blockIdx.y ? kb : qb;
  const int token = (int)(idx >> 9);
  const int wi = (int)(idx & 511);
  const int head = wi >> 5, i = wi & 31;
  const int spos = token & 2047;
  const float f = freqs[spos * 32 + i];
  float sn, cs;
  sincosf(f, &sn, &cs);
  const long off = (long)token * 1024 + head * 64 + 2 * i;
  const float x0 = (float)p[off], x1 = (float)p[off + 1];
  p[off]     = (__bf16)(x0 * cs - x1 * sn);
  p[off + 1] = (__bf16)(x1 * cs + x0 * sn);
}

// ---------------------------------------------------------------- GEMM: out = act @ W^T + bias (+epilogue)
// act [M][K] bf16 row-major, W [N][K] bf16 row-major. 128x128 tile, BK=64, 4 waves.
enum { EPI_NONE = 0, EPI_GELU = 1, EPI_RES = 2 };

template <int EPI, typename OT>
__global__ __launch_bounds__(256) void gemm_bt(
    const __bf16* __restrict__ A, const __bf16* __restrict__ W,
    const float* __restrict__ bias, const float* __restrict__ res,
    OT* __restrict__ out, int M, int N, int K) {
  __shared__ __bf16 lsA[128 * 64];
  __shared__ __bf16 lsB[128 * 64];
  const int tid = threadIdx.x, lane = tid & 63, w = tid >> 6;
  const int bm = blockIdx.y, bn = blockIdx.x;
  const int wm = w >> 1, wn = w & 1;
  const long Kl = K, Nl = N;
  const long a_row0 = (long)bm * 128, b_row0 = (long)bn * 128;
  const int pr_row = lane >> 3;
  const int pr_col = (lane & 7) * 8;

  f32x4 acc[4][4];
  const f32x4 fz = {0.f, 0.f, 0.f, 0.f};
#pragma unroll
  for (int i = 0; i < 4; ++i)
#pragma unroll
    for (int j = 0; j < 4; ++j) acc[i][j] = fz;

  for (int kt = 0; kt < K; kt += 64) {
#pragma unroll
    for (int p = 0; p < 4; ++p) {
      const int seg = p * 4 + w;
      const int row = seg * 8 + pr_row;
      gload16(A + (a_row0 + row) * Kl + kt + pr_col, (char*)lsA + seg * 1024);
      gload16(W + (b_row0 + row) * Kl + kt + pr_col, (char*)lsB + seg * 1024);
    }
    __syncthreads();
#pragma unroll
    for (int kk = 0; kk < 2; ++kk) {
      bf16x8 af[4], bfr[4];
#pragma unroll
      for (int i = 0; i < 4; ++i) {
        af[i]  = *(const bf16x8*)&lsA[(wm * 64 + i * 16 + (lane & 15)) * 64 + kk * 32 + 8 * (lane >> 4)];
        bfr[i] = *(const bf16x8*)&lsB[(wn * 64 + i * 16 + (lane & 15)) * 64 + kk * 32 + 8 * (lane >> 4)];
      }
#pragma unroll
      for (int mi = 0; mi < 4; ++mi)
#pragma unroll
        for (int ni = 0; ni < 4; ++ni)
          acc[mi][ni] = MFMA16(af[mi], bfr[ni], acc[mi][ni]);
    }
    __syncthreads();
  }

#pragma unroll
  for (int mi = 0; mi < 4; ++mi) {
#pragma unroll
    for (int ni = 0; ni < 4; ++ni) {
      const int col = bn * 128 + wn * 64 + ni * 16 + (lane & 15);
      const float bb = bias[col];
#pragma unroll
      for (int r = 0; r < 4; ++r) {
        const long row = a_row0 + wm * 64 + mi * 16 + (lane >> 4) * 4 + r;
        float vv = acc[mi][ni][r] + bb;
        if constexpr (EPI == EPI_GELU) vv = 0.5f * vv * (1.0f + erff(vv * 0.70710678f));
        if constexpr (EPI == EPI_RES) vv += res[row * Nl + col];
        out[row * Nl + col] = (OT)vv;
      }
    }
  }
}

// ---------------------------------------------------------------- Flash attention (causal)
// grid (S/128, H, B), 256 threads = 4 waves, each wave owns 32 q rows.
__global__ __launch_bounds__(256) void attn_kernel(
    const __bf16* __restrict__ q, const __bf16* __restrict__ kmat,
    const __bf16* __restrict__ v, __bf16* __restrict__ o) {
  __shared__ __bf16 lsK[64 * 64];
  __shared__ __bf16 lsV[64 * 64];      // transposed: lsV[d][key]
  __shared__ __bf16 lsP[4][32 * 64];
  const int tid = threadIdx.x, lane = tid & 63, w = tid >> 6;
  const int b = blockIdx.z, h = blockIdx.y, q0 = blockIdx.x * 128;
  const int qw = q0 + w * 32;
  const long base = (long)b * 2048 * 1024 + h * 64;

  // Q fragments in registers
  bf16x8 aq[2][2];
#pragma unroll
  for (int mi = 0; mi < 2; ++mi)
#pragma unroll
    for (int kk = 0; kk < 2; ++kk) {
      const int row = qw + mi * 16 + (lane & 15);
      const int d = kk * 32 + 8 * (lane >> 4);
      aq[mi][kk] = *(const bf16x8*)&q[base + (long)row * 1024 + d];
    }

  const f32x4 fz = {0.f, 0.f, 0.f, 0.f};
  f32x4 oacc[2][4];
  float mrun[2][4], lrun[2][4];
#pragma unroll
  for (int mi = 0; mi < 2; ++mi) {
#pragma unroll
    for (int ni = 0; ni < 4; ++ni) oacc[mi][ni] = fz;
#pragma unroll
    for (int r = 0; r < 4; ++r) { mrun[mi][r] = -1e30f; lrun[mi][r] = 0.f; }
  }

  const int nkt = (q0 >> 6) + 2;
  for (int kt = 0; kt < nkt; ++kt) {
    // stage K tile [64 keys][64 d]
#pragma unroll
    for (int p = 0; p < 2; ++p) {
      const int seg = p * 4 + w;
      const int row = seg * 8 + (lane >> 3);
      gload16(kmat + base + (long)(kt * 64 + row) * 1024 + (lane & 7) * 8,
              (char*)lsK + seg * 1024);
    }
    // stage V transposed
    {
      const int key = tid >> 2, db = (tid & 3) * 16;
      const long gv = base + (long)(kt * 64 + key) * 1024 + db;
      bf16x8 v0 = *(const bf16x8*)&v[gv];
      bf16x8 v1 = *(const bf16x8*)&v[gv + 8];
#pragma unroll
      for (int j = 0; j < 8; ++j) {
        lsV[(db + j) * 64 + key] = v0[j];
        lsV[(db + 8 + j) * 64 + key] = v1[j];
      }
    }
    __syncthreads();

    // S = Q K^T
    f32x4 sacc[2][4];
#pragma unroll
    for (int mi = 0; mi < 2; ++mi)
#pragma unroll
      for (int ni = 0; ni < 4; ++ni) sacc[mi][ni] = fz;
#pragma unroll
    for (int kk = 0; kk < 2; ++kk) {
      bf16x8 bk[4];
#pragma unroll
      for (int ni = 0; ni < 4; ++ni)
        bk[ni] = *(const bf16x8*)&lsK[(ni * 16 + (lane & 15)) * 64 + kk * 32 + 8 * (lane >> 4)];
#pragma unroll
      for (int mi = 0; mi < 2; ++mi)
#pragma unroll
        for (int ni = 0; ni < 4; ++ni)
          sacc[mi][ni] = MFMA16(aq[mi][kk], bk[ni], sacc[mi][ni]);
    }

    // online softmax (wave-parallel, 16-lane row groups)
#pragma unroll
    for (int mi = 0; mi < 2; ++mi) {
#pragma unroll
      for (int r = 0; r < 4; ++r) {
        const int row_g = qw + mi * 16 + (lane >> 4) * 4 + r;
        float sv[4];
        float mx = -3.0e38f;
#pragma unroll
        for (int ni = 0; ni < 4; ++ni) {
          const int key_g = kt * 64 + ni * 16 + (lane & 15);
          float s = sacc[mi][ni][r] * 0.125f;
          if (key_g > row_g) s = -1e9f;
          sv[ni] = s;
          mx = fmaxf(mx, s);
        }
#pragma unroll
        for (int d = 1; d < 16; d <<= 1) mx = fmaxf(mx, __shfl_xor(mx, d));
        const float mold = mrun[mi][r];
        const float mnew = fmaxf(mold, mx);
        const float fac = __expf(mold - mnew);
        float sum = 0.f;
#pragma unroll
        for (int ni = 0; ni < 4; ++ni) {
          const float pp = __expf(sv[ni] - mnew);
          sum += pp;
          lsP[w][(mi * 16 + (lane >> 4) * 4 + r) * 64 + ni * 16 + (lane & 15)] = (__bf16)pp;
        }
#pragma unroll
        for (int d = 1; d < 16; d <<= 1) sum += __shfl_xor(sum, d);
        mrun[mi][r] = mnew;
        lrun[mi][r] = lrun[mi][r] * fac + sum;
#pragma unroll
        for (int ni = 0; ni < 4; ++ni) oacc[mi][ni][r] *= fac;
      }
    }
    __syncthreads();

    // O += P V
#pragma unroll
    for (int kk = 0; kk < 2; ++kk) {
      bf16x8 ap[2], bv[4];
#pragma unroll
      for (int mi = 0; mi < 2; ++mi)
        ap[mi] = *(const bf16x8*)&lsP[w][(mi * 16 + (lane & 15)) * 64 + kk * 32 + 8 * (lane >> 4)];
#pragma unroll
      for (int ni = 0; ni < 4; ++ni)
        bv[ni] = *(const bf16x8*)&lsV[(ni * 16 + (lane & 15)) * 64 + kk * 32 + 8 * (lane >> 4)];
#pragma unroll
      for (int mi = 0; mi < 2; ++mi)
#pragma unroll
        for (int ni = 0; ni < 4; ++ni)
          oacc[mi][ni] = MFMA16(ap[mi], bv[ni], oacc[mi][ni]);
    }
    __syncthreads();
  }

  // epilogue
#pragma unroll
  for (int mi = 0; mi < 2; ++mi)
#pragma unroll
    for (int ni = 0; ni < 4; ++ni)
#pragma unroll
      for (int r = 0; r < 4; ++r) {
        const int row_g = qw + mi * 16 + (lane >> 4) * 4 + r;
        o[base + (long)row_g * 1024 + ni * 16 + (lane & 15)] =
            (__bf16)(oacc[mi][ni][r] / lrun[mi][r]);
      }
}

// ---------------------------------------------------------------- launcher
extern "C" void kernel_launch(void* const* d_in, const int* in_sizes, int n_in,
                              void* d_out, int out_size, void* d_ws, size_t ws_size,
                              hipStream_t stream) {
  const float* x    = (const float*)d_in[0];
  const float* fr   = (const float*)d_in[1];
  const float* ln1g = (const float*)d_in[3];
  const float* ln1b = (const float*)d_in[4];
  const float* Wq   = (const float*)d_in[5];
  const float* bq   = (const float*)d_in[6];
  const float* Wk   = (const float*)d_in[7];
  const float* bk   = (const float*)d_in[8];
  const float* Wv   = (const float*)d_in[9];
  const float* bv   = (const float*)d_in[10];
  const float* Wo   = (const float*)d_in[11];
  const float* bo   = (const float*)d_in[12];
  const float* ln2g = (const float*)d_in[13];
  const float* ln2b = (const float*)d_in[14];
  const float* W1   = (const float*)d_in[15];
  const float* b1   = (const float*)d_in[16];
  const float* W2   = (const float*)d_in[17];
  const float* b2   = (const float*)d_in[18];
  float* out = (float*)d_out;

  char* ws = (char*)d_ws;
  const size_t SZ = 8388608;  // 8 MB
  __bf16* xn   = (__bf16*)(ws + 0);
  __bf16* qb   = (__bf16*)(ws + 1 * SZ);
  __bf16* kb   = (__bf16*)(ws + 2 * SZ);
  __bf16* vb   = (__bf16*)(ws + 3 * SZ);
  __bf16* attn = (__bf16*)(ws + 0);              // reuse xn
  float*  x2   = (float*)(ws + 4 * SZ);          // 16 MB (f32)
  __bf16* hin  = (__bf16*)(ws + 6 * SZ);
  __bf16* hmid = (__bf16*)(ws + 0);              // 32 MB, reuses 0..4*SZ
  char* wb = ws + 7 * SZ;                        // bf16 weights, 24 MB
  __bf16* Wqb = (__bf16*)(wb + 0);
  __bf16* Wkb = (__bf16*)(wb + 2097152);
  __bf16* Wvb = (__bf16*)(wb + 2 * 2097152);
  __bf16* Wob = (__bf16*)(wb + 3 * 2097152);
  __bf16* W1b = (__bf16*)(wb + 4 * 2097152);
  __bf16* W2b = (__bf16*)(wb + 8 * 2097152);

  const int M = 4096, D = 1024, FF = 4096;
  dim3 blk(256);

  // weight conversion f32 -> bf16
  cvt_kernel<<<512,  blk, 0, stream>>>(Wq, Wqb, (long)D * D);
  cvt_kernel<<<512,  blk, 0, stream>>>(Wk, Wkb, (long)D * D);
  cvt_kernel<<<512,  blk, 0, stream>>>(Wv, Wvb, (long)D * D);
  cvt_kernel<<<512,  blk, 0, stream>>>(Wo, Wob, (long)D * D);
  cvt_kernel<<<2048, blk, 0, stream>>>(W1, W1b, (long)FF * D);
  cvt_kernel<<<2048, blk, 0, stream>>>(W2, W2b, (long)D * FF);

  ln_kernel<<<4096, blk, 0, stream>>>(x, ln1g, ln1b, xn);
  {
    dim3 g(D / 128, M / 128);
    gemm_bt<EPI_NONE, __bf16><<<g, blk, 0, stream>>>(xn, Wqb, bq, nullptr, qb, M, D, D);
    gemm_bt<EPI_NONE, __bf16><<<g, blk, 0, stream>>>(xn, Wkb, bk, nullptr, kb, M, D, D);
    gemm_bt<EPI_NONE, __bf16><<<g, blk, 0, stream>>>(xn, Wvb, bv, nullptr, vb, M, D, D);
  }
  rope_kernel<<<dim3(8192, 2), blk, 0, stream>>>(qb, kb, fr);
  attn_kernel<<<dim3(16, 16, 2), blk, 0, stream>>>(qb, kb, vb, attn);
  gemm_bt<EPI_RES, float><<<dim3(D / 128, M / 128), blk, 0, stream>>>(attn, Wob, bo, x, x2, M, D, D);
  ln_kernel<<<4096, blk, 0, stream>>>(x2, ln2g, ln2b, hin);
  gemm_bt<EPI_GELU, __bf16><<<dim3(FF / 128, M / 128), blk, 0, stream>>>(hin, W1b, b1, nullptr, hmid, M, FF, D);
  gemm_bt<EPI_RES, float><<<dim3(D / 128, M / 128), blk, 0, stream>>>(hmid, W2b, b2, x2, out, M, D, FF);
}

// Round 3
// 406.534 us; speedup vs baseline: 1.1269x; 1.1269x over previous
//
#include <hip/hip_runtime.h>
#include <hip/hip_bf16.h>

typedef __bf16 bf16x8 __attribute__((ext_vector_type(8)));
typedef __bf16 bf16x4 __attribute__((ext_vector_type(4)));
typedef float  f32x4  __attribute__((ext_vector_type(4)));

#define MFMA16(a, b, c) __builtin_amdgcn_mfma_f32_16x16x32_bf16((a), (b), (c), 0, 0, 0)

__device__ __forceinline__ void gload16(const void* g, void* l) {
  __builtin_amdgcn_global_load_lds(
      (const __attribute__((address_space(1))) unsigned int*)g,
      (__attribute__((address_space(3))) unsigned int*)l, 16, 0, 0);
}

// ---------------------------------------------------------------- f32 -> bf16 pack
__global__ __launch_bounds__(256) void cvt_kernel(
    const float* __restrict__ in, __bf16* __restrict__ out, long n) {
  const long i = ((long)blockIdx.x * 256 + threadIdx.x) * 8;
  if (i + 7 < n) {
    float4 a = *(const float4*)&in[i];
    float4 b = *(const float4*)&in[i + 4];
    bf16x8 o;
    o[0] = (__bf16)a.x; o[1] = (__bf16)a.y; o[2] = (__bf16)a.z; o[3] = (__bf16)a.w;
    o[4] = (__bf16)b.x; o[5] = (__bf16)b.y; o[6] = (__bf16)b.z; o[7] = (__bf16)b.w;
    *(bf16x8*)&out[i] = o;
  }
}

// pack 3 bias vectors (1024 each) into one f32[3072]
__global__ __launch_bounds__(256) void pack3_kernel(
    const float* __restrict__ a, const float* __restrict__ b,
    const float* __restrict__ c, float* __restrict__ o) {
  const int i = blockIdx.x * 256 + threadIdx.x;
  o[i] = i < 1024 ? a[i] : (i < 2048 ? b[i - 1024] : c[i - 2048]);
}

// ---------------------------------------------------------------- LayerNorm (f32 in -> bf16 out)
__global__ __launch_bounds__(256) void ln_kernel(
    const float* __restrict__ in, const float* __restrict__ gg,
    const float* __restrict__ bb, __bf16* __restrict__ out) {
  __shared__ float sred[8];
  const long row = blockIdx.x;
  const int tid = threadIdx.x;
  float4 u = *(const float4*)&in[row * 1024 + tid * 4];
  float f[4] = {u.x, u.y, u.z, u.w};
  float s = 0.f, sq = 0.f;
#pragma unroll
  for (int j = 0; j < 4; ++j) { s += f[j]; sq += f[j] * f[j]; }
#pragma unroll
  for (int d = 32; d; d >>= 1) { s += __shfl_xor(s, d); sq += __shfl_xor(sq, d); }
  const int w = tid >> 6;
  if ((tid & 63) == 0) { sred[w * 2] = s; sred[w * 2 + 1] = sq; }
  __syncthreads();
  s  = sred[0] + sred[2] + sred[4] + sred[6];
  sq = sred[1] + sred[3] + sred[5] + sred[7];
  const float mean = s * (1.f / 1024.f);
  const float var  = sq * (1.f / 1024.f) - mean * mean;
  const float rstd = rsqrtf(var + 1e-5f);
  float4 gv = *(const float4*)&gg[tid * 4];
  float4 bv = *(const float4*)&bb[tid * 4];
  bf16x4 ov;
  ov[0] = (__bf16)((f[0] - mean) * rstd * gv.x + bv.x);
  ov[1] = (__bf16)((f[1] - mean) * rstd * gv.y + bv.y);
  ov[2] = (__bf16)((f[2] - mean) * rstd * gv.z + bv.z);
  ov[3] = (__bf16)((f[3] - mean) * rstd * gv.w + bv.w);
  *(bf16x4*)&out[row * 1024 + tid * 4] = ov;
}

// ---------------------------------------------------------------- RoPE (in place on packed qkv, LD=3072)
__global__ __launch_bounds__(256) void rope_kernel(
    __bf16* __restrict__ qkv, const float* __restrict__ freqs) {
  const long idx = (long)blockIdx.x * 256 + threadIdx.x;  // pair index
  __bf16* p = qkv + (blockIdx.y ? 1024 : 0);
  const int token = (int)(idx >> 9);
  const int wi = (int)(idx & 511);
  const int head = wi >> 5, i = wi & 31;
  const int spos = token & 2047;
  const float f = freqs[spos * 32 + i];
  float sn, cs;
  sincosf(f, &sn, &cs);
  const long off = (long)token * 3072 + head * 64 + 2 * i;
  const float x0 = (float)p[off], x1 = (float)p[off + 1];
  p[off]     = (__bf16)(x0 * cs - x1 * sn);
  p[off + 1] = (__bf16)(x1 * cs + x0 * sn);
}

// ---------------------------------------------------------------- GEMM: out = act @ W^T + bias (+epilogue)
enum { EPI_NONE = 0, EPI_GELU = 1, EPI_RES = 2 };

template <int EPI, typename OT>
__global__ __launch_bounds__(256) void gemm_bt(
    const __bf16* __restrict__ A, const __bf16* __restrict__ W,
    const float* __restrict__ bias, const float* __restrict__ res,
    OT* __restrict__ out, int M, int N, int K) {
  __shared__ __bf16 lsA[128 * 64];
  __shared__ __bf16 lsB[128 * 64];
  const int tid = threadIdx.x, lane = tid & 63, w = tid >> 6;
  const int bm = blockIdx.y, bn = blockIdx.x;
  const int wm = w >> 1, wn = w & 1;
  const long Kl = K, Nl = N;
  const long a_row0 = (long)bm * 128, b_row0 = (long)bn * 128;
  const int pr_row = lane >> 3;
  const int pr_col = (lane & 7) * 8;

  f32x4 acc[4][4];
  const f32x4 fz = {0.f, 0.f, 0.f, 0.f};
#pragma unroll
  for (int i = 0; i < 4; ++i)
#pragma unroll
    for (int j = 0; j < 4; ++j) acc[i][j] = fz;

  for (int kt = 0; kt < K; kt += 64) {
#pragma unroll
    for (int p = 0; p < 4; ++p) {
      const int seg = p * 4 + w;
      const int row = seg * 8 + pr_row;
      gload16(A + (a_row0 + row) * Kl + kt + pr_col, (char*)lsA + seg * 1024);
      gload16(W + (b_row0 + row) * Kl + kt + pr_col, (char*)lsB + seg * 1024);
    }
    __syncthreads();
#pragma unroll
    for (int kk = 0; kk < 2; ++kk) {
      bf16x8 af[4], bfr[4];
#pragma unroll
      for (int i = 0; i < 4; ++i) {
        af[i]  = *(const bf16x8*)&lsA[(wm * 64 + i * 16 + (lane & 15)) * 64 + kk * 32 + 8 * (lane >> 4)];
        bfr[i] = *(const bf16x8*)&lsB[(wn * 64 + i * 16 + (lane & 15)) * 64 + kk * 32 + 8 * (lane >> 4)];
      }
#pragma unroll
      for (int mi = 0; mi < 4; ++mi)
#pragma unroll
        for (int ni = 0; ni < 4; ++ni)
          acc[mi][ni] = MFMA16(af[mi], bfr[ni], acc[mi][ni]);
    }
    __syncthreads();
  }

#pragma unroll
  for (int mi = 0; mi < 4; ++mi) {
#pragma unroll
    for (int ni = 0; ni < 4; ++ni) {
      const int col = bn * 128 + wn * 64 + ni * 16 + (lane & 15);
      const float bb = bias[col];
#pragma unroll
      for (int r = 0; r < 4; ++r) {
        const long row = a_row0 + wm * 64 + mi * 16 + (lane >> 4) * 4 + r;
        float vv = acc[mi][ni][r] + bb;
        if constexpr (EPI == EPI_GELU) vv = 0.5f * vv * (1.0f + erff(vv * 0.70710678f));
        if constexpr (EPI == EPI_RES) vv += res[row * Nl + col];
        out[row * Nl + col] = (OT)vv;
      }
    }
  }
}

// ---------------------------------------------------------------- Flash attention (causal), packed qkv LD=3072
// grid (S/64, H, B), 256 threads = 4 waves, each wave owns 16 q rows.
__global__ __launch_bounds__(256) void attn_kernel(
    const __bf16* __restrict__ qkv, __bf16* __restrict__ o) {
  __shared__ __bf16 lsK[64 * 64];
  __shared__ __bf16 lsV[64 * 64];
  __shared__ __bf16 lsP[4][16 * 64];
  const int tid = threadIdx.x, lane = tid & 63, w = tid >> 6;
  const int hi = lane >> 4, lo = lane & 15;
  const int b = blockIdx.z, h = blockIdx.y, q0 = blockIdx.x * 64;
  const int qw = q0 + w * 16;
  const long base  = (long)b * 2048 * 3072 + h * 64;
  const long obase = (long)b * 2048 * 1024 + h * 64;
  const __bf16* q    = qkv;
  const __bf16* kmat = qkv + 1024;
  const __bf16* v    = qkv + 2048;

  // Q fragments in registers
  bf16x8 aq[2];
#pragma unroll
  for (int kk = 0; kk < 2; ++kk)
    aq[kk] = *(const bf16x8*)&q[base + (long)(qw + lo) * 3072 + kk * 32 + 8 * hi];

  const f32x4 fz = {0.f, 0.f, 0.f, 0.f};
  f32x4 oacc[4];
  float mrun[4], lrun[4];
#pragma unroll
  for (int ni = 0; ni < 4; ++ni) oacc[ni] = fz;
#pragma unroll
  for (int r = 0; r < 4; ++r) { mrun[r] = -1e30f; lrun[r] = 0.f; }

  const int nkt = blockIdx.x + 1;
  for (int kt = 0; kt < nkt; ++kt) {
    // stage K tile [64 keys][64 d] via gload_lds, source pre-swizzled (T2 inverse)
#pragma unroll
    for (int p = 0; p < 2; ++p) {
      const int seg = p * 4 + w;
      const int row = seg * 8 + (lane >> 3);
      const int scol = (((lane & 7) ^ (lane >> 3)) * 8);
      gload16(kmat + base + (long)(kt * 64 + row) * 3072 + scol, (char*)lsK + seg * 1024);
    }
    // stage V transposed [d][key], XOR-swizzled both sides
    {
      const int key = tid >> 2, db = (tid & 3) * 16;
      const long gv = base + (long)(kt * 64 + key) * 3072 + db;
      bf16x8 v0 = *(const bf16x8*)&v[gv];
      bf16x8 v1 = *(const bf16x8*)&v[gv + 8];
      char* lv = (char*)lsV;
#pragma unroll
      for (int j = 0; j < 8; ++j) {
        const int d0 = db + j, d1 = db + 8 + j;
        *(__bf16*)(lv + d0 * 128 + ((key * 2) ^ ((d0 & 7) << 4) ^ (((d0 >> 4) & 3) << 5))) = v0[j];
        *(__bf16*)(lv + d1 * 128 + ((key * 2) ^ ((d1 & 7) << 4) ^ (((d1 >> 4) & 3) << 5))) = v1[j];
      }
    }
    __syncthreads();

    // S = Q K^T   (swizzled K reads)
    f32x4 sacc[4];
#pragma unroll
    for (int ni = 0; ni < 4; ++ni) sacc[ni] = fz;
#pragma unroll
    for (int kk = 0; kk < 2; ++kk) {
      bf16x8 bk[4];
#pragma unroll
      for (int ni = 0; ni < 4; ++ni) {
        const int row = ni * 16 + lo;
        bk[ni] = *(const bf16x8*)((char*)lsK + row * 128 +
                                  ((kk * 64 + 16 * hi) ^ ((row & 7) << 4)));
      }
#pragma unroll
      for (int ni = 0; ni < 4; ++ni)
        sacc[ni] = MFMA16(aq[kk], bk[ni], sacc[ni]);
    }

    // online softmax (wave-parallel, 16-lane row groups)
#pragma unroll
    for (int r = 0; r < 4; ++r) {
      const int row_g = qw + hi * 4 + r;
      const int prow = hi * 4 + r;
      float sv[4];
      float mx = -3.0e38f;
#pragma unroll
      for (int ni = 0; ni < 4; ++ni) {
        const int key_g = kt * 64 + ni * 16 + lo;
        float s = sacc[ni][r] * 0.125f;
        if (key_g > row_g) s = -1e9f;
        sv[ni] = s;
        mx = fmaxf(mx, s);
      }
#pragma unroll
      for (int d = 1; d < 16; d <<= 1) mx = fmaxf(mx, __shfl_xor(mx, d));
      const float mold = mrun[r];
      const float mnew = fmaxf(mold, mx);
      const float fac = __expf(mold - mnew);
      float sum = 0.f;
#pragma unroll
      for (int ni = 0; ni < 4; ++ni) {
        const float pp = __expf(sv[ni] - mnew);
        sum += pp;
        *(__bf16*)((char*)lsP[w] + prow * 128 +
                   (((ni * 16 + lo) * 2) ^ ((prow & 7) << 4))) = (__bf16)pp;
      }
#pragma unroll
      for (int d = 1; d < 16; d <<= 1) sum += __shfl_xor(sum, d);
      mrun[r] = mnew;
      lrun[r] = lrun[r] * fac + sum;
#pragma unroll
      for (int ni = 0; ni < 4; ++ni) oacc[ni][r] *= fac;
    }
    // no barrier needed: lsP is wave-private, DS ops are wave-ordered

    // O += P V   (swizzled P and V reads)
#pragma unroll
    for (int kk = 0; kk < 2; ++kk) {
      bf16x8 ap, bv[4];
      ap = *(const bf16x8*)((char*)lsP[w] + lo * 128 +
                            ((kk * 64 + 16 * hi) ^ ((lo & 7) << 4)));
#pragma unroll
      for (int ni = 0; ni < 4; ++ni) {
        const int d = ni * 16 + lo;
        bv[ni] = *(const bf16x8*)((char*)lsV + d * 128 +
                                  ((kk * 64 + 16 * hi) ^ ((d & 7) << 4) ^ (((d >> 4) & 3) << 5)));
      }
#pragma unroll
      for (int ni = 0; ni < 4; ++ni)
        oacc[ni] = MFMA16(ap, bv[ni], oacc[ni]);
    }
    __syncthreads();
  }

  // epilogue
#pragma unroll
  for (int ni = 0; ni < 4; ++ni)
#pragma unroll
    for (int r = 0; r < 4; ++r) {
      const int row_g = qw + hi * 4 + r;
      o[obase + (long)row_g * 1024 + ni * 16 + lo] = (__bf16)(oacc[ni][r] / lrun[r]);
    }
}

// ---------------------------------------------------------------- launcher
extern "C" void kernel_launch(void* const* d_in, const int* in_sizes, int n_in,
                              void* d_out, int out_size, void* d_ws, size_t ws_size,
                              hipStream_t stream) {
  const float* x    = (const float*)d_in[0];
  const float* fr   = (const float*)d_in[1];
  const float* ln1g = (const float*)d_in[3];
  const float* ln1b = (const float*)d_in[4];
  const float* Wq   = (const float*)d_in[5];
  const float* bq   = (const float*)d_in[6];
  const float* Wk   = (const float*)d_in[7];
  const float* bk   = (const float*)d_in[8];
  const float* Wv   = (const float*)d_in[9];
  const float* bv   = (const float*)d_in[10];
  const float* Wo   = (const float*)d_in[11];
  const float* bo   = (const float*)d_in[12];
  const float* ln2g = (const float*)d_in[13];
  const float* ln2b = (const float*)d_in[14];
  const float* W1   = (const float*)d_in[15];
  const float* b1   = (const float*)d_in[16];
  const float* W2   = (const float*)d_in[17];
  const float* b2   = (const float*)d_in[18];
  float* out = (float*)d_out;

  char* ws = (char*)d_ws;
  const size_t SZ = 8388608;  // 8 MB
  __bf16* xn   = (__bf16*)(ws + 0);              // 8 MB
  __bf16* qkv  = (__bf16*)(ws + 1 * SZ);         // 24 MB (8..32)
  __bf16* attn = (__bf16*)(ws + 0);              // reuse xn
  float*  bqkv = (float*)(ws + 4 * SZ);          // 12 KB, dead before x2 written
  float*  x2   = (float*)(ws + 4 * SZ);          // 16 MB f32 (32..48)
  __bf16* hin  = (__bf16*)(ws + 6 * SZ);         // 8 MB (48..56)
  __bf16* hmid = (__bf16*)(ws + 0);              // 32 MB (0..32), qkv/attn dead
  char* wb = ws + 7 * SZ;                        // bf16 weights, 24 MB (56..80)
  __bf16* Wqkvb = (__bf16*)(wb + 0);             // 6 MB: Wq|Wk|Wv packed along N
  __bf16* Wob   = (__bf16*)(wb + 6 * 1048576);
  __bf16* W1b   = (__bf16*)(wb + 8 * 1048576);
  __bf16* W2b   = (__bf16*)(wb + 16 * 1048576);

  const int M = 4096, D = 1024, FF = 4096;
  dim3 blk(256);

  // weight conversion f32 -> bf16 (Wq/Wk/Wv packed contiguously -> one [3072][1024])
  cvt_kernel<<<512,  blk, 0, stream>>>(Wq, Wqkvb,               (long)D * D);
  cvt_kernel<<<512,  blk, 0, stream>>>(Wk, Wqkvb + 1048576,     (long)D * D);
  cvt_kernel<<<512,  blk, 0, stream>>>(Wv, Wqkvb + 2 * 1048576, (long)D * D);
  cvt_kernel<<<512,  blk, 0, stream>>>(Wo, Wob, (long)D * D);
  cvt_kernel<<<2048, blk, 0, stream>>>(W1, W1b, (long)FF * D);
  cvt_kernel<<<2048, blk, 0, stream>>>(W2, W2b, (long)D * FF);
  pack3_kernel<<<12, blk, 0, stream>>>(bq, bk, bv, bqkv);

  ln_kernel<<<4096, blk, 0, stream>>>(x, ln1g, ln1b, xn);
  gemm_bt<EPI_NONE, __bf16><<<dim3(3072 / 128, M / 128), blk, 0, stream>>>(
      xn, Wqkvb, bqkv, nullptr, qkv, M, 3072, D);
  rope_kernel<<<dim3(8192, 2), blk, 0, stream>>>(qkv, fr);
  attn_kernel<<<dim3(32, 16, 2), blk, 0, stream>>>(qkv, attn);
  gemm_bt<EPI_RES, float><<<dim3(D / 128, M / 128), blk, 0, stream>>>(
      attn, Wob, bo, x, x2, M, D, D);
  ln_kernel<<<4096, blk, 0, stream>>>(x2, ln2g, ln2b, hin);
  gemm_bt<EPI_GELU, __bf16><<<dim3(FF / 128, M / 128), blk, 0, stream>>>(
      hin, W1b, b1, nullptr, hmid, M, FF, D);
  gemm_bt<EPI_RES, float><<<dim3(D / 128, M / 128), blk, 0, stream>>>(
      hmid, W2b, b2, x2, out, M, D, FF);
}

// Round 6
// 402.854 us; speedup vs baseline: 1.1372x; 1.0091x over previous
//
#include <hip/hip_runtime.h>
#include <hip/hip_bf16.h>

typedef __bf16 bf16x8 __attribute__((ext_vector_type(8)));
typedef __bf16 bf16x4 __attribute__((ext_vector_type(4)));
typedef float  f32x4  __attribute__((ext_vector_type(4)));

#define MFMA16(a, b, c) __builtin_amdgcn_mfma_f32_16x16x32_bf16((a), (b), (c), 0, 0, 0)

__device__ __forceinline__ void gload16(const void* g, void* l) {
  __builtin_amdgcn_global_load_lds(
      (const __attribute__((address_space(1))) unsigned int*)g,
      (__attribute__((address_space(3))) unsigned int*)l, 16, 0, 0);
}

// ---------------------------------------------------------------- f32 -> bf16 pack
__global__ __launch_bounds__(256) void cvt_kernel(
    const float* __restrict__ in, __bf16* __restrict__ out, long n) {
  const long i = ((long)blockIdx.x * 256 + threadIdx.x) * 8;
  if (i + 7 < n) {
    float4 a = *(const float4*)&in[i];
    float4 b = *(const float4*)&in[i + 4];
    bf16x8 o;
    o[0] = (__bf16)a.x; o[1] = (__bf16)a.y; o[2] = (__bf16)a.z; o[3] = (__bf16)a.w;
    o[4] = (__bf16)b.x; o[5] = (__bf16)b.y; o[6] = (__bf16)b.z; o[7] = (__bf16)b.w;
    *(bf16x8*)&out[i] = o;
  }
}

// pack 3 bias vectors (1024 each) into one f32[3072]
__global__ __launch_bounds__(256) void pack3_kernel(
    const float* __restrict__ a, const float* __restrict__ b,
    const float* __restrict__ c, float* __restrict__ o) {
  const int i = blockIdx.x * 256 + threadIdx.x;
  o[i] = i < 1024 ? a[i] : (i < 2048 ? b[i - 1024] : c[i - 2048]);
}

// ---------------------------------------------------------------- LayerNorm (f32 in -> bf16 out)
__global__ __launch_bounds__(256) void ln_kernel(
    const float* __restrict__ in, const float* __restrict__ gg,
    const float* __restrict__ bb, __bf16* __restrict__ out) {
  __shared__ float sred[8];
  const long row = blockIdx.x;
  const int tid = threadIdx.x;
  float4 u = *(const float4*)&in[row * 1024 + tid * 4];
  float f[4] = {u.x, u.y, u.z, u.w};
  float s = 0.f, sq = 0.f;
#pragma unroll
  for (int j = 0; j < 4; ++j) { s += f[j]; sq += f[j] * f[j]; }
#pragma unroll
  for (int d = 32; d; d >>= 1) { s += __shfl_xor(s, d); sq += __shfl_xor(sq, d); }
  const int w = tid >> 6;
  if ((tid & 63) == 0) { sred[w * 2] = s; sred[w * 2 + 1] = sq; }
  __syncthreads();
  s  = sred[0] + sred[2] + sred[4] + sred[6];
  sq = sred[1] + sred[3] + sred[5] + sred[7];
  const float mean = s * (1.f / 1024.f);
  const float var  = sq * (1.f / 1024.f) - mean * mean;
  const float rstd = rsqrtf(var + 1e-5f);
  float4 gv = *(const float4*)&gg[tid * 4];
  float4 bv = *(const float4*)&bb[tid * 4];
  bf16x4 ov;
  ov[0] = (__bf16)((f[0] - mean) * rstd * gv.x + bv.x);
  ov[1] = (__bf16)((f[1] - mean) * rstd * gv.y + bv.y);
  ov[2] = (__bf16)((f[2] - mean) * rstd * gv.z + bv.z);
  ov[3] = (__bf16)((f[3] - mean) * rstd * gv.w + bv.w);
  *(bf16x4*)&out[row * 1024 + tid * 4] = ov;
}

// ---------------------------------------------------------------- RoPE (in place on packed qkv, LD=3072), bf16x8 vectorized
__global__ __launch_bounds__(256) void rope_kernel(
    __bf16* __restrict__ qkv, const float* __restrict__ freqs) {
  const int idx = blockIdx.x * 256 + threadIdx.x;   // [0, 4096*16*8)
  __bf16* p = qkv + (blockIdx.y ? 1024 : 0);
  const int token = idx >> 7;
  const int wi = idx & 127;
  const int head = wi >> 3, i4 = wi & 7;
  const int spos = token & 2047;
  float4 fv = *(const float4*)&freqs[spos * 32 + i4 * 4];
  const long off = (long)token * 3072 + head * 64 + i4 * 8;
  bf16x8 u = *(bf16x8*)&p[off];
  float sn[4], cs[4];
  sincosf(fv.x, &sn[0], &cs[0]);
  sincosf(fv.y, &sn[1], &cs[1]);
  sincosf(fv.z, &sn[2], &cs[2]);
  sincosf(fv.w, &sn[3], &cs[3]);
  bf16x8 ov;
#pragma unroll
  for (int j = 0; j < 4; ++j) {
    const float x0 = (float)u[2 * j], x1 = (float)u[2 * j + 1];
    ov[2 * j]     = (__bf16)(x0 * cs[j] - x1 * sn[j]);
    ov[2 * j + 1] = (__bf16)(x1 * cs[j] + x0 * sn[j]);
  }
  *(bf16x8*)&p[off] = ov;
}

// ---------------------------------------------------------------- GEMM: out = act @ W^T + bias (+epilogue)
enum { EPI_NONE = 0, EPI_GELU = 1, EPI_RES = 2 };

template <int EPI, typename OT>
__global__ __launch_bounds__(256) void gemm_bt(
    const __bf16* __restrict__ A, const __bf16* __restrict__ W,
    const float* __restrict__ bias, const float* __restrict__ res,
    OT* __restrict__ out, int M, int N, int K) {
  __shared__ __bf16 lsA[128 * 64];
  __shared__ __bf16 lsB[128 * 64];
  const int tid = threadIdx.x, lane = tid & 63, w = tid >> 6;
  const int bm = blockIdx.y, bn = blockIdx.x;
  const int wm = w >> 1, wn = w & 1;
  const long Kl = K, Nl = N;
  const long a_row0 = (long)bm * 128, b_row0 = (long)bn * 128;
  const int pr_row = lane >> 3;
  const int pr_col = (lane & 7) * 8;

  f32x4 acc[4][4];
  const f32x4 fz = {0.f, 0.f, 0.f, 0.f};
#pragma unroll
  for (int i = 0; i < 4; ++i)
#pragma unroll
    for (int j = 0; j < 4; ++j) acc[i][j] = fz;

  for (int kt = 0; kt < K; kt += 64) {
#pragma unroll
    for (int p = 0; p < 4; ++p) {
      const int seg = p * 4 + w;
      const int row = seg * 8 + pr_row;
      gload16(A + (a_row0 + row) * Kl + kt + pr_col, (char*)lsA + seg * 1024);
      gload16(W + (b_row0 + row) * Kl + kt + pr_col, (char*)lsB + seg * 1024);
    }
    __syncthreads();
#pragma unroll
    for (int kk = 0; kk < 2; ++kk) {
      bf16x8 af[4], bfr[4];
#pragma unroll
      for (int i = 0; i < 4; ++i) {
        af[i]  = *(const bf16x8*)&lsA[(wm * 64 + i * 16 + (lane & 15)) * 64 + kk * 32 + 8 * (lane >> 4)];
        bfr[i] = *(const bf16x8*)&lsB[(wn * 64 + i * 16 + (lane & 15)) * 64 + kk * 32 + 8 * (lane >> 4)];
      }
#pragma unroll
      for (int mi = 0; mi < 4; ++mi)
#pragma unroll
        for (int ni = 0; ni < 4; ++ni)
          acc[mi][ni] = MFMA16(af[mi], bfr[ni], acc[mi][ni]);
    }
    __syncthreads();
  }

#pragma unroll
  for (int mi = 0; mi < 4; ++mi) {
#pragma unroll
    for (int ni = 0; ni < 4; ++ni) {
      const int col = bn * 128 + wn * 64 + ni * 16 + (lane & 15);
      const float bb = bias[col];
#pragma unroll
      for (int r = 0; r < 4; ++r) {
        const long row = a_row0 + wm * 64 + mi * 16 + (lane >> 4) * 4 + r;
        float vv = acc[mi][ni][r] + bb;
        if constexpr (EPI == EPI_GELU) vv = 0.5f * vv * (1.0f + erff(vv * 0.70710678f));
        if constexpr (EPI == EPI_RES) vv += res[row * Nl + col];
        out[row * Nl + col] = (OT)vv;
      }
    }
  }
}

// ---------------------------------------------------------------- Flash attention (causal), packed qkv LD=3072
// grid (S/64, H, B), 256 threads = 4 waves, each wave owns 16 q rows.
// Identical numerics to the R3-passing version; only block order reversed (LPT).
__global__ __launch_bounds__(256) void attn_kernel(
    const __bf16* __restrict__ qkv, __bf16* __restrict__ o) {
  __shared__ __bf16 lsK[64 * 64];
  __shared__ __bf16 lsV[64 * 64];
  __shared__ __bf16 lsP[4][16 * 64];
  const int tid = threadIdx.x, lane = tid & 63, w = tid >> 6;
  const int hi = lane >> 4, lo = lane & 15;
  const int bx = gridDim.x - 1 - blockIdx.x;   // LPT: longest blocks first
  const int b = blockIdx.z, h = blockIdx.y, q0 = bx * 64;
  const int qw = q0 + w * 16;
  const long base  = (long)b * 2048 * 3072 + h * 64;
  const long obase = (long)b * 2048 * 1024 + h * 64;
  const __bf16* q    = qkv;
  const __bf16* kmat = qkv + 1024;
  const __bf16* v    = qkv + 2048;

  // Q fragments in registers
  bf16x8 aq[2];
#pragma unroll
  for (int kk = 0; kk < 2; ++kk)
    aq[kk] = *(const bf16x8*)&q[base + (long)(qw + lo) * 3072 + kk * 32 + 8 * hi];

  const f32x4 fz = {0.f, 0.f, 0.f, 0.f};
  f32x4 oacc[4];
  float mrun[4], lrun[4];
#pragma unroll
  for (int ni = 0; ni < 4; ++ni) oacc[ni] = fz;
#pragma unroll
  for (int r = 0; r < 4; ++r) { mrun[r] = -1e30f; lrun[r] = 0.f; }

  const int nkt = bx + 1;
  for (int kt = 0; kt < nkt; ++kt) {
    // stage K tile [64 keys][64 d] via gload_lds, source pre-swizzled (T2 inverse)
#pragma unroll
    for (int p = 0; p < 2; ++p) {
      const int seg = p * 4 + w;
      const int row = seg * 8 + (lane >> 3);
      const int scol = (((lane & 7) ^ (lane >> 3)) * 8);
      gload16(kmat + base + (long)(kt * 64 + row) * 3072 + scol, (char*)lsK + seg * 1024);
    }
    // stage V transposed [d][key], XOR-swizzled both sides
    {
      const int key = tid >> 2, db = (tid & 3) * 16;
      const long gv = base + (long)(kt * 64 + key) * 3072 + db;
      bf16x8 v0 = *(const bf16x8*)&v[gv];
      bf16x8 v1 = *(const bf16x8*)&v[gv + 8];
      char* lv = (char*)lsV;
#pragma unroll
      for (int j = 0; j < 8; ++j) {
        const int d0 = db + j, d1 = db + 8 + j;
        *(__bf16*)(lv + d0 * 128 + ((key * 2) ^ ((d0 & 7) << 4) ^ (((d0 >> 4) & 3) << 5))) = v0[j];
        *(__bf16*)(lv + d1 * 128 + ((key * 2) ^ ((d1 & 7) << 4) ^ (((d1 >> 4) & 3) << 5))) = v1[j];
      }
    }
    __syncthreads();

    // S = Q K^T   (swizzled K reads)
    f32x4 sacc[4];
#pragma unroll
    for (int ni = 0; ni < 4; ++ni) sacc[ni] = fz;
#pragma unroll
    for (int kk = 0; kk < 2; ++kk) {
      bf16x8 bk[4];
#pragma unroll
      for (int ni = 0; ni < 4; ++ni) {
        const int row = ni * 16 + lo;
        bk[ni] = *(const bf16x8*)((char*)lsK + row * 128 +
                                  ((kk * 64 + 16 * hi) ^ ((row & 7) << 4)));
      }
#pragma unroll
      for (int ni = 0; ni < 4; ++ni)
        sacc[ni] = MFMA16(aq[kk], bk[ni], sacc[ni]);
    }

    // online softmax (wave-parallel, 16-lane row groups)
#pragma unroll
    for (int r = 0; r < 4; ++r) {
      const int row_g = qw + hi * 4 + r;
      const int prow = hi * 4 + r;
      float sv[4];
      float mx = -3.0e38f;
#pragma unroll
      for (int ni = 0; ni < 4; ++ni) {
        const int key_g = kt * 64 + ni * 16 + lo;
        float s = sacc[ni][r] * 0.125f;
        if (key_g > row_g) s = -1e9f;
        sv[ni] = s;
        mx = fmaxf(mx, s);
      }
#pragma unroll
      for (int d = 1; d < 16; d <<= 1) mx = fmaxf(mx, __shfl_xor(mx, d));
      const float mold = mrun[r];
      const float mnew = fmaxf(mold, mx);
      const float fac = __expf(mold - mnew);
      float sum = 0.f;
#pragma unroll
      for (int ni = 0; ni < 4; ++ni) {
        const float pp = __expf(sv[ni] - mnew);
        sum += pp;
        *(__bf16*)((char*)lsP[w] + prow * 128 +
                   (((ni * 16 + lo) * 2) ^ ((prow & 7) << 4))) = (__bf16)pp;
      }
#pragma unroll
      for (int d = 1; d < 16; d <<= 1) sum += __shfl_xor(sum, d);
      mrun[r] = mnew;
      lrun[r] = lrun[r] * fac + sum;
#pragma unroll
      for (int ni = 0; ni < 4; ++ni) oacc[ni][r] *= fac;
    }
    // no barrier needed: lsP is wave-private, DS ops are wave-ordered

    // O += P V   (swizzled P and V reads)
#pragma unroll
    for (int kk = 0; kk < 2; ++kk) {
      bf16x8 ap, bv[4];
      ap = *(const bf16x8*)((char*)lsP[w] + lo * 128 +
                            ((kk * 64 + 16 * hi) ^ ((lo & 7) << 4)));
#pragma unroll
      for (int ni = 0; ni < 4; ++ni) {
        const int d = ni * 16 + lo;
        bv[ni] = *(const bf16x8*)((char*)lsV + d * 128 +
                                  ((kk * 64 + 16 * hi) ^ ((d & 7) << 4) ^ (((d >> 4) & 3) << 5)));
      }
#pragma unroll
      for (int ni = 0; ni < 4; ++ni)
        oacc[ni] = MFMA16(ap, bv[ni], oacc[ni]);
    }
    __syncthreads();
  }

  // epilogue
#pragma unroll
  for (int ni = 0; ni < 4; ++ni)
#pragma unroll
    for (int r = 0; r < 4; ++r) {
      const int row_g = qw + hi * 4 + r;
      o[obase + (long)row_g * 1024 + ni * 16 + lo] = (__bf16)(oacc[ni][r] / lrun[r]);
    }
}

// ---------------------------------------------------------------- launcher
extern "C" void kernel_launch(void* const* d_in, const int* in_sizes, int n_in,
                              void* d_out, int out_size, void* d_ws, size_t ws_size,
                              hipStream_t stream) {
  const float* x    = (const float*)d_in[0];
  const float* fr   = (const float*)d_in[1];
  const float* ln1g = (const float*)d_in[3];
  const float* ln1b = (const float*)d_in[4];
  const float* Wq   = (const float*)d_in[5];
  const float* bq   = (const float*)d_in[6];
  const float* Wk   = (const float*)d_in[7];
  const float* bk   = (const float*)d_in[8];
  const float* Wv   = (const float*)d_in[9];
  const float* bv   = (const float*)d_in[10];
  const float* Wo   = (const float*)d_in[11];
  const float* bo   = (const float*)d_in[12];
  const float* ln2g = (const float*)d_in[13];
  const float* ln2b = (const float*)d_in[14];
  const float* W1   = (const float*)d_in[15];
  const float* b1   = (const float*)d_in[16];
  const float* W2   = (const float*)d_in[17];
  const float* b2   = (const float*)d_in[18];
  float* out = (float*)d_out;

  char* ws = (char*)d_ws;
  const size_t SZ = 8388608;  // 8 MB
  __bf16* xn   = (__bf16*)(ws + 0);              // 8 MB
  __bf16* qkv  = (__bf16*)(ws + 1 * SZ);         // 24 MB (8..32)
  __bf16* attn = (__bf16*)(ws + 0);              // reuse xn
  float*  bqkv = (float*)(ws + 4 * SZ);          // 12 KB, dead before x2 written
  float*  x2   = (float*)(ws + 4 * SZ);          // 16 MB f32 (32..48)
  __bf16* hin  = (__bf16*)(ws + 6 * SZ);         // 8 MB (48..56)
  __bf16* hmid = (__bf16*)(ws + 0);              // 32 MB (0..32), qkv/attn dead
  char* wb = ws + 7 * SZ;                        // bf16 weights, 24 MB (56..80)
  __bf16* Wqkvb = (__bf16*)(wb + 0);             // 6 MB: Wq|Wk|Wv packed along N
  __bf16* Wob   = (__bf16*)(wb + 6 * 1048576);
  __bf16* W1b   = (__bf16*)(wb + 8 * 1048576);
  __bf16* W2b   = (__bf16*)(wb + 16 * 1048576);

  const int M = 4096, D = 1024, FF = 4096;
  dim3 blk(256);

  cvt_kernel<<<512,  blk, 0, stream>>>(Wq, Wqkvb,               (long)D * D);
  cvt_kernel<<<512,  blk, 0, stream>>>(Wk, Wqkvb + 1048576,     (long)D * D);
  cvt_kernel<<<512,  blk, 0, stream>>>(Wv, Wqkvb + 2 * 1048576, (long)D * D);
  cvt_kernel<<<512,  blk, 0, stream>>>(Wo, Wob, (long)D * D);
  cvt_kernel<<<2048, blk, 0, stream>>>(W1, W1b, (long)FF * D);
  cvt_kernel<<<2048, blk, 0, stream>>>(W2, W2b, (long)D * FF);
  pack3_kernel<<<12, blk, 0, stream>>>(bq, bk, bv, bqkv);

  ln_kernel<<<4096, blk, 0, stream>>>(x, ln1g, ln1b, xn);
  gemm_bt<EPI_NONE, __bf16><<<dim3(3072 / 128, M / 128), blk, 0, stream>>>(
      xn, Wqkvb, bqkv, nullptr, qkv, M, 3072, D);
  rope_kernel<<<dim3(2048, 2), blk, 0, stream>>>(qkv, fr);
  attn_kernel<<<dim3(32, 16, 2), blk, 0, stream>>>(qkv, attn);
  gemm_bt<EPI_RES, float><<<dim3(D / 128, M / 128), blk, 0, stream>>>(
      attn, Wob, bo, x, x2, M, D, D);
  ln_kernel<<<4096, blk, 0, stream>>>(x2, ln2g, ln2b, hin);
  gemm_bt<EPI_GELU, __bf16><<<dim3(FF / 128, M / 128), blk, 0, stream>>>(
      hin, W1b, b1, nullptr, hmid, M, FF, D);
  gemm_bt<EPI_RES, float><<<dim3(D / 128, M / 128), blk, 0, stream>>>(
      hmid, W2b, b2, x2, out, M, D, FF);
}

// Round 7
// 383.192 us; speedup vs baseline: 1.1955x; 1.0513x over previous
//
#include <hip/hip_runtime.h>
#include <hip/hip_bf16.h>

typedef __bf16 bf16x8 __attribute__((ext_vector_type(8)));
typedef __bf16 bf16x4 __attribute__((ext_vector_type(4)));
typedef float  f32x4  __attribute__((ext_vector_type(4)));

#define MFMA16(a, b, c) __builtin_amdgcn_mfma_f32_16x16x32_bf16((a), (b), (c), 0, 0, 0)

__device__ __forceinline__ void gload16(const void* g, void* l) {
  __builtin_amdgcn_global_load_lds(
      (const __attribute__((address_space(1))) unsigned int*)g,
      (__attribute__((address_space(3))) unsigned int*)l, 16, 0, 0);
}

// ---------------------------------------------------------------- f32 -> bf16 pack, all 6 weights in one launch
// dst is one contiguous bf16 region: Wq|Wk|Wv|Wo|W1|W2 (1M,1M,1M,1M,4M,4M elements)
__global__ __launch_bounds__(256) void cvt6_kernel(
    const float* __restrict__ wq, const float* __restrict__ wk,
    const float* __restrict__ wv, const float* __restrict__ wo,
    const float* __restrict__ w1, const float* __restrict__ w2,
    __bf16* __restrict__ dst) {
  const long i = ((long)blockIdx.x * 256 + threadIdx.x) * 8;  // [0, 12M)
  const long M1 = 1048576;
  const float* src;
  long off;
  if      (i < 1 * M1) { src = wq; off = i; }
  else if (i < 2 * M1) { src = wk; off = i - 1 * M1; }
  else if (i < 3 * M1) { src = wv; off = i - 2 * M1; }
  else if (i < 4 * M1) { src = wo; off = i - 3 * M1; }
  else if (i < 8 * M1) { src = w1; off = i - 4 * M1; }
  else                 { src = w2; off = i - 8 * M1; }
  float4 a = *(const float4*)&src[off];
  float4 b = *(const float4*)&src[off + 4];
  bf16x8 o;
  o[0] = (__bf16)a.x; o[1] = (__bf16)a.y; o[2] = (__bf16)a.z; o[3] = (__bf16)a.w;
  o[4] = (__bf16)b.x; o[5] = (__bf16)b.y; o[6] = (__bf16)b.z; o[7] = (__bf16)b.w;
  *(bf16x8*)&dst[i] = o;
}

// pack 3 bias vectors (1024 each) into one f32[3072]
__global__ __launch_bounds__(256) void pack3_kernel(
    const float* __restrict__ a, const float* __restrict__ b,
    const float* __restrict__ c, float* __restrict__ o) {
  const int i = blockIdx.x * 256 + threadIdx.x;
  o[i] = i < 1024 ? a[i] : (i < 2048 ? b[i - 1024] : c[i - 2048]);
}

// ---------------------------------------------------------------- LayerNorm (f32 in -> bf16 out)
__global__ __launch_bounds__(256) void ln_kernel(
    const float* __restrict__ in, const float* __restrict__ gg,
    const float* __restrict__ bb, __bf16* __restrict__ out) {
  __shared__ float sred[8];
  const long row = blockIdx.x;
  const int tid = threadIdx.x;
  float4 u = *(const float4*)&in[row * 1024 + tid * 4];
  float f[4] = {u.x, u.y, u.z, u.w};
  float s = 0.f, sq = 0.f;
#pragma unroll
  for (int j = 0; j < 4; ++j) { s += f[j]; sq += f[j] * f[j]; }
#pragma unroll
  for (int d = 32; d; d >>= 1) { s += __shfl_xor(s, d); sq += __shfl_xor(sq, d); }
  const int w = tid >> 6;
  if ((tid & 63) == 0) { sred[w * 2] = s; sred[w * 2 + 1] = sq; }
  __syncthreads();
  s  = sred[0] + sred[2] + sred[4] + sred[6];
  sq = sred[1] + sred[3] + sred[5] + sred[7];
  const float mean = s * (1.f / 1024.f);
  const float var  = sq * (1.f / 1024.f) - mean * mean;
  const float rstd = rsqrtf(var + 1e-5f);
  float4 gv = *(const float4*)&gg[tid * 4];
  float4 bv = *(const float4*)&bb[tid * 4];
  bf16x4 ov;
  ov[0] = (__bf16)((f[0] - mean) * rstd * gv.x + bv.x);
  ov[1] = (__bf16)((f[1] - mean) * rstd * gv.y + bv.y);
  ov[2] = (__bf16)((f[2] - mean) * rstd * gv.z + bv.z);
  ov[3] = (__bf16)((f[3] - mean) * rstd * gv.w + bv.w);
  *(bf16x4*)&out[row * 1024 + tid * 4] = ov;
}

// ---------------------------------------------------------------- RoPE (in place on packed qkv, LD=3072), bf16x8
// blockIdx.y==0 -> q (scaled by 0.125, exact pow2 fold of 1/sqrt(HD)); y==1 -> k.
__global__ __launch_bounds__(256) void rope_kernel(
    __bf16* __restrict__ qkv, const float* __restrict__ freqs) {
  const int idx = blockIdx.x * 256 + threadIdx.x;   // [0, 4096*16*8)
  const int isq = (blockIdx.y == 0);
  __bf16* p = qkv + (isq ? 0 : 1024);
  const float scale = isq ? 0.125f : 1.0f;
  const int token = idx >> 7;
  const int wi = idx & 127;
  const int head = wi >> 3, i4 = wi & 7;
  const int spos = token & 2047;
  float4 fv = *(const float4*)&freqs[spos * 32 + i4 * 4];
  const long off = (long)token * 3072 + head * 64 + i4 * 8;
  bf16x8 u = *(bf16x8*)&p[off];
  float sn[4], cs[4];
  sincosf(fv.x, &sn[0], &cs[0]);
  sincosf(fv.y, &sn[1], &cs[1]);
  sincosf(fv.z, &sn[2], &cs[2]);
  sincosf(fv.w, &sn[3], &cs[3]);
  bf16x8 ov;
#pragma unroll
  for (int j = 0; j < 4; ++j) {
    const float x0 = (float)u[2 * j], x1 = (float)u[2 * j + 1];
    ov[2 * j]     = (__bf16)((x0 * cs[j] - x1 * sn[j]) * scale);
    ov[2 * j + 1] = (__bf16)((x1 * cs[j] + x0 * sn[j]) * scale);
  }
  *(bf16x8*)&p[off] = ov;
}

// ---------------------------------------------------------------- GEMM: out = act @ W^T + bias (+epilogue)
enum { EPI_NONE = 0, EPI_GELU = 1, EPI_RES = 2 };

template <int EPI, typename OT>
__global__ __launch_bounds__(256) void gemm_bt(
    const __bf16* __restrict__ A, const __bf16* __restrict__ W,
    const float* __restrict__ bias, const float* __restrict__ res,
    OT* __restrict__ out, int M, int N, int K) {
  __shared__ __bf16 lsA[128 * 64];
  __shared__ __bf16 lsB[128 * 64];
  const int tid = threadIdx.x, lane = tid & 63, w = tid >> 6;
  const int bm = blockIdx.y, bn = blockIdx.x;
  const int wm = w >> 1, wn = w & 1;
  const long Kl = K, Nl = N;
  const long a_row0 = (long)bm * 128, b_row0 = (long)bn * 128;
  const int pr_row = lane >> 3;
  const int pr_col = (lane & 7) * 8;

  f32x4 acc[4][4];
  const f32x4 fz = {0.f, 0.f, 0.f, 0.f};
#pragma unroll
  for (int i = 0; i < 4; ++i)
#pragma unroll
    for (int j = 0; j < 4; ++j) acc[i][j] = fz;

  for (int kt = 0; kt < K; kt += 64) {
#pragma unroll
    for (int p = 0; p < 4; ++p) {
      const int seg = p * 4 + w;
      const int row = seg * 8 + pr_row;
      gload16(A + (a_row0 + row) * Kl + kt + pr_col, (char*)lsA + seg * 1024);
      gload16(W + (b_row0 + row) * Kl + kt + pr_col, (char*)lsB + seg * 1024);
    }
    __syncthreads();
#pragma unroll
    for (int kk = 0; kk < 2; ++kk) {
      bf16x8 af[4], bfr[4];
#pragma unroll
      for (int i = 0; i < 4; ++i) {
        af[i]  = *(const bf16x8*)&lsA[(wm * 64 + i * 16 + (lane & 15)) * 64 + kk * 32 + 8 * (lane >> 4)];
        bfr[i] = *(const bf16x8*)&lsB[(wn * 64 + i * 16 + (lane & 15)) * 64 + kk * 32 + 8 * (lane >> 4)];
      }
#pragma unroll
      for (int mi = 0; mi < 4; ++mi)
#pragma unroll
        for (int ni = 0; ni < 4; ++ni)
          acc[mi][ni] = MFMA16(af[mi], bfr[ni], acc[mi][ni]);
    }
    __syncthreads();
  }

#pragma unroll
  for (int mi = 0; mi < 4; ++mi) {
#pragma unroll
    for (int ni = 0; ni < 4; ++ni) {
      const int col = bn * 128 + wn * 64 + ni * 16 + (lane & 15);
      const float bb = bias[col];
#pragma unroll
      for (int r = 0; r < 4; ++r) {
        const long row = a_row0 + wm * 64 + mi * 16 + (lane >> 4) * 4 + r;
        float vv = acc[mi][ni][r] + bb;
        if constexpr (EPI == EPI_GELU) vv = 0.5f * vv * (1.0f + erff(vv * 0.70710678f));
        if constexpr (EPI == EPI_RES) vv += res[row * Nl + col];
        out[row * Nl + col] = (OT)vv;
      }
    }
  }
}

// ---------------------------------------------------------------- Flash attention (causal), packed qkv LD=3072
// grid (S/64, H, B), 4 waves x 16 q rows. Double-buffered K/V prefetch (T3 minimum):
// issue next tile's K gload_lds + V reg-loads BEFORE computing current tile,
// V regs->LDS after compute, single barrier per tile. Q pre-scaled by 0.125 in RoPE.
__global__ __launch_bounds__(256) void attn_kernel(
    const __bf16* __restrict__ qkv, __bf16* __restrict__ o) {
  __shared__ __bf16 lsK[2][64 * 64];
  __shared__ __bf16 lsV[2][64 * 64];
  __shared__ __bf16 lsP[4][16 * 64];
  const int tid = threadIdx.x, lane = tid & 63, w = tid >> 6;
  const int hi = lane >> 4, lo = lane & 15;
  const int bx = gridDim.x - 1 - blockIdx.x;   // LPT: longest blocks first
  const int b = blockIdx.z, h = blockIdx.y, q0 = bx * 64;
  const int qw = q0 + w * 16;
  const long base  = (long)b * 2048 * 3072 + h * 64;
  const long obase = (long)b * 2048 * 1024 + h * 64;
  const __bf16* q    = qkv;
  const __bf16* kmat = qkv + 1024;
  const __bf16* v    = qkv + 2048;

  // staging geometry (same lane maps as the R6-passing kernel)
  const int ks_row = (lane >> 3);
  const int ks_scol = (((lane & 7) ^ (lane >> 3)) * 8);
  const int vs_key = tid >> 2, vs_db = (tid & 3) * 16;

  // Q fragments in registers (already scaled by 0.125)
  bf16x8 aq[2];
#pragma unroll
  for (int kk = 0; kk < 2; ++kk)
    aq[kk] = *(const bf16x8*)&q[base + (long)(qw + lo) * 3072 + kk * 32 + 8 * hi];

  const f32x4 fz = {0.f, 0.f, 0.f, 0.f};
  f32x4 oacc[4];
  float mrun[4], lrun[4];
#pragma unroll
  for (int ni = 0; ni < 4; ++ni) oacc[ni] = fz;
#pragma unroll
  for (int r = 0; r < 4; ++r) { mrun[r] = -1e30f; lrun[r] = 0.f; }

  const int nkt = bx + 1;

  // ---- prologue: stage tile 0 into buffer 0
  bf16x8 pv0, pv1;
  {
#pragma unroll
    for (int p = 0; p < 2; ++p) {
      const int seg = p * 4 + w;
      gload16(kmat + base + (long)(seg * 8 + ks_row) * 3072 + ks_scol,
              (char*)lsK[0] + seg * 1024);
    }
    const long gv = base + (long)vs_key * 3072 + vs_db;
    pv0 = *(const bf16x8*)&v[gv];
    pv1 = *(const bf16x8*)&v[gv + 8];
    char* lv = (char*)lsV[0];
#pragma unroll
    for (int j = 0; j < 8; ++j) {
      const int d0 = vs_db + j, d1 = vs_db + 8 + j;
      *(__bf16*)(lv + d0 * 128 + ((vs_key * 2) ^ ((d0 & 7) << 4) ^ (((d0 >> 4) & 3) << 5))) = pv0[j];
      *(__bf16*)(lv + d1 * 128 + ((vs_key * 2) ^ ((d1 & 7) << 4) ^ (((d1 >> 4) & 3) << 5))) = pv1[j];
    }
  }
  __syncthreads();

  for (int kt = 0; kt < nkt; ++kt) {
    const int cur = kt & 1;
    const bool more = (kt + 1 < nkt);

    // ---- issue next tile's loads (K direct to LDS buf^1, V to regs)
    if (more) {
#pragma unroll
      for (int p = 0; p < 2; ++p) {
        const int seg = p * 4 + w;
        gload16(kmat + base + (long)((kt + 1) * 64 + seg * 8 + ks_row) * 3072 + ks_scol,
                (char*)lsK[cur ^ 1] + seg * 1024);
      }
      const long gv = base + (long)((kt + 1) * 64 + vs_key) * 3072 + vs_db;
      pv0 = *(const bf16x8*)&v[gv];
      pv1 = *(const bf16x8*)&v[gv + 8];
    }

    // ---- S = Q K^T  (swizzled K reads from buf cur)
    f32x4 sacc[4];
#pragma unroll
    for (int ni = 0; ni < 4; ++ni) sacc[ni] = fz;
#pragma unroll
    for (int kk = 0; kk < 2; ++kk) {
      bf16x8 bk[4];
#pragma unroll
      for (int ni = 0; ni < 4; ++ni) {
        const int row = ni * 16 + lo;
        bk[ni] = *(const bf16x8*)((char*)lsK[cur] + row * 128 +
                                  ((kk * 64 + 16 * hi) ^ ((row & 7) << 4)));
      }
#pragma unroll
      for (int ni = 0; ni < 4; ++ni)
        sacc[ni] = MFMA16(aq[kk], bk[ni], sacc[ni]);
    }

    // ---- online softmax (wave-parallel, 16-lane row groups)
#pragma unroll
    for (int r = 0; r < 4; ++r) {
      const int row_g = qw + hi * 4 + r;
      const int prow = hi * 4 + r;
      float sv[4];
      float mx = -3.0e38f;
#pragma unroll
      for (int ni = 0; ni < 4; ++ni) {
        const int key_g = kt * 64 + ni * 16 + lo;
        float s = sacc[ni][r];
        if (key_g > row_g) s = -1e9f;
        sv[ni] = s;
        mx = fmaxf(mx, s);
      }
#pragma unroll
      for (int d = 1; d < 16; d <<= 1) mx = fmaxf(mx, __shfl_xor(mx, d));
      const float mold = mrun[r];
      const float mnew = fmaxf(mold, mx);
      const float fac = __expf(mold - mnew);
      float sum = 0.f;
#pragma unroll
      for (int ni = 0; ni < 4; ++ni) {
        const float pp = __expf(sv[ni] - mnew);
        sum += pp;
        *(__bf16*)((char*)lsP[w] + prow * 128 +
                   (((ni * 16 + lo) * 2) ^ ((prow & 7) << 4))) = (__bf16)pp;
      }
#pragma unroll
      for (int d = 1; d < 16; d <<= 1) sum += __shfl_xor(sum, d);
      mrun[r] = mnew;
      lrun[r] = lrun[r] * fac + sum;
#pragma unroll
      for (int ni = 0; ni < 4; ++ni) oacc[ni][r] *= fac;
    }
    // no barrier: lsP is wave-private, DS ops are wave-ordered

    // ---- O += P V  (swizzled P and V reads from buf cur)
#pragma unroll
    for (int kk = 0; kk < 2; ++kk) {
      bf16x8 ap, bv[4];
      ap = *(const bf16x8*)((char*)lsP[w] + lo * 128 +
                            ((kk * 64 + 16 * hi) ^ ((lo & 7) << 4)));
#pragma unroll
      for (int ni = 0; ni < 4; ++ni) {
        const int d = ni * 16 + lo;
        bv[ni] = *(const bf16x8*)((char*)lsV[cur] + d * 128 +
                                  ((kk * 64 + 16 * hi) ^ ((d & 7) << 4) ^ (((d >> 4) & 3) << 5)));
      }
#pragma unroll
      for (int ni = 0; ni < 4; ++ni)
        oacc[ni] = MFMA16(ap, bv[ni], oacc[ni]);
    }

    // ---- write prefetched V into buf^1, then the single per-tile barrier
    if (more) {
      char* lv = (char*)lsV[cur ^ 1];
#pragma unroll
      for (int j = 0; j < 8; ++j) {
        const int d0 = vs_db + j, d1 = vs_db + 8 + j;
        *(__bf16*)(lv + d0 * 128 + ((vs_key * 2) ^ ((d0 & 7) << 4) ^ (((d0 >> 4) & 3) << 5))) = pv0[j];
        *(__bf16*)(lv + d1 * 128 + ((vs_key * 2) ^ ((d1 & 7) << 4) ^ (((d1 >> 4) & 3) << 5))) = pv1[j];
      }
    }
    __syncthreads();
  }

  // epilogue
#pragma unroll
  for (int ni = 0; ni < 4; ++ni)
#pragma unroll
    for (int r = 0; r < 4; ++r) {
      const int row_g = qw + hi * 4 + r;
      o[obase + (long)row_g * 1024 + ni * 16 + lo] = (__bf16)(oacc[ni][r] / lrun[r]);
    }
}

// ---------------------------------------------------------------- launcher
extern "C" void kernel_launch(void* const* d_in, const int* in_sizes, int n_in,
                              void* d_out, int out_size, void* d_ws, size_t ws_size,
                              hipStream_t stream) {
  const float* x    = (const float*)d_in[0];
  const float* fr   = (const float*)d_in[1];
  const float* ln1g = (const float*)d_in[3];
  const float* ln1b = (const float*)d_in[4];
  const float* Wq   = (const float*)d_in[5];
  const float* bq   = (const float*)d_in[6];
  const float* Wk   = (const float*)d_in[7];
  const float* bk   = (const float*)d_in[8];
  const float* Wv   = (const float*)d_in[9];
  const float* bv   = (const float*)d_in[10];
  const float* Wo   = (const float*)d_in[11];
  const float* bo   = (const float*)d_in[12];
  const float* ln2g = (const float*)d_in[13];
  const float* ln2b = (const float*)d_in[14];
  const float* W1   = (const float*)d_in[15];
  const float* b1   = (const float*)d_in[16];
  const float* W2   = (const float*)d_in[17];
  const float* b2   = (const float*)d_in[18];
  float* out = (float*)d_out;

  char* ws = (char*)d_ws;
  const size_t SZ = 8388608;  // 8 MB
  __bf16* xn   = (__bf16*)(ws + 0);              // 8 MB
  __bf16* qkv  = (__bf16*)(ws + 1 * SZ);         // 24 MB (8..32)
  __bf16* attn = (__bf16*)(ws + 0);              // reuse xn
  float*  bqkv = (float*)(ws + 4 * SZ);          // 12 KB, dead before x2 written
  float*  x2   = (float*)(ws + 4 * SZ);          // 16 MB f32 (32..48)
  __bf16* hin  = (__bf16*)(ws + 6 * SZ);         // 8 MB (48..56)
  __bf16* hmid = (__bf16*)(ws + 0);              // 32 MB (0..32), qkv/attn dead
  char* wb = ws + 7 * SZ;                        // bf16 weights, 24 MB (56..80), contiguous
  __bf16* Wqkvb = (__bf16*)(wb + 0);             // 6 MB: Wq|Wk|Wv packed along N
  __bf16* Wob   = (__bf16*)(wb + 6 * 1048576);
  __bf16* W1b   = (__bf16*)(wb + 8 * 1048576);
  __bf16* W2b   = (__bf16*)(wb + 16 * 1048576);

  const int M = 4096, D = 1024, FF = 4096;
  dim3 blk(256);

  cvt6_kernel<<<6144, blk, 0, stream>>>(Wq, Wk, Wv, Wo, W1, W2, Wqkvb);
  pack3_kernel<<<12, blk, 0, stream>>>(bq, bk, bv, bqkv);

  ln_kernel<<<4096, blk, 0, stream>>>(x, ln1g, ln1b, xn);
  gemm_bt<EPI_NONE, __bf16><<<dim3(3072 / 128, M / 128), blk, 0, stream>>>(
      xn, Wqkvb, bqkv, nullptr, qkv, M, 3072, D);
  rope_kernel<<<dim3(2048, 2), blk, 0, stream>>>(qkv, fr);
  attn_kernel<<<dim3(32, 16, 2), blk, 0, stream>>>(qkv, attn);
  gemm_bt<EPI_RES, float><<<dim3(D / 128, M / 128), blk, 0, stream>>>(
      attn, Wob, bo, x, x2, M, D, D);
  ln_kernel<<<4096, blk, 0, stream>>>(x2, ln2g, ln2b, hin);
  gemm_bt<EPI_GELU, __bf16><<<dim3(FF / 128, M / 128), blk, 0, stream>>>(
      hin, W1b, b1, nullptr, hmid, M, FF, D);
  gemm_bt<EPI_RES, float><<<dim3(D / 128, M / 128), blk, 0, stream>>>(
      hmid, W2b, b2, x2, out, M, D, FF);
}

// Round 8
// 334.912 us; speedup vs baseline: 1.3679x; 1.1442x over previous
//
#include <hip/hip_runtime.h>
#include <hip/hip_bf16.h>

typedef __bf16 bf16x8 __attribute__((ext_vector_type(8)));
typedef __bf16 bf16x4 __attribute__((ext_vector_type(4)));
typedef float  f32x4  __attribute__((ext_vector_type(4)));

#define MFMA16(a, b, c) __builtin_amdgcn_mfma_f32_16x16x32_bf16((a), (b), (c), 0, 0, 0)

__device__ __forceinline__ void gload16(const void* g, void* l) {
  __builtin_amdgcn_global_load_lds(
      (const __attribute__((address_space(1))) unsigned int*)g,
      (__attribute__((address_space(3))) unsigned int*)l, 16, 0, 0);
}

// ---------------------------------------------------------------- f32 -> bf16 pack, all 6 weights in one launch
__global__ __launch_bounds__(256) void cvt6_kernel(
    const float* __restrict__ wq, const float* __restrict__ wk,
    const float* __restrict__ wv, const float* __restrict__ wo,
    const float* __restrict__ w1, const float* __restrict__ w2,
    __bf16* __restrict__ dst) {
  const long i = ((long)blockIdx.x * 256 + threadIdx.x) * 8;  // [0, 12M)
  const long M1 = 1048576;
  const float* src;
  long off;
  if      (i < 1 * M1) { src = wq; off = i; }
  else if (i < 2 * M1) { src = wk; off = i - 1 * M1; }
  else if (i < 3 * M1) { src = wv; off = i - 2 * M1; }
  else if (i < 4 * M1) { src = wo; off = i - 3 * M1; }
  else if (i < 8 * M1) { src = w1; off = i - 4 * M1; }
  else                 { src = w2; off = i - 8 * M1; }
  float4 a = *(const float4*)&src[off];
  float4 b = *(const float4*)&src[off + 4];
  bf16x8 o;
  o[0] = (__bf16)a.x; o[1] = (__bf16)a.y; o[2] = (__bf16)a.z; o[3] = (__bf16)a.w;
  o[4] = (__bf16)b.x; o[5] = (__bf16)b.y; o[6] = (__bf16)b.z; o[7] = (__bf16)b.w;
  *(bf16x8*)&dst[i] = o;
}

// pack 3 bias vectors (1024 each) into one f32[3072]
__global__ __launch_bounds__(256) void pack3_kernel(
    const float* __restrict__ a, const float* __restrict__ b,
    const float* __restrict__ c, float* __restrict__ o) {
  const int i = blockIdx.x * 256 + threadIdx.x;
  o[i] = i < 1024 ? a[i] : (i < 2048 ? b[i - 1024] : c[i - 2048]);
}

// ---------------------------------------------------------------- LayerNorm (f32 in -> bf16 out)
__global__ __launch_bounds__(256) void ln_kernel(
    const float* __restrict__ in, const float* __restrict__ gg,
    const float* __restrict__ bb, __bf16* __restrict__ out) {
  __shared__ float sred[8];
  const long row = blockIdx.x;
  const int tid = threadIdx.x;
  float4 u = *(const float4*)&in[row * 1024 + tid * 4];
  float f[4] = {u.x, u.y, u.z, u.w};
  float s = 0.f, sq = 0.f;
#pragma unroll
  for (int j = 0; j < 4; ++j) { s += f[j]; sq += f[j] * f[j]; }
#pragma unroll
  for (int d = 32; d; d >>= 1) { s += __shfl_xor(s, d); sq += __shfl_xor(sq, d); }
  const int w = tid >> 6;
  if ((tid & 63) == 0) { sred[w * 2] = s; sred[w * 2 + 1] = sq; }
  __syncthreads();
  s  = sred[0] + sred[2] + sred[4] + sred[6];
  sq = sred[1] + sred[3] + sred[5] + sred[7];
  const float mean = s * (1.f / 1024.f);
  const float var  = sq * (1.f / 1024.f) - mean * mean;
  const float rstd = rsqrtf(var + 1e-5f);
  float4 gv = *(const float4*)&gg[tid * 4];
  float4 bv = *(const float4*)&bb[tid * 4];
  bf16x4 ov;
  ov[0] = (__bf16)((f[0] - mean) * rstd * gv.x + bv.x);
  ov[1] = (__bf16)((f[1] - mean) * rstd * gv.y + bv.y);
  ov[2] = (__bf16)((f[2] - mean) * rstd * gv.z + bv.z);
  ov[3] = (__bf16)((f[3] - mean) * rstd * gv.w + bv.w);
  *(bf16x4*)&out[row * 1024 + tid * 4] = ov;
}

// ---------------------------------------------------------------- RoPE (in place on packed qkv, LD=3072), bf16x8
// blockIdx.y==0 -> q (scaled by 0.125, exact pow2 fold of 1/sqrt(HD)); y==1 -> k.
__global__ __launch_bounds__(256) void rope_kernel(
    __bf16* __restrict__ qkv, const float* __restrict__ freqs) {
  const int idx = blockIdx.x * 256 + threadIdx.x;   // [0, 4096*16*8)
  const int isq = (blockIdx.y == 0);
  __bf16* p = qkv + (isq ? 0 : 1024);
  const float scale = isq ? 0.125f : 1.0f;
  const int token = idx >> 7;
  const int wi = idx & 127;
  const int head = wi >> 3, i4 = wi & 7;
  const int spos = token & 2047;
  float4 fv = *(const float4*)&freqs[spos * 32 + i4 * 4];
  const long off = (long)token * 3072 + head * 64 + i4 * 8;
  bf16x8 u = *(bf16x8*)&p[off];
  float sn[4], cs[4];
  sincosf(fv.x, &sn[0], &cs[0]);
  sincosf(fv.y, &sn[1], &cs[1]);
  sincosf(fv.z, &sn[2], &cs[2]);
  sincosf(fv.w, &sn[3], &cs[3]);
  bf16x8 ov;
#pragma unroll
  for (int j = 0; j < 4; ++j) {
    const float x0 = (float)u[2 * j], x1 = (float)u[2 * j + 1];
    ov[2 * j]     = (__bf16)((x0 * cs[j] - x1 * sn[j]) * scale);
    ov[2 * j + 1] = (__bf16)((x1 * cs[j] + x0 * sn[j]) * scale);
  }
  *(bf16x8*)&p[off] = ov;
}

// ---------------------------------------------------------------- GEMM: out = act @ W^T + bias (+epilogue)
enum { EPI_NONE = 0, EPI_GELU = 1, EPI_RES = 2 };

template <int EPI, typename OT>
__global__ __launch_bounds__(256) void gemm_bt(
    const __bf16* __restrict__ A, const __bf16* __restrict__ W,
    const float* __restrict__ bias, const float* __restrict__ res,
    OT* __restrict__ out, int M, int N, int K) {
  __shared__ __bf16 lsA[128 * 64];
  __shared__ __bf16 lsB[128 * 64];
  const int tid = threadIdx.x, lane = tid & 63, w = tid >> 6;
  const int bm = blockIdx.y, bn = blockIdx.x;
  const int wm = w >> 1, wn = w & 1;
  const long Kl = K, Nl = N;
  const long a_row0 = (long)bm * 128, b_row0 = (long)bn * 128;
  const int pr_row = lane >> 3;
  const int pr_col = (lane & 7) * 8;

  f32x4 acc[4][4];
  const f32x4 fz = {0.f, 0.f, 0.f, 0.f};
#pragma unroll
  for (int i = 0; i < 4; ++i)
#pragma unroll
    for (int j = 0; j < 4; ++j) acc[i][j] = fz;

  for (int kt = 0; kt < K; kt += 64) {
#pragma unroll
    for (int p = 0; p < 4; ++p) {
      const int seg = p * 4 + w;
      const int row = seg * 8 + pr_row;
      gload16(A + (a_row0 + row) * Kl + kt + pr_col, (char*)lsA + seg * 1024);
      gload16(W + (b_row0 + row) * Kl + kt + pr_col, (char*)lsB + seg * 1024);
    }
    __syncthreads();
#pragma unroll
    for (int kk = 0; kk < 2; ++kk) {
      bf16x8 af[4], bfr[4];
#pragma unroll
      for (int i = 0; i < 4; ++i) {
        af[i]  = *(const bf16x8*)&lsA[(wm * 64 + i * 16 + (lane & 15)) * 64 + kk * 32 + 8 * (lane >> 4)];
        bfr[i] = *(const bf16x8*)&lsB[(wn * 64 + i * 16 + (lane & 15)) * 64 + kk * 32 + 8 * (lane >> 4)];
      }
#pragma unroll
      for (int mi = 0; mi < 4; ++mi)
#pragma unroll
        for (int ni = 0; ni < 4; ++ni)
          acc[mi][ni] = MFMA16(af[mi], bfr[ni], acc[mi][ni]);
    }
    __syncthreads();
  }

#pragma unroll
  for (int mi = 0; mi < 4; ++mi) {
#pragma unroll
    for (int ni = 0; ni < 4; ++ni) {
      const int col = bn * 128 + wn * 64 + ni * 16 + (lane & 15);
      const float bb = bias[col];
#pragma unroll
      for (int r = 0; r < 4; ++r) {
        const long row = a_row0 + wm * 64 + mi * 16 + (lane >> 4) * 4 + r;
        float vv = acc[mi][ni][r] + bb;
        if constexpr (EPI == EPI_GELU) vv = 0.5f * vv * (1.0f + erff(vv * 0.70710678f));
        if constexpr (EPI == EPI_RES) vv += res[row * Nl + col];
        out[row * Nl + col] = (OT)vv;
      }
    }
  }
}

// ---------------------------------------------------------------- Flash attention (causal), packed qkv LD=3072
// Causal pairing: block pi handles Q-tiles pi and 31-pi (work = 33 K-tiles, constant).
// Both Q-tiles share the staged K/V. grid (16, H, B), 4 waves x 16 q-rows per tile.
// Double-buffered K/V prefetch; Q pre-scaled by 0.125 in RoPE.
__global__ __launch_bounds__(256) void attn_kernel(
    const __bf16* __restrict__ qkv, __bf16* __restrict__ o) {
  __shared__ __bf16 lsK[2][64 * 64];
  __shared__ __bf16 lsV[2][64 * 64];
  __shared__ __bf16 lsP[4][16 * 64];
  const int tid = threadIdx.x, lane = tid & 63, w = tid >> 6;
  const int hi = lane >> 4, lo = lane & 15;
  const int pi = blockIdx.x;                  // 0..15
  const int qtL = pi, qtH = 31 - pi;
  const int b = blockIdx.z, h = blockIdx.y;
  const int qwL = qtL * 64 + w * 16;
  const int qwH = qtH * 64 + w * 16;
  const long base  = (long)b * 2048 * 3072 + h * 64;
  const long obase = (long)b * 2048 * 1024 + h * 64;
  const __bf16* q    = qkv;
  const __bf16* kmat = qkv + 1024;
  const __bf16* v    = qkv + 2048;

  // staging geometry
  const int ks_row = (lane >> 3);
  const int ks_scol = (((lane & 7) ^ (lane >> 3)) * 8);
  const int vs_key = tid >> 2, vs_db = (tid & 3) * 16;

  // Q fragments (already scaled by 0.125)
  bf16x8 aqL[2], aqH[2];
#pragma unroll
  for (int kk = 0; kk < 2; ++kk) {
    aqL[kk] = *(const bf16x8*)&q[base + (long)(qwL + lo) * 3072 + kk * 32 + 8 * hi];
    aqH[kk] = *(const bf16x8*)&q[base + (long)(qwH + lo) * 3072 + kk * 32 + 8 * hi];
  }

  const f32x4 fz = {0.f, 0.f, 0.f, 0.f};
  f32x4 oaccL[4], oaccH[4];
  float mrunL[4], lrunL[4], mrunH[4], lrunH[4];
#pragma unroll
  for (int ni = 0; ni < 4; ++ni) { oaccL[ni] = fz; oaccH[ni] = fz; }
#pragma unroll
  for (int r = 0; r < 4; ++r) {
    mrunL[r] = -1e30f; lrunL[r] = 0.f;
    mrunH[r] = -1e30f; lrunH[r] = 0.f;
  }

  const int nkt = qtH + 1;   // = 32 - pi

  // ---- prologue: stage tile 0 into buffer 0
  bf16x8 pv0, pv1;
  {
#pragma unroll
    for (int p = 0; p < 2; ++p) {
      const int seg = p * 4 + w;
      gload16(kmat + base + (long)(seg * 8 + ks_row) * 3072 + ks_scol,
              (char*)lsK[0] + seg * 1024);
    }
    const long gv = base + (long)vs_key * 3072 + vs_db;
    pv0 = *(const bf16x8*)&v[gv];
    pv1 = *(const bf16x8*)&v[gv + 8];
    char* lv = (char*)lsV[0];
#pragma unroll
    for (int j = 0; j < 8; ++j) {
      const int d0 = vs_db + j, d1 = vs_db + 8 + j;
      *(__bf16*)(lv + d0 * 128 + ((vs_key * 2) ^ ((d0 & 7) << 4) ^ (((d0 >> 4) & 3) << 5))) = pv0[j];
      *(__bf16*)(lv + d1 * 128 + ((vs_key * 2) ^ ((d1 & 7) << 4) ^ (((d1 >> 4) & 3) << 5))) = pv1[j];
    }
  }
  __syncthreads();

  // per-Q-tile compute for one staged K/V tile (identical numerics to R7)
  auto process = [&](const bf16x8 (&aq)[2], f32x4 (&oacc)[4], float (&mrun)[4],
                     float (&lrun)[4], const int qw, const int kt, const int cur) {
    // S = Q K^T  (swizzled K reads)
    f32x4 sacc[4];
#pragma unroll
    for (int ni = 0; ni < 4; ++ni) sacc[ni] = fz;
#pragma unroll
    for (int kk = 0; kk < 2; ++kk) {
      bf16x8 bk[4];
#pragma unroll
      for (int ni = 0; ni < 4; ++ni) {
        const int row = ni * 16 + lo;
        bk[ni] = *(const bf16x8*)((char*)lsK[cur] + row * 128 +
                                  ((kk * 64 + 16 * hi) ^ ((row & 7) << 4)));
      }
#pragma unroll
      for (int ni = 0; ni < 4; ++ni)
        sacc[ni] = MFMA16(aq[kk], bk[ni], sacc[ni]);
    }

    // online softmax (wave-parallel, 16-lane row groups)
#pragma unroll
    for (int r = 0; r < 4; ++r) {
      const int row_g = qw + hi * 4 + r;
      const int prow = hi * 4 + r;
      float sv[4];
      float mx = -3.0e38f;
#pragma unroll
      for (int ni = 0; ni < 4; ++ni) {
        const int key_g = kt * 64 + ni * 16 + lo;
        float s = sacc[ni][r];
        if (key_g > row_g) s = -1e9f;
        sv[ni] = s;
        mx = fmaxf(mx, s);
      }
#pragma unroll
      for (int d = 1; d < 16; d <<= 1) mx = fmaxf(mx, __shfl_xor(mx, d));
      const float mold = mrun[r];
      const float mnew = fmaxf(mold, mx);
      const float fac = __expf(mold - mnew);
      float sum = 0.f;
#pragma unroll
      for (int ni = 0; ni < 4; ++ni) {
        const float pp = __expf(sv[ni] - mnew);
        sum += pp;
        *(__bf16*)((char*)lsP[w] + prow * 128 +
                   (((ni * 16 + lo) * 2) ^ ((prow & 7) << 4))) = (__bf16)pp;
      }
#pragma unroll
      for (int d = 1; d < 16; d <<= 1) sum += __shfl_xor(sum, d);
      mrun[r] = mnew;
      lrun[r] = lrun[r] * fac + sum;
#pragma unroll
      for (int ni = 0; ni < 4; ++ni) oacc[ni][r] *= fac;
    }
    // no barrier: lsP is wave-private, DS ops are wave-ordered

    // O += P V  (swizzled P and V reads)
#pragma unroll
    for (int kk = 0; kk < 2; ++kk) {
      bf16x8 ap, bv[4];
      ap = *(const bf16x8*)((char*)lsP[w] + lo * 128 +
                            ((kk * 64 + 16 * hi) ^ ((lo & 7) << 4)));
#pragma unroll
      for (int ni = 0; ni < 4; ++ni) {
        const int d = ni * 16 + lo;
        bv[ni] = *(const bf16x8*)((char*)lsV[cur] + d * 128 +
                                  ((kk * 64 + 16 * hi) ^ ((d & 7) << 4) ^ (((d >> 4) & 3) << 5)));
      }
#pragma unroll
      for (int ni = 0; ni < 4; ++ni)
        oacc[ni] = MFMA16(ap, bv[ni], oacc[ni]);
    }
  };

  for (int kt = 0; kt < nkt; ++kt) {
    const int cur = kt & 1;
    const bool more = (kt + 1 < nkt);

    // issue next tile's loads (K direct to LDS buf^1, V to regs)
    if (more) {
#pragma unroll
      for (int p = 0; p < 2; ++p) {
        const int seg = p * 4 + w;
        gload16(kmat + base + (long)((kt + 1) * 64 + seg * 8 + ks_row) * 3072 + ks_scol,
                (char*)lsK[cur ^ 1] + seg * 1024);
      }
      const long gv = base + (long)((kt + 1) * 64 + vs_key) * 3072 + vs_db;
      pv0 = *(const bf16x8*)&v[gv];
      pv1 = *(const bf16x8*)&v[gv + 8];
    }

    // high Q-tile always; low Q-tile while kt <= qtL (block-uniform branch)
    process(aqH, oaccH, mrunH, lrunH, qwH, kt, cur);
    if (kt <= qtL) process(aqL, oaccL, mrunL, lrunL, qwL, kt, cur);

    // write prefetched V into buf^1, then the single per-tile barrier
    if (more) {
      char* lv = (char*)lsV[cur ^ 1];
#pragma unroll
      for (int j = 0; j < 8; ++j) {
        const int d0 = vs_db + j, d1 = vs_db + 8 + j;
        *(__bf16*)(lv + d0 * 128 + ((vs_key * 2) ^ ((d0 & 7) << 4) ^ (((d0 >> 4) & 3) << 5))) = pv0[j];
        *(__bf16*)(lv + d1 * 128 + ((vs_key * 2) ^ ((d1 & 7) << 4) ^ (((d1 >> 4) & 3) << 5))) = pv1[j];
      }
    }
    __syncthreads();
  }

  // epilogue: both Q-tiles
#pragma unroll
  for (int ni = 0; ni < 4; ++ni)
#pragma unroll
    for (int r = 0; r < 4; ++r) {
      const int rowH = qwH + hi * 4 + r;
      const int rowL = qwL + hi * 4 + r;
      o[obase + (long)rowH * 1024 + ni * 16 + lo] = (__bf16)(oaccH[ni][r] / lrunH[r]);
      o[obase + (long)rowL * 1024 + ni * 16 + lo] = (__bf16)(oaccL[ni][r] / lrunL[r]);
    }
}

// ---------------------------------------------------------------- launcher
extern "C" void kernel_launch(void* const* d_in, const int* in_sizes, int n_in,
                              void* d_out, int out_size, void* d_ws, size_t ws_size,
                              hipStream_t stream) {
  const float* x    = (const float*)d_in[0];
  const float* fr   = (const float*)d_in[1];
  const float* ln1g = (const float*)d_in[3];
  const float* ln1b = (const float*)d_in[4];
  const float* Wq   = (const float*)d_in[5];
  const float* bq   = (const float*)d_in[6];
  const float* Wk   = (const float*)d_in[7];
  const float* bk   = (const float*)d_in[8];
  const float* Wv   = (const float*)d_in[9];
  const float* bv   = (const float*)d_in[10];
  const float* Wo   = (const float*)d_in[11];
  const float* bo   = (const float*)d_in[12];
  const float* ln2g = (const float*)d_in[13];
  const float* ln2b = (const float*)d_in[14];
  const float* W1   = (const float*)d_in[15];
  const float* b1   = (const float*)d_in[16];
  const float* W2   = (const float*)d_in[17];
  const float* b2   = (const float*)d_in[18];
  float* out = (float*)d_out;

  char* ws = (char*)d_ws;
  const size_t SZ = 8388608;  // 8 MB
  __bf16* xn   = (__bf16*)(ws + 0);              // 8 MB
  __bf16* qkv  = (__bf16*)(ws + 1 * SZ);         // 24 MB (8..32)
  __bf16* attn = (__bf16*)(ws + 0);              // reuse xn
  float*  bqkv = (float*)(ws + 4 * SZ);          // 12 KB, dead before x2 written
  float*  x2   = (float*)(ws + 4 * SZ);          // 16 MB f32 (32..48)
  __bf16* hin  = (__bf16*)(ws + 6 * SZ);         // 8 MB (48..56)
  __bf16* hmid = (__bf16*)(ws + 0);              // 32 MB (0..32), qkv/attn dead
  char* wb = ws + 7 * SZ;                        // bf16 weights, 24 MB (56..80), contiguous
  __bf16* Wqkvb = (__bf16*)(wb + 0);             // 6 MB: Wq|Wk|Wv packed along N
  __bf16* Wob   = (__bf16*)(wb + 6 * 1048576);
  __bf16* W1b   = (__bf16*)(wb + 8 * 1048576);
  __bf16* W2b   = (__bf16*)(wb + 16 * 1048576);

  const int M = 4096, D = 1024, FF = 4096;
  dim3 blk(256);

  cvt6_kernel<<<6144, blk, 0, stream>>>(Wq, Wk, Wv, Wo, W1, W2, Wqkvb);
  pack3_kernel<<<12, blk, 0, stream>>>(bq, bk, bv, bqkv);

  ln_kernel<<<4096, blk, 0, stream>>>(x, ln1g, ln1b, xn);
  gemm_bt<EPI_NONE, __bf16><<<dim3(3072 / 128, M / 128), blk, 0, stream>>>(
      xn, Wqkvb, bqkv, nullptr, qkv, M, 3072, D);
  rope_kernel<<<dim3(2048, 2), blk, 0, stream>>>(qkv, fr);
  attn_kernel<<<dim3(16, 16, 2), blk, 0, stream>>>(qkv, attn);
  gemm_bt<EPI_RES, float><<<dim3(D / 128, M / 128), blk, 0, stream>>>(
      attn, Wob, bo, x, x2, M, D, D);
  ln_kernel<<<4096, blk, 0, stream>>>(x2, ln2g, ln2b, hin);
  gemm_bt<EPI_GELU, __bf16><<<dim3(FF / 128, M / 128), blk, 0, stream>>>(
      hin, W1b, b1, nullptr, hmid, M, FF, D);
  gemm_bt<EPI_RES, float><<<dim3(D / 128, M / 128), blk, 0, stream>>>(
      hmid, W2b, b2, x2, out, M, D, FF);
}

// Round 9
// 317.571 us; speedup vs baseline: 1.4425x; 1.0546x over previous
//
#include <hip/hip_runtime.h>
#include <hip/hip_bf16.h>

typedef __bf16 bf16x8 __attribute__((ext_vector_type(8)));
typedef __bf16 bf16x4 __attribute__((ext_vector_type(4)));
typedef float  f32x4  __attribute__((ext_vector_type(4)));

#define MFMA16(a, b, c) __builtin_amdgcn_mfma_f32_16x16x32_bf16((a), (b), (c), 0, 0, 0)

__device__ __forceinline__ void gload16(const void* g, void* l) {
  __builtin_amdgcn_global_load_lds(
      (const __attribute__((address_space(1))) unsigned int*)g,
      (__attribute__((address_space(3))) unsigned int*)l, 16, 0, 0);
}

// ---------------------------------------------------------------- f32 -> bf16 pack, all 6 weights in one launch
__global__ __launch_bounds__(256) void cvt6_kernel(
    const float* __restrict__ wq, const float* __restrict__ wk,
    const float* __restrict__ wv, const float* __restrict__ wo,
    const float* __restrict__ w1, const float* __restrict__ w2,
    __bf16* __restrict__ dst) {
  const long i = ((long)blockIdx.x * 256 + threadIdx.x) * 8;  // [0, 12M)
  const long M1 = 1048576;
  const float* src;
  long off;
  if      (i < 1 * M1) { src = wq; off = i; }
  else if (i < 2 * M1) { src = wk; off = i - 1 * M1; }
  else if (i < 3 * M1) { src = wv; off = i - 2 * M1; }
  else if (i < 4 * M1) { src = wo; off = i - 3 * M1; }
  else if (i < 8 * M1) { src = w1; off = i - 4 * M1; }
  else                 { src = w2; off = i - 8 * M1; }
  float4 a = *(const float4*)&src[off];
  float4 b = *(const float4*)&src[off + 4];
  bf16x8 o;
  o[0] = (__bf16)a.x; o[1] = (__bf16)a.y; o[2] = (__bf16)a.z; o[3] = (__bf16)a.w;
  o[4] = (__bf16)b.x; o[5] = (__bf16)b.y; o[6] = (__bf16)b.z; o[7] = (__bf16)b.w;
  *(bf16x8*)&dst[i] = o;
}

// pack 3 bias vectors (1024 each) into one f32[3072]
__global__ __launch_bounds__(256) void pack3_kernel(
    const float* __restrict__ a, const float* __restrict__ b,
    const float* __restrict__ c, float* __restrict__ o) {
  const int i = blockIdx.x * 256 + threadIdx.x;
  o[i] = i < 1024 ? a[i] : (i < 2048 ? b[i - 1024] : c[i - 2048]);
}

// ---------------------------------------------------------------- LayerNorm (f32 in -> bf16 out)
__global__ __launch_bounds__(256) void ln_kernel(
    const float* __restrict__ in, const float* __restrict__ gg,
    const float* __restrict__ bb, __bf16* __restrict__ out) {
  __shared__ float sred[8];
  const long row = blockIdx.x;
  const int tid = threadIdx.x;
  float4 u = *(const float4*)&in[row * 1024 + tid * 4];
  float f[4] = {u.x, u.y, u.z, u.w};
  float s = 0.f, sq = 0.f;
#pragma unroll
  for (int j = 0; j < 4; ++j) { s += f[j]; sq += f[j] * f[j]; }
#pragma unroll
  for (int d = 32; d; d >>= 1) { s += __shfl_xor(s, d); sq += __shfl_xor(sq, d); }
  const int w = tid >> 6;
  if ((tid & 63) == 0) { sred[w * 2] = s; sred[w * 2 + 1] = sq; }
  __syncthreads();
  s  = sred[0] + sred[2] + sred[4] + sred[6];
  sq = sred[1] + sred[3] + sred[5] + sred[7];
  const float mean = s * (1.f / 1024.f);
  const float var  = sq * (1.f / 1024.f) - mean * mean;
  const float rstd = rsqrtf(var + 1e-5f);
  float4 gv = *(const float4*)&gg[tid * 4];
  float4 bv = *(const float4*)&bb[tid * 4];
  bf16x4 ov;
  ov[0] = (__bf16)((f[0] - mean) * rstd * gv.x + bv.x);
  ov[1] = (__bf16)((f[1] - mean) * rstd * gv.y + bv.y);
  ov[2] = (__bf16)((f[2] - mean) * rstd * gv.z + bv.z);
  ov[3] = (__bf16)((f[3] - mean) * rstd * gv.w + bv.w);
  *(bf16x4*)&out[row * 1024 + tid * 4] = ov;
}

// ---------------------------------------------------------------- RoPE (in place on packed qkv, LD=3072), bf16x8
// blockIdx.y==0 -> q (scaled by 0.125, exact pow2 fold of 1/sqrt(HD)); y==1 -> k.
__global__ __launch_bounds__(256) void rope_kernel(
    __bf16* __restrict__ qkv, const float* __restrict__ freqs) {
  const int idx = blockIdx.x * 256 + threadIdx.x;   // [0, 4096*16*8)
  const int isq = (blockIdx.y == 0);
  __bf16* p = qkv + (isq ? 0 : 1024);
  const float scale = isq ? 0.125f : 1.0f;
  const int token = idx >> 7;
  const int wi = idx & 127;
  const int head = wi >> 3, i4 = wi & 7;
  const int spos = token & 2047;
  float4 fv = *(const float4*)&freqs[spos * 32 + i4 * 4];
  const long off = (long)token * 3072 + head * 64 + i4 * 8;
  bf16x8 u = *(bf16x8*)&p[off];
  float sn[4], cs[4];
  sincosf(fv.x, &sn[0], &cs[0]);
  sincosf(fv.y, &sn[1], &cs[1]);
  sincosf(fv.z, &sn[2], &cs[2]);
  sincosf(fv.w, &sn[3], &cs[3]);
  bf16x8 ov;
#pragma unroll
  for (int j = 0; j < 4; ++j) {
    const float x0 = (float)u[2 * j], x1 = (float)u[2 * j + 1];
    ov[2 * j]     = (__bf16)((x0 * cs[j] - x1 * sn[j]) * scale);
    ov[2 * j + 1] = (__bf16)((x1 * cs[j] + x0 * sn[j]) * scale);
  }
  *(bf16x8*)&p[off] = ov;
}

// ---------------------------------------------------------------- GEMM: out = act @ W^T + bias (+epilogue)
// BN=128: 4 waves as 2x2, wave owns 64x64 (acc[4][4]). BN=64: wave owns 64x32 (acc[4][2]).
enum { EPI_NONE = 0, EPI_GELU = 1, EPI_RES = 2 };

template <int EPI, typename OT, int BN>
__global__ __launch_bounds__(256) void gemm_bt(
    const __bf16* __restrict__ A, const __bf16* __restrict__ W,
    const float* __restrict__ bias, const float* __restrict__ res,
    OT* __restrict__ out, int M, int N, int K) {
  constexpr int NI = BN / 32;          // fragments per wave along N
  __shared__ __bf16 lsA[128 * 64];
  __shared__ __bf16 lsB[BN * 64];
  const int tid = threadIdx.x, lane = tid & 63, w = tid >> 6;
  const int bm = blockIdx.y, bn = blockIdx.x;
  const int wm = w >> 1, wn = w & 1;
  const long Kl = K, Nl = N;
  const long a_row0 = (long)bm * 128, b_row0 = (long)bn * BN;
  const int pr_row = lane >> 3;
  const int pr_col = (lane & 7) * 8;

  f32x4 acc[4][NI];
  const f32x4 fz = {0.f, 0.f, 0.f, 0.f};
#pragma unroll
  for (int i = 0; i < 4; ++i)
#pragma unroll
    for (int j = 0; j < NI; ++j) acc[i][j] = fz;

  for (int kt = 0; kt < K; kt += 64) {
#pragma unroll
    for (int p = 0; p < 4; ++p) {
      const int seg = p * 4 + w;
      const int row = seg * 8 + pr_row;
      gload16(A + (a_row0 + row) * Kl + kt + pr_col, (char*)lsA + seg * 1024);
    }
#pragma unroll
    for (int p = 0; p < BN / 32; ++p) {
      const int seg = p * 4 + w;
      const int row = seg * 8 + pr_row;
      gload16(W + (b_row0 + row) * Kl + kt + pr_col, (char*)lsB + seg * 1024);
    }
    __syncthreads();
#pragma unroll
    for (int kk = 0; kk < 2; ++kk) {
      bf16x8 af[4], bfr[NI];
#pragma unroll
      for (int i = 0; i < 4; ++i)
        af[i]  = *(const bf16x8*)&lsA[(wm * 64 + i * 16 + (lane & 15)) * 64 + kk * 32 + 8 * (lane >> 4)];
#pragma unroll
      for (int i = 0; i < NI; ++i)
        bfr[i] = *(const bf16x8*)&lsB[(wn * (BN / 2) + i * 16 + (lane & 15)) * 64 + kk * 32 + 8 * (lane >> 4)];
#pragma unroll
      for (int mi = 0; mi < 4; ++mi)
#pragma unroll
        for (int ni = 0; ni < NI; ++ni)
          acc[mi][ni] = MFMA16(af[mi], bfr[ni], acc[mi][ni]);
    }
    __syncthreads();
  }

#pragma unroll
  for (int mi = 0; mi < 4; ++mi) {
#pragma unroll
    for (int ni = 0; ni < NI; ++ni) {
      const int col = bn * BN + wn * (BN / 2) + ni * 16 + (lane & 15);
      const float bb = bias[col];
#pragma unroll
      for (int r = 0; r < 4; ++r) {
        const long row = a_row0 + wm * 64 + mi * 16 + (lane >> 4) * 4 + r;
        float vv = acc[mi][ni][r] + bb;
        if constexpr (EPI == EPI_GELU) vv = 0.5f * vv * (1.0f + erff(vv * 0.70710678f));
        if constexpr (EPI == EPI_RES) vv += res[row * Nl + col];
        out[row * Nl + col] = (OT)vv;
      }
    }
  }
}

// ---------------------------------------------------------------- Flash attention (causal), packed qkv LD=3072
// Causal pairing: block pi handles Q-tiles pi and 31-pi (work = 33 K-tiles, constant).
// Both Q-tiles share the staged K/V. grid (16, H, B), 4 waves x 16 q-rows per tile.
// Double-buffered K/V prefetch; Q pre-scaled by 0.125 in RoPE.
__global__ __launch_bounds__(256) void attn_kernel(
    const __bf16* __restrict__ qkv, __bf16* __restrict__ o) {
  __shared__ __bf16 lsK[2][64 * 64];
  __shared__ __bf16 lsV[2][64 * 64];
  __shared__ __bf16 lsP[4][16 * 64];
  const int tid = threadIdx.x, lane = tid & 63, w = tid >> 6;
  const int hi = lane >> 4, lo = lane & 15;
  const int pi = blockIdx.x;                  // 0..15
  const int qtL = pi, qtH = 31 - pi;
  const int b = blockIdx.z, h = blockIdx.y;
  const int qwL = qtL * 64 + w * 16;
  const int qwH = qtH * 64 + w * 16;
  const long base  = (long)b * 2048 * 3072 + h * 64;
  const long obase = (long)b * 2048 * 1024 + h * 64;
  const __bf16* q    = qkv;
  const __bf16* kmat = qkv + 1024;
  const __bf16* v    = qkv + 2048;

  // staging geometry
  const int ks_row = (lane >> 3);
  const int ks_scol = (((lane & 7) ^ (lane >> 3)) * 8);
  const int vs_key = tid >> 2, vs_db = (tid & 3) * 16;

  // Q fragments (already scaled by 0.125)
  bf16x8 aqL[2], aqH[2];
#pragma unroll
  for (int kk = 0; kk < 2; ++kk) {
    aqL[kk] = *(const bf16x8*)&q[base + (long)(qwL + lo) * 3072 + kk * 32 + 8 * hi];
    aqH[kk] = *(const bf16x8*)&q[base + (long)(qwH + lo) * 3072 + kk * 32 + 8 * hi];
  }

  const f32x4 fz = {0.f, 0.f, 0.f, 0.f};
  f32x4 oaccL[4], oaccH[4];
  float mrunL[4], lrunL[4], mrunH[4], lrunH[4];
#pragma unroll
  for (int ni = 0; ni < 4; ++ni) { oaccL[ni] = fz; oaccH[ni] = fz; }
#pragma unroll
  for (int r = 0; r < 4; ++r) {
    mrunL[r] = -1e30f; lrunL[r] = 0.f;
    mrunH[r] = -1e30f; lrunH[r] = 0.f;
  }

  const int nkt = qtH + 1;   // = 32 - pi

  // ---- prologue: stage tile 0 into buffer 0
  bf16x8 pv0, pv1;
  {
#pragma unroll
    for (int p = 0; p < 2; ++p) {
      const int seg = p * 4 + w;
      gload16(kmat + base + (long)(seg * 8 + ks_row) * 3072 + ks_scol,
              (char*)lsK[0] + seg * 1024);
    }
    const long gv = base + (long)vs_key * 3072 + vs_db;
    pv0 = *(const bf16x8*)&v[gv];
    pv1 = *(const bf16x8*)&v[gv + 8];
    char* lv = (char*)lsV[0];
#pragma unroll
    for (int j = 0; j < 8; ++j) {
      const int d0 = vs_db + j, d1 = vs_db + 8 + j;
      *(__bf16*)(lv + d0 * 128 + ((vs_key * 2) ^ ((d0 & 7) << 4) ^ (((d0 >> 4) & 3) << 5))) = pv0[j];
      *(__bf16*)(lv + d1 * 128 + ((vs_key * 2) ^ ((d1 & 7) << 4) ^ (((d1 >> 4) & 3) << 5))) = pv1[j];
    }
  }
  __syncthreads();

  // per-Q-tile compute for one staged K/V tile
  auto process = [&](const bf16x8 (&aq)[2], f32x4 (&oacc)[4], float (&mrun)[4],
                     float (&lrun)[4], const int qw, const int kt, const int cur) {
    // S = Q K^T  (swizzled K reads)
    f32x4 sacc[4];
#pragma unroll
    for (int ni = 0; ni < 4; ++ni) sacc[ni] = fz;
#pragma unroll
    for (int kk = 0; kk < 2; ++kk) {
      bf16x8 bk[4];
#pragma unroll
      for (int ni = 0; ni < 4; ++ni) {
        const int row = ni * 16 + lo;
        bk[ni] = *(const bf16x8*)((char*)lsK[cur] + row * 128 +
                                  ((kk * 64 + 16 * hi) ^ ((row & 7) << 4)));
      }
#pragma unroll
      for (int ni = 0; ni < 4; ++ni)
        sacc[ni] = MFMA16(aq[kk], bk[ni], sacc[ni]);
    }

    // online softmax (wave-parallel, 16-lane row groups)
#pragma unroll
    for (int r = 0; r < 4; ++r) {
      const int row_g = qw + hi * 4 + r;
      const int prow = hi * 4 + r;
      float sv[4];
      float mx = -3.0e38f;
#pragma unroll
      for (int ni = 0; ni < 4; ++ni) {
        const int key_g = kt * 64 + ni * 16 + lo;
        float s = sacc[ni][r];
        if (key_g > row_g) s = -1e9f;
        sv[ni] = s;
        mx = fmaxf(mx, s);
      }
#pragma unroll
      for (int d = 1; d < 16; d <<= 1) mx = fmaxf(mx, __shfl_xor(mx, d));
      const float mold = mrun[r];
      const float mnew = fmaxf(mold, mx);
      const float fac = __expf(mold - mnew);
      float sum = 0.f;
#pragma unroll
      for (int ni = 0; ni < 4; ++ni) {
        const float pp = __expf(sv[ni] - mnew);
        sum += pp;
        *(__bf16*)((char*)lsP[w] + prow * 128 +
                   (((ni * 16 + lo) * 2) ^ ((prow & 7) << 4))) = (__bf16)pp;
      }
#pragma unroll
      for (int d = 1; d < 16; d <<= 1) sum += __shfl_xor(sum, d);
      mrun[r] = mnew;
      lrun[r] = lrun[r] * fac + sum;
#pragma unroll
      for (int ni = 0; ni < 4; ++ni) oacc[ni][r] *= fac;
    }
    // no barrier: lsP is wave-private, DS ops are wave-ordered

    // O += P V  (swizzled P and V reads)
#pragma unroll
    for (int kk = 0; kk < 2; ++kk) {
      bf16x8 ap, bv[4];
      ap = *(const bf16x8*)((char*)lsP[w] + lo * 128 +
                            ((kk * 64 + 16 * hi) ^ ((lo & 7) << 4)));
#pragma unroll
      for (int ni = 0; ni < 4; ++ni) {
        const int d = ni * 16 + lo;
        bv[ni] = *(const bf16x8*)((char*)lsV[cur] + d * 128 +
                                  ((kk * 64 + 16 * hi) ^ ((d & 7) << 4) ^ (((d >> 4) & 3) << 5)));
      }
#pragma unroll
      for (int ni = 0; ni < 4; ++ni)
        oacc[ni] = MFMA16(ap, bv[ni], oacc[ni]);
    }
  };

  for (int kt = 0; kt < nkt; ++kt) {
    const int cur = kt & 1;
    const bool more = (kt + 1 < nkt);

    // issue next tile's loads (K direct to LDS buf^1, V to regs)
    if (more) {
#pragma unroll
      for (int p = 0; p < 2; ++p) {
        const int seg = p * 4 + w;
        gload16(kmat + base + (long)((kt + 1) * 64 + seg * 8 + ks_row) * 3072 + ks_scol,
                (char*)lsK[cur ^ 1] + seg * 1024);
      }
      const long gv = base + (long)((kt + 1) * 64 + vs_key) * 3072 + vs_db;
      pv0 = *(const bf16x8*)&v[gv];
      pv1 = *(const bf16x8*)&v[gv + 8];
    }

    // high Q-tile always; low Q-tile while kt <= qtL (block-uniform branch)
    process(aqH, oaccH, mrunH, lrunH, qwH, kt, cur);
    if (kt <= qtL) process(aqL, oaccL, mrunL, lrunL, qwL, kt, cur);

    // write prefetched V into buf^1, then the single per-tile barrier
    if (more) {
      char* lv = (char*)lsV[cur ^ 1];
#pragma unroll
      for (int j = 0; j < 8; ++j) {
        const int d0 = vs_db + j, d1 = vs_db + 8 + j;
        *(__bf16*)(lv + d0 * 128 + ((vs_key * 2) ^ ((d0 & 7) << 4) ^ (((d0 >> 4) & 3) << 5))) = pv0[j];
        *(__bf16*)(lv + d1 * 128 + ((vs_key * 2) ^ ((d1 & 7) << 4) ^ (((d1 >> 4) & 3) << 5))) = pv1[j];
      }
    }
    __syncthreads();
  }

  // epilogue: both Q-tiles
#pragma unroll
  for (int ni = 0; ni < 4; ++ni)
#pragma unroll
    for (int r = 0; r < 4; ++r) {
      const int rowH = qwH + hi * 4 + r;
      const int rowL = qwL + hi * 4 + r;
      o[obase + (long)rowH * 1024 + ni * 16 + lo] = (__bf16)(oaccH[ni][r] / lrunH[r]);
      o[obase + (long)rowL * 1024 + ni * 16 + lo] = (__bf16)(oaccL[ni][r] / lrunL[r]);
    }
}

// ---------------------------------------------------------------- launcher
extern "C" void kernel_launch(void* const* d_in, const int* in_sizes, int n_in,
                              void* d_out, int out_size, void* d_ws, size_t ws_size,
                              hipStream_t stream) {
  const float* x    = (const float*)d_in[0];
  const float* fr   = (const float*)d_in[1];
  const float* ln1g = (const float*)d_in[3];
  const float* ln1b = (const float*)d_in[4];
  const float* Wq   = (const float*)d_in[5];
  const float* bq   = (const float*)d_in[6];
  const float* Wk   = (const float*)d_in[7];
  const float* bk   = (const float*)d_in[8];
  const float* Wv   = (const float*)d_in[9];
  const float* bv   = (const float*)d_in[10];
  const float* Wo   = (const float*)d_in[11];
  const float* bo   = (const float*)d_in[12];
  const float* ln2g = (const float*)d_in[13];
  const float* ln2b = (const float*)d_in[14];
  const float* W1   = (const float*)d_in[15];
  const float* b1   = (const float*)d_in[16];
  const float* W2   = (const float*)d_in[17];
  const float* b2   = (const float*)d_in[18];
  float* out = (float*)d_out;

  char* ws = (char*)d_ws;
  const size_t SZ = 8388608;  // 8 MB
  __bf16* xn   = (__bf16*)(ws + 0);              // 8 MB
  __bf16* qkv  = (__bf16*)(ws + 1 * SZ);         // 24 MB (8..32)
  __bf16* attn = (__bf16*)(ws + 0);              // reuse xn
  float*  bqkv = (float*)(ws + 4 * SZ);          // 12 KB, dead before x2 written
  float*  x2   = (float*)(ws + 4 * SZ);          // 16 MB f32 (32..48)
  __bf16* hin  = (__bf16*)(ws + 6 * SZ);         // 8 MB (48..56)
  __bf16* hmid = (__bf16*)(ws + 0);              // 32 MB (0..32), qkv/attn dead
  char* wb = ws + 7 * SZ;                        // bf16 weights, 24 MB (56..80), contiguous
  __bf16* Wqkvb = (__bf16*)(wb + 0);             // 6 MB: Wq|Wk|Wv packed along N
  __bf16* Wob   = (__bf16*)(wb + 6 * 1048576);
  __bf16* W1b   = (__bf16*)(wb + 8 * 1048576);
  __bf16* W2b   = (__bf16*)(wb + 16 * 1048576);

  const int M = 4096, D = 1024, FF = 4096;
  dim3 blk(256);

  cvt6_kernel<<<6144, blk, 0, stream>>>(Wq, Wk, Wv, Wo, W1, W2, Wqkvb);
  pack3_kernel<<<12, blk, 0, stream>>>(bq, bk, bv, bqkv);

  ln_kernel<<<4096, blk, 0, stream>>>(x, ln1g, ln1b, xn);
  gemm_bt<EPI_NONE, __bf16, 128><<<dim3(3072 / 128, M / 128), blk, 0, stream>>>(
      xn, Wqkvb, bqkv, nullptr, qkv, M, 3072, D);
  rope_kernel<<<dim3(2048, 2), blk, 0, stream>>>(qkv, fr);
  attn_kernel<<<dim3(16, 16, 2), blk, 0, stream>>>(qkv, attn);
  gemm_bt<EPI_RES, float, 64><<<dim3(D / 64, M / 128), blk, 0, stream>>>(
      attn, Wob, bo, x, x2, M, D, D);
  ln_kernel<<<4096, blk, 0, stream>>>(x2, ln2g, ln2b, hin);
  gemm_bt<EPI_GELU, __bf16, 128><<<dim3(FF / 128, M / 128), blk, 0, stream>>>(
      hin, W1b, b1, nullptr, hmid, M, FF, D);
  gemm_bt<EPI_RES, float, 64><<<dim3(D / 64, M / 128), blk, 0, stream>>>(
      hmid, W2b, b2, x2, out, M, D, FF);
}

// Round 10
// 303.896 us; speedup vs baseline: 1.5075x; 1.0450x over previous
//
#include <hip/hip_runtime.h>
#include <hip/hip_bf16.h>

typedef __bf16 bf16x8 __attribute__((ext_vector_type(8)));
typedef __bf16 bf16x4 __attribute__((ext_vector_type(4)));
typedef float  f32x4  __attribute__((ext_vector_type(4)));

#define MFMA16(a, b, c) __builtin_amdgcn_mfma_f32_16x16x32_bf16((a), (b), (c), 0, 0, 0)

__device__ __forceinline__ void gload16(const void* g, void* l) {
  __builtin_amdgcn_global_load_lds(
      (const __attribute__((address_space(1))) unsigned int*)g,
      (__attribute__((address_space(3))) unsigned int*)l, 16, 0, 0);
}

// ---------------------------------------------------------------- f32 -> bf16 pack, all 6 weights in one launch
__global__ __launch_bounds__(256) void cvt6_kernel(
    const float* __restrict__ wq, const float* __restrict__ wk,
    const float* __restrict__ wv, const float* __restrict__ wo,
    const float* __restrict__ w1, const float* __restrict__ w2,
    __bf16* __restrict__ dst) {
  const long i = ((long)blockIdx.x * 256 + threadIdx.x) * 8;  // [0, 12M)
  const long M1 = 1048576;
  const float* src;
  long off;
  if      (i < 1 * M1) { src = wq; off = i; }
  else if (i < 2 * M1) { src = wk; off = i - 1 * M1; }
  else if (i < 3 * M1) { src = wv; off = i - 2 * M1; }
  else if (i < 4 * M1) { src = wo; off = i - 3 * M1; }
  else if (i < 8 * M1) { src = w1; off = i - 4 * M1; }
  else                 { src = w2; off = i - 8 * M1; }
  float4 a = *(const float4*)&src[off];
  float4 b = *(const float4*)&src[off + 4];
  bf16x8 o;
  o[0] = (__bf16)a.x; o[1] = (__bf16)a.y; o[2] = (__bf16)a.z; o[3] = (__bf16)a.w;
  o[4] = (__bf16)b.x; o[5] = (__bf16)b.y; o[6] = (__bf16)b.z; o[7] = (__bf16)b.w;
  *(bf16x8*)&dst[i] = o;
}

// pack 3 bias vectors (1024 each) into one f32[3072]
__global__ __launch_bounds__(256) void pack3_kernel(
    const float* __restrict__ a, const float* __restrict__ b,
    const float* __restrict__ c, float* __restrict__ o) {
  const int i = blockIdx.x * 256 + threadIdx.x;
  o[i] = i < 1024 ? a[i] : (i < 2048 ? b[i - 1024] : c[i - 2048]);
}

// ---------------------------------------------------------------- LayerNorm (f32 in -> bf16 out)
__global__ __launch_bounds__(256) void ln_kernel(
    const float* __restrict__ in, const float* __restrict__ gg,
    const float* __restrict__ bb, __bf16* __restrict__ out) {
  __shared__ float sred[8];
  const long row = blockIdx.x;
  const int tid = threadIdx.x;
  float4 u = *(const float4*)&in[row * 1024 + tid * 4];
  float f[4] = {u.x, u.y, u.z, u.w};
  float s = 0.f, sq = 0.f;
#pragma unroll
  for (int j = 0; j < 4; ++j) { s += f[j]; sq += f[j] * f[j]; }
#pragma unroll
  for (int d = 32; d; d >>= 1) { s += __shfl_xor(s, d); sq += __shfl_xor(sq, d); }
  const int w = tid >> 6;
  if ((tid & 63) == 0) { sred[w * 2] = s; sred[w * 2 + 1] = sq; }
  __syncthreads();
  s  = sred[0] + sred[2] + sred[4] + sred[6];
  sq = sred[1] + sred[3] + sred[5] + sred[7];
  const float mean = s * (1.f / 1024.f);
  const float var  = sq * (1.f / 1024.f) - mean * mean;
  const float rstd = rsqrtf(var + 1e-5f);
  float4 gv = *(const float4*)&gg[tid * 4];
  float4 bv = *(const float4*)&bb[tid * 4];
  bf16x4 ov;
  ov[0] = (__bf16)((f[0] - mean) * rstd * gv.x + bv.x);
  ov[1] = (__bf16)((f[1] - mean) * rstd * gv.y + bv.y);
  ov[2] = (__bf16)((f[2] - mean) * rstd * gv.z + bv.z);
  ov[3] = (__bf16)((f[3] - mean) * rstd * gv.w + bv.w);
  *(bf16x4*)&out[row * 1024 + tid * 4] = ov;
}

// ---------------------------------------------------------------- RoPE (in place on packed qkv, LD=3072), bf16x8
// blockIdx.y==0 -> q (scaled by 0.125, exact pow2 fold of 1/sqrt(HD)); y==1 -> k.
__global__ __launch_bounds__(256) void rope_kernel(
    __bf16* __restrict__ qkv, const float* __restrict__ freqs) {
  const int idx = blockIdx.x * 256 + threadIdx.x;   // [0, 4096*16*8)
  const int isq = (blockIdx.y == 0);
  __bf16* p = qkv + (isq ? 0 : 1024);
  const float scale = isq ? 0.125f : 1.0f;
  const int token = idx >> 7;
  const int wi = idx & 127;
  const int head = wi >> 3, i4 = wi & 7;
  const int spos = token & 2047;
  float4 fv = *(const float4*)&freqs[spos * 32 + i4 * 4];
  const long off = (long)token * 3072 + head * 64 + i4 * 8;
  bf16x8 u = *(bf16x8*)&p[off];
  float sn[4], cs[4];
  sincosf(fv.x, &sn[0], &cs[0]);
  sincosf(fv.y, &sn[1], &cs[1]);
  sincosf(fv.z, &sn[2], &cs[2]);
  sincosf(fv.w, &sn[3], &cs[3]);
  bf16x8 ov;
#pragma unroll
  for (int j = 0; j < 4; ++j) {
    const float x0 = (float)u[2 * j], x1 = (float)u[2 * j + 1];
    ov[2 * j]     = (__bf16)((x0 * cs[j] - x1 * sn[j]) * scale);
    ov[2 * j + 1] = (__bf16)((x1 * cs[j] + x0 * sn[j]) * scale);
  }
  *(bf16x8*)&p[off] = ov;
}

// ---------------------------------------------------------------- GEMM: out = act @ W^T + bias (+epilogue)
// BN=128: 4 waves as 2x2, wave owns 64x64 (acc[4][4]). BN=64: wave owns 64x32 (acc[4][2]).
enum { EPI_NONE = 0, EPI_GELU = 1, EPI_RES = 2 };

template <int EPI, typename OT, int BN>
__global__ __launch_bounds__(256) void gemm_bt(
    const __bf16* __restrict__ A, const __bf16* __restrict__ W,
    const float* __restrict__ bias, const float* __restrict__ res,
    OT* __restrict__ out, int M, int N, int K) {
  constexpr int NI = BN / 32;          // fragments per wave along N
  __shared__ __bf16 lsA[128 * 64];
  __shared__ __bf16 lsB[BN * 64];
  const int tid = threadIdx.x, lane = tid & 63, w = tid >> 6;
  const int bm = blockIdx.y, bn = blockIdx.x;
  const int wm = w >> 1, wn = w & 1;
  const long Kl = K, Nl = N;
  const long a_row0 = (long)bm * 128, b_row0 = (long)bn * BN;
  const int pr_row = lane >> 3;
  const int pr_col = (lane & 7) * 8;

  f32x4 acc[4][NI];
  const f32x4 fz = {0.f, 0.f, 0.f, 0.f};
#pragma unroll
  for (int i = 0; i < 4; ++i)
#pragma unroll
    for (int j = 0; j < NI; ++j) acc[i][j] = fz;

  for (int kt = 0; kt < K; kt += 64) {
#pragma unroll
    for (int p = 0; p < 4; ++p) {
      const int seg = p * 4 + w;
      const int row = seg * 8 + pr_row;
      gload16(A + (a_row0 + row) * Kl + kt + pr_col, (char*)lsA + seg * 1024);
    }
#pragma unroll
    for (int p = 0; p < BN / 32; ++p) {
      const int seg = p * 4 + w;
      const int row = seg * 8 + pr_row;
      gload16(W + (b_row0 + row) * Kl + kt + pr_col, (char*)lsB + seg * 1024);
    }
    __syncthreads();
#pragma unroll
    for (int kk = 0; kk < 2; ++kk) {
      bf16x8 af[4], bfr[NI];
#pragma unroll
      for (int i = 0; i < 4; ++i)
        af[i]  = *(const bf16x8*)&lsA[(wm * 64 + i * 16 + (lane & 15)) * 64 + kk * 32 + 8 * (lane >> 4)];
#pragma unroll
      for (int i = 0; i < NI; ++i)
        bfr[i] = *(const bf16x8*)&lsB[(wn * (BN / 2) + i * 16 + (lane & 15)) * 64 + kk * 32 + 8 * (lane >> 4)];
#pragma unroll
      for (int mi = 0; mi < 4; ++mi)
#pragma unroll
        for (int ni = 0; ni < NI; ++ni)
          acc[mi][ni] = MFMA16(af[mi], bfr[ni], acc[mi][ni]);
    }
    __syncthreads();
  }

#pragma unroll
  for (int mi = 0; mi < 4; ++mi) {
#pragma unroll
    for (int ni = 0; ni < NI; ++ni) {
      const int col = bn * BN + wn * (BN / 2) + ni * 16 + (lane & 15);
      const float bb = bias[col];
#pragma unroll
      for (int r = 0; r < 4; ++r) {
        const long row = a_row0 + wm * 64 + mi * 16 + (lane >> 4) * 4 + r;
        float vv = acc[mi][ni][r] + bb;
        if constexpr (EPI == EPI_GELU) vv = 0.5f * vv * (1.0f + erff(vv * 0.70710678f));
        if constexpr (EPI == EPI_RES) vv += res[row * Nl + col];
        out[row * Nl + col] = (OT)vv;
      }
    }
  }
}

// ---------------------------------------------------------------- Flash attention (causal), packed qkv LD=3072
// Causal pairing: block pi handles Q-tiles pi and 31-pi (33 K-tiles each, constant work).
// Swapped QK^T: sacc = mfma(K,Q) puts each q-row's keys lane-local -> softmax is
// lane-local max/sum + 2 shfl_xor (vs 4-step chains x 4 rows). PV / staging unchanged.
__global__ __launch_bounds__(256) void attn_kernel(
    const __bf16* __restrict__ qkv, __bf16* __restrict__ o) {
  __shared__ __bf16 lsK[2][64 * 64];
  __shared__ __bf16 lsV[2][64 * 64];
  __shared__ __bf16 lsP[4][16 * 64];
  const int tid = threadIdx.x, lane = tid & 63, w = tid >> 6;
  const int hi = lane >> 4, lo = lane & 15;
  const int pi = blockIdx.x;                  // 0..15
  const int qtL = pi, qtH = 31 - pi;
  const int b = blockIdx.z, h = blockIdx.y;
  const int qwL = qtL * 64 + w * 16;
  const int qwH = qtH * 64 + w * 16;
  const long base  = (long)b * 2048 * 3072 + h * 64;
  const long obase = (long)b * 2048 * 1024 + h * 64;
  const __bf16* q    = qkv;
  const __bf16* kmat = qkv + 1024;
  const __bf16* v    = qkv + 2048;

  // staging geometry
  const int ks_row = (lane >> 3);
  const int ks_scol = (((lane & 7) ^ (lane >> 3)) * 8);
  const int vs_key = tid >> 2, vs_db = (tid & 3) * 16;

  // Q fragments (already scaled by 0.125); row = qw + lo, k-slots 8*hi (+kk*32)
  bf16x8 aqL[2], aqH[2];
#pragma unroll
  for (int kk = 0; kk < 2; ++kk) {
    aqL[kk] = *(const bf16x8*)&q[base + (long)(qwL + lo) * 3072 + kk * 32 + 8 * hi];
    aqH[kk] = *(const bf16x8*)&q[base + (long)(qwH + lo) * 3072 + kk * 32 + 8 * hi];
  }

  const f32x4 fz = {0.f, 0.f, 0.f, 0.f};
  f32x4 oaccL[4], oaccH[4];
  float mrunL = -1e30f, lrunL = 0.f, mrunH = -1e30f, lrunH = 0.f;
#pragma unroll
  for (int ni = 0; ni < 4; ++ni) { oaccL[ni] = fz; oaccH[ni] = fz; }

  const int nkt = qtH + 1;   // = 32 - pi

  // ---- prologue: stage tile 0 into buffer 0
  bf16x8 pv0, pv1;
  {
#pragma unroll
    for (int p = 0; p < 2; ++p) {
      const int seg = p * 4 + w;
      gload16(kmat + base + (long)(seg * 8 + ks_row) * 3072 + ks_scol,
              (char*)lsK[0] + seg * 1024);
    }
    const long gv = base + (long)vs_key * 3072 + vs_db;
    pv0 = *(const bf16x8*)&v[gv];
    pv1 = *(const bf16x8*)&v[gv + 8];
    char* lv = (char*)lsV[0];
#pragma unroll
    for (int j = 0; j < 8; ++j) {
      const int d0 = vs_db + j, d1 = vs_db + 8 + j;
      *(__bf16*)(lv + d0 * 128 + ((vs_key * 2) ^ ((d0 & 7) << 4) ^ (((d0 >> 4) & 3) << 5))) = pv0[j];
      *(__bf16*)(lv + d1 * 128 + ((vs_key * 2) ^ ((d1 & 7) << 4) ^ (((d1 >> 4) & 3) << 5))) = pv1[j];
    }
  }
  __syncthreads();

  // per-Q-tile compute for one staged K/V tile (swapped-operand softmax)
  auto process = [&](const bf16x8 (&aq)[2], f32x4 (&oacc)[4], float& mrun,
                     float& lrun, const int qw, const int kt, const int cur) {
    // S' = mfma(K, Q): sacc[ni][r] = S[key kt*64+ni*16+hi*4+r][row qw+lo]
    f32x4 sacc[4];
#pragma unroll
    for (int ni = 0; ni < 4; ++ni) sacc[ni] = fz;
#pragma unroll
    for (int kk = 0; kk < 2; ++kk) {
      bf16x8 bk[4];
#pragma unroll
      for (int ni = 0; ni < 4; ++ni) {
        const int row = ni * 16 + lo;
        bk[ni] = *(const bf16x8*)((char*)lsK[cur] + row * 128 +
                                  ((kk * 64 + 16 * hi) ^ ((row & 7) << 4)));
      }
#pragma unroll
      for (int ni = 0; ni < 4; ++ni)
        sacc[ni] = MFMA16(bk[ni], aq[kk], sacc[ni]);
    }

    // causal mask (every tile; no-op for non-diagonal tiles)
    const int rg = qw + lo;
#pragma unroll
    for (int ni = 0; ni < 4; ++ni)
#pragma unroll
      for (int r = 0; r < 4; ++r)
        if (kt * 64 + ni * 16 + hi * 4 + r > rg) sacc[ni][r] = -1e9f;

    // row max: lane-local 16-max + 2 shfl_xor across hi-groups
    float mx = -3.0e38f;
#pragma unroll
    for (int ni = 0; ni < 4; ++ni)
#pragma unroll
      for (int r = 0; r < 4; ++r) mx = fmaxf(mx, sacc[ni][r]);
    mx = fmaxf(mx, __shfl_xor(mx, 16));
    mx = fmaxf(mx, __shfl_xor(mx, 32));
    const float mold = mrun;
    const float mnew = fmaxf(mold, mx);
    const float fac = __expf(mold - mnew);

    // P = exp(S - mnew) -> lsP row lo; per-lane partial sum + 2 shfl_xor
    float sum = 0.f;
    char* pbase = (char*)lsP[w] + lo * 128;
    const int swz = (lo & 7) << 4;
#pragma unroll
    for (int ni = 0; ni < 4; ++ni)
#pragma unroll
      for (int r = 0; r < 4; ++r) {
        const float pp = __expf(sacc[ni][r] - mnew);
        sum += pp;
        *(__bf16*)(pbase + ((32 * ni + 8 * hi + 2 * r) ^ swz)) = (__bf16)pp;
      }
    sum += __shfl_xor(sum, 16);
    sum += __shfl_xor(sum, 32);
    mrun = mnew;
    lrun = lrun * fac + sum;

    // O rescale: broadcast fac into the (hi,r) row domain
    float facr[4];
#pragma unroll
    for (int r = 0; r < 4; ++r) facr[r] = __shfl(fac, hi * 4 + r);
#pragma unroll
    for (int ni = 0; ni < 4; ++ni)
#pragma unroll
      for (int r = 0; r < 4; ++r) oacc[ni][r] *= facr[r];
    // no barrier: lsP is wave-private, DS ops are wave-ordered

    // O += P V  (swizzled P and V reads; oacc[ni][r] = O[row hi*4+r][d ni*16+lo])
#pragma unroll
    for (int kk = 0; kk < 2; ++kk) {
      bf16x8 ap, bv[4];
      ap = *(const bf16x8*)(pbase + ((kk * 64 + 16 * hi) ^ swz));
#pragma unroll
      for (int ni = 0; ni < 4; ++ni) {
        const int d = ni * 16 + lo;
        bv[ni] = *(const bf16x8*)((char*)lsV[cur] + d * 128 +
                                  ((kk * 64 + 16 * hi) ^ ((d & 7) << 4) ^ (((d >> 4) & 3) << 5)));
      }
#pragma unroll
      for (int ni = 0; ni < 4; ++ni)
        oacc[ni] = MFMA16(ap, bv[ni], oacc[ni]);
    }
  };

  for (int kt = 0; kt < nkt; ++kt) {
    const int cur = kt & 1;
    const bool more = (kt + 1 < nkt);

    // issue next tile's loads (K direct to LDS buf^1, V to regs)
    if (more) {
#pragma unroll
      for (int p = 0; p < 2; ++p) {
        const int seg = p * 4 + w;
        gload16(kmat + base + (long)((kt + 1) * 64 + seg * 8 + ks_row) * 3072 + ks_scol,
                (char*)lsK[cur ^ 1] + seg * 1024);
      }
      const long gv = base + (long)((kt + 1) * 64 + vs_key) * 3072 + vs_db;
      pv0 = *(const bf16x8*)&v[gv];
      pv1 = *(const bf16x8*)&v[gv + 8];
    }

    // high Q-tile always; low Q-tile while kt <= qtL (block-uniform branch)
    process(aqH, oaccH, mrunH, lrunH, qwH, kt, cur);
    if (kt <= qtL) process(aqL, oaccL, mrunL, lrunL, qwL, kt, cur);

    // write prefetched V into buf^1, then the single per-tile barrier
    if (more) {
      char* lv = (char*)lsV[cur ^ 1];
#pragma unroll
      for (int j = 0; j < 8; ++j) {
        const int d0 = vs_db + j, d1 = vs_db + 8 + j;
        *(__bf16*)(lv + d0 * 128 + ((vs_key * 2) ^ ((d0 & 7) << 4) ^ (((d0 >> 4) & 3) << 5))) = pv0[j];
        *(__bf16*)(lv + d1 * 128 + ((vs_key * 2) ^ ((d1 & 7) << 4) ^ (((d1 >> 4) & 3) << 5))) = pv1[j];
      }
    }
    __syncthreads();
  }

  // epilogue: broadcast row sums into the (hi,r) domain, store both Q-tiles
  float lprH[4], lprL[4];
#pragma unroll
  for (int r = 0; r < 4; ++r) {
    lprH[r] = __shfl(lrunH, hi * 4 + r);
    lprL[r] = __shfl(lrunL, hi * 4 + r);
  }
#pragma unroll
  for (int ni = 0; ni < 4; ++ni)
#pragma unroll
    for (int r = 0; r < 4; ++r) {
      const int rowH = qwH + hi * 4 + r;
      const int rowL = qwL + hi * 4 + r;
      o[obase + (long)rowH * 1024 + ni * 16 + lo] = (__bf16)(oaccH[ni][r] / lprH[r]);
      o[obase + (long)rowL * 1024 + ni * 16 + lo] = (__bf16)(oaccL[ni][r] / lprL[r]);
    }
}

// ---------------------------------------------------------------- launcher
extern "C" void kernel_launch(void* const* d_in, const int* in_sizes, int n_in,
                              void* d_out, int out_size, void* d_ws, size_t ws_size,
                              hipStream_t stream) {
  const float* x    = (const float*)d_in[0];
  const float* fr   = (const float*)d_in[1];
  const float* ln1g = (const float*)d_in[3];
  const float* ln1b = (const float*)d_in[4];
  const float* Wq   = (const float*)d_in[5];
  const float* bq   = (const float*)d_in[6];
  const float* Wk   = (const float*)d_in[7];
  const float* bk   = (const float*)d_in[8];
  const float* Wv   = (const float*)d_in[9];
  const float* bv   = (const float*)d_in[10];
  const float* Wo   = (const float*)d_in[11];
  const float* bo   = (const float*)d_in[12];
  const float* ln2g = (const float*)d_in[13];
  const float* ln2b = (const float*)d_in[14];
  const float* W1   = (const float*)d_in[15];
  const float* b1   = (const float*)d_in[16];
  const float* W2   = (const float*)d_in[17];
  const float* b2   = (const float*)d_in[18];
  float* out = (float*)d_out;

  char* ws = (char*)d_ws;
  const size_t SZ = 8388608;  // 8 MB
  __bf16* xn   = (__bf16*)(ws + 0);              // 8 MB
  __bf16* qkv  = (__bf16*)(ws + 1 * SZ);         // 24 MB (8..32)
  __bf16* attn = (__bf16*)(ws + 0);              // reuse xn
  float*  bqkv = (float*)(ws + 4 * SZ);          // 12 KB, dead before x2 written
  float*  x2   = (float*)(ws + 4 * SZ);          // 16 MB f32 (32..48)
  __bf16* hin  = (__bf16*)(ws + 6 * SZ);         // 8 MB (48..56)
  __bf16* hmid = (__bf16*)(ws + 0);              // 32 MB (0..32), qkv/attn dead
  char* wb = ws + 7 * SZ;                        // bf16 weights, 24 MB (56..80), contiguous
  __bf16* Wqkvb = (__bf16*)(wb + 0);             // 6 MB: Wq|Wk|Wv packed along N
  __bf16* Wob   = (__bf16*)(wb + 6 * 1048576);
  __bf16* W1b   = (__bf16*)(wb + 8 * 1048576);
  __bf16* W2b   = (__bf16*)(wb + 16 * 1048576);

  const int M = 4096, D = 1024, FF = 4096;
  dim3 blk(256);

  cvt6_kernel<<<6144, blk, 0, stream>>>(Wq, Wk, Wv, Wo, W1, W2, Wqkvb);
  pack3_kernel<<<12, blk, 0, stream>>>(bq, bk, bv, bqkv);

  ln_kernel<<<4096, blk, 0, stream>>>(x, ln1g, ln1b, xn);
  gemm_bt<EPI_NONE, __bf16, 128><<<dim3(3072 / 128, M / 128), blk, 0, stream>>>(
      xn, Wqkvb, bqkv, nullptr, qkv, M, 3072, D);
  rope_kernel<<<dim3(2048, 2), blk, 0, stream>>>(qkv, fr);
  attn_kernel<<<dim3(16, 16, 2), blk, 0, stream>>>(qkv, attn);
  gemm_bt<EPI_RES, float, 64><<<dim3(D / 64, M / 128), blk, 0, stream>>>(
      attn, Wob, bo, x, x2, M, D, D);
  ln_kernel<<<4096, blk, 0, stream>>>(x2, ln2g, ln2b, hin);
  gemm_bt<EPI_GELU, __bf16, 128><<<dim3(FF / 128, M / 128), blk, 0, stream>>>(
      hin, W1b, b1, nullptr, hmid, M, FF, D);
  gemm_bt<EPI_RES, float, 64><<<dim3(D / 64, M / 128), blk, 0, stream>>>(
      hmid, W2b, b2, x2, out, M, D, FF);
}

// Round 11
// 269.974 us; speedup vs baseline: 1.6969x; 1.1256x over previous
//
#include <hip/hip_runtime.h>
#include <hip/hip_bf16.h>

typedef __bf16 bf16x8 __attribute__((ext_vector_type(8)));
typedef __bf16 bf16x4 __attribute__((ext_vector_type(4)));
typedef float  f32x4  __attribute__((ext_vector_type(4)));

#define MFMA16(a, b, c) __builtin_amdgcn_mfma_f32_16x16x32_bf16((a), (b), (c), 0, 0, 0)

__device__ __forceinline__ void gload16(const void* g, void* l) {
  __builtin_amdgcn_global_load_lds(
      (const __attribute__((address_space(1))) unsigned int*)g,
      (__attribute__((address_space(3))) unsigned int*)l, 16, 0, 0);
}

// ---------------------------------------------------------------- f32 -> bf16 pack, all 6 weights in one launch
__global__ __launch_bounds__(256) void cvt6_kernel(
    const float* __restrict__ wq, const float* __restrict__ wk,
    const float* __restrict__ wv, const float* __restrict__ wo,
    const float* __restrict__ w1, const float* __restrict__ w2,
    __bf16* __restrict__ dst) {
  const long i = ((long)blockIdx.x * 256 + threadIdx.x) * 8;  // [0, 12M)
  const long M1 = 1048576;
  const float* src;
  long off;
  if      (i < 1 * M1) { src = wq; off = i; }
  else if (i < 2 * M1) { src = wk; off = i - 1 * M1; }
  else if (i < 3 * M1) { src = wv; off = i - 2 * M1; }
  else if (i < 4 * M1) { src = wo; off = i - 3 * M1; }
  else if (i < 8 * M1) { src = w1; off = i - 4 * M1; }
  else                 { src = w2; off = i - 8 * M1; }
  float4 a = *(const float4*)&src[off];
  float4 b = *(const float4*)&src[off + 4];
  bf16x8 o;
  o[0] = (__bf16)a.x; o[1] = (__bf16)a.y; o[2] = (__bf16)a.z; o[3] = (__bf16)a.w;
  o[4] = (__bf16)b.x; o[5] = (__bf16)b.y; o[6] = (__bf16)b.z; o[7] = (__bf16)b.w;
  *(bf16x8*)&dst[i] = o;
}

// pack 3 bias vectors (1024 each) into one f32[3072]
__global__ __launch_bounds__(256) void pack3_kernel(
    const float* __restrict__ a, const float* __restrict__ b,
    const float* __restrict__ c, float* __restrict__ o) {
  const int i = blockIdx.x * 256 + threadIdx.x;
  o[i] = i < 1024 ? a[i] : (i < 2048 ? b[i - 1024] : c[i - 2048]);
}

// ---------------------------------------------------------------- LayerNorm (f32 in -> bf16 out)
__global__ __launch_bounds__(256) void ln_kernel(
    const float* __restrict__ in, const float* __restrict__ gg,
    const float* __restrict__ bb, __bf16* __restrict__ out) {
  __shared__ float sred[8];
  const long row = blockIdx.x;
  const int tid = threadIdx.x;
  float4 u = *(const float4*)&in[row * 1024 + tid * 4];
  float f[4] = {u.x, u.y, u.z, u.w};
  float s = 0.f, sq = 0.f;
#pragma unroll
  for (int j = 0; j < 4; ++j) { s += f[j]; sq += f[j] * f[j]; }
#pragma unroll
  for (int d = 32; d; d >>= 1) { s += __shfl_xor(s, d); sq += __shfl_xor(sq, d); }
  const int w = tid >> 6;
  if ((tid & 63) == 0) { sred[w * 2] = s; sred[w * 2 + 1] = sq; }
  __syncthreads();
  s  = sred[0] + sred[2] + sred[4] + sred[6];
  sq = sred[1] + sred[3] + sred[5] + sred[7];
  const float mean = s * (1.f / 1024.f);
  const float var  = sq * (1.f / 1024.f) - mean * mean;
  const float rstd = rsqrtf(var + 1e-5f);
  float4 gv = *(const float4*)&gg[tid * 4];
  float4 bv = *(const float4*)&bb[tid * 4];
  bf16x4 ov;
  ov[0] = (__bf16)((f[0] - mean) * rstd * gv.x + bv.x);
  ov[1] = (__bf16)((f[1] - mean) * rstd * gv.y + bv.y);
  ov[2] = (__bf16)((f[2] - mean) * rstd * gv.z + bv.z);
  ov[3] = (__bf16)((f[3] - mean) * rstd * gv.w + bv.w);
  *(bf16x4*)&out[row * 1024 + tid * 4] = ov;
}

// ---------------------------------------------------------------- RoPE (in place on packed qkv, LD=3072), bf16x8
__global__ __launch_bounds__(256) void rope_kernel(
    __bf16* __restrict__ qkv, const float* __restrict__ freqs) {
  const int idx = blockIdx.x * 256 + threadIdx.x;   // [0, 4096*16*8)
  const int isq = (blockIdx.y == 0);
  __bf16* p = qkv + (isq ? 0 : 1024);
  const float scale = isq ? 0.125f : 1.0f;
  const int token = idx >> 7;
  const int wi = idx & 127;
  const int head = wi >> 3, i4 = wi & 7;
  const int spos = token & 2047;
  float4 fv = *(const float4*)&freqs[spos * 32 + i4 * 4];
  const long off = (long)token * 3072 + head * 64 + i4 * 8;
  bf16x8 u = *(bf16x8*)&p[off];
  float sn[4], cs[4];
  sincosf(fv.x, &sn[0], &cs[0]);
  sincosf(fv.y, &sn[1], &cs[1]);
  sincosf(fv.z, &sn[2], &cs[2]);
  sincosf(fv.w, &sn[3], &cs[3]);
  bf16x8 ov;
#pragma unroll
  for (int j = 0; j < 4; ++j) {
    const float x0 = (float)u[2 * j], x1 = (float)u[2 * j + 1];
    ov[2 * j]     = (__bf16)((x0 * cs[j] - x1 * sn[j]) * scale);
    ov[2 * j + 1] = (__bf16)((x1 * cs[j] + x0 * sn[j]) * scale);
  }
  *(bf16x8*)&p[off] = ov;
}

// ---------------------------------------------------------------- GEMM (m97 structure): out = act @ W^T + bias (+epi)
enum { EPI_NONE = 0, EPI_GELU = 1, EPI_RES = 2 };

template <int EPI, typename OT, int BN>
__global__ __launch_bounds__(256) void gemm_bt(
    const __bf16* __restrict__ A, const __bf16* __restrict__ W,
    const float* __restrict__ bias, const float* __restrict__ res,
    OT* __restrict__ out, int M, int N, int K) {
  constexpr int NI = BN / 32;          // fragments per wave along N
  __shared__ __bf16 lsA[128 * 64];
  __shared__ __bf16 lsB[BN * 64];
  const int tid = threadIdx.x, lane = tid & 63, w = tid >> 6;
  const int bm = blockIdx.y, bn = blockIdx.x;
  const int wm = w >> 1, wn = w & 1;
  const long Kl = K, Nl = N;
  const long a_row0 = (long)bm * 128, b_row0 = (long)bn * BN;
  const int pr_row = lane >> 3;
  const int pr_col = (lane & 7) * 8;

  f32x4 acc[4][NI];
  const f32x4 fz = {0.f, 0.f, 0.f, 0.f};
#pragma unroll
  for (int i = 0; i < 4; ++i)
#pragma unroll
    for (int j = 0; j < NI; ++j) acc[i][j] = fz;

  for (int kt = 0; kt < K; kt += 64) {
#pragma unroll
    for (int p = 0; p < 4; ++p) {
      const int seg = p * 4 + w;
      const int row = seg * 8 + pr_row;
      gload16(A + (a_row0 + row) * Kl + kt + pr_col, (char*)lsA + seg * 1024);
    }
#pragma unroll
    for (int p = 0; p < BN / 32; ++p) {
      const int seg = p * 4 + w;
      const int row = seg * 8 + pr_row;
      gload16(W + (b_row0 + row) * Kl + kt + pr_col, (char*)lsB + seg * 1024);
    }
    __syncthreads();
#pragma unroll
    for (int kk = 0; kk < 2; ++kk) {
      bf16x8 af[4], bfr[NI];
#pragma unroll
      for (int i = 0; i < 4; ++i)
        af[i]  = *(const bf16x8*)&lsA[(wm * 64 + i * 16 + (lane & 15)) * 64 + kk * 32 + 8 * (lane >> 4)];
#pragma unroll
      for (int i = 0; i < NI; ++i)
        bfr[i] = *(const bf16x8*)&lsB[(wn * (BN / 2) + i * 16 + (lane & 15)) * 64 + kk * 32 + 8 * (lane >> 4)];
#pragma unroll
      for (int mi = 0; mi < 4; ++mi)
#pragma unroll
        for (int ni = 0; ni < NI; ++ni)
          acc[mi][ni] = MFMA16(af[mi], bfr[ni], acc[mi][ni]);
    }
    __syncthreads();
  }

#pragma unroll
  for (int mi = 0; mi < 4; ++mi) {
#pragma unroll
    for (int ni = 0; ni < NI; ++ni) {
      const int col = bn * BN + wn * (BN / 2) + ni * 16 + (lane & 15);
      const float bb = bias[col];
#pragma unroll
      for (int r = 0; r < 4; ++r) {
        const long row = a_row0 + wm * 64 + mi * 16 + (lane >> 4) * 4 + r;
        float vv = acc[mi][ni][r] + bb;
        if constexpr (EPI == EPI_GELU) vv = 0.5f * vv * (1.0f + erff(vv * 0.70710678f));
        if constexpr (EPI == EPI_RES) vv += res[row * Nl + col];
        out[row * Nl + col] = (OT)vv;
      }
    }
  }
}

// ---------------------------------------------------------------- 256x256 8-phase GEMM (m201 template, plain HIP)
// 512 threads = 8 waves (2M x 4N); BK=64; LDS 128KB: [buf][A/B][half][16KB], st_16x32
// subtiled+swizzled; gload_lds with linear dest + inverse-swizzled per-lane source;
// counted vmcnt(4) once per K-tile; setprio around MFMA clusters. Requires K>=128, %64==0.
template <int EPI, typename OT>
__global__ __launch_bounds__(512) void gemm256(
    const __bf16* __restrict__ A, const __bf16* __restrict__ W,
    const float* __restrict__ bias, OT* __restrict__ out,
    int M, int N, int K) {
  __shared__ char lds[2][2][2][16384];  // [buf][0=A,1=B][half][bytes]
  const int tid = threadIdx.x, l = tid & 63, w = tid >> 6;
  const int wm = w >> 2, wn = w & 3;
  const int lo = l & 15, hi = l >> 4;
  const int bm = blockIdx.y, bn = blockIdx.x;
  const long Kl = K, Nl = N;
  const long arow0 = (long)bm * 256, brow0 = (long)bn * 256;
  const int nk = K >> 6;

  // staging lane geometry: lane l owns subtile byte 16l (linear dest);
  // inverse-swizzle the SOURCE: row=(l>>2), col-block=(l&3)^(((l>>5)&1)<<1)
  const int st_row = l >> 2;
  const int st_cb  = ((l & 3) ^ (((l >> 5) & 1) << 1)) * 8;  // bf16 units

  f32x4 acc[8][4];
  const f32x4 fz = {0.f, 0.f, 0.f, 0.f};
#pragma unroll
  for (int i = 0; i < 8; ++i)
#pragma unroll
    for (int j = 0; j < 4; ++j) acc[i][j] = fz;

  // stage one half-tile (128 rows x 64 cols) = 16 subtiles; wave w does subtiles w, w+8
  auto stageA = [&](int u, int h) {
    char* base = &lds[u & 1][0][h][0];
    const __bf16* src = A + (arow0 + h * 128) * Kl + u * 64;
#pragma unroll
    for (int c = 0; c < 2; ++c) {
      const int s = c * 8 + w;
      gload16(src + (long)((s >> 1) * 16 + st_row) * Kl + ((s & 1) * 32 + st_cb),
              base + s * 1024);
    }
  };
  auto stageB = [&](int u, int h) {
    char* base = &lds[u & 1][1][h][0];
    const __bf16* src = W + (brow0 + h * 128) * Kl + u * 64;
#pragma unroll
    for (int c = 0; c < 2; ++c) {
      const int s = c * 8 + w;
      gload16(src + (long)((s >> 1) * 16 + st_row) * Kl + ((s & 1) * 32 + st_cb),
              base + s * 1024);
    }
  };
  // swizzled read: element row "rr" (0..255), col bytes cB (0..127, 16B-aligned)
  auto rdA = [&](int u, int rr, int cB) -> bf16x8 {
    const char* p = &lds[u & 1][0][rr >> 7][0];
    const int mr = rr & 127;
    return *(const bf16x8*)(p + (mr >> 4) * 2048 + ((cB >> 6) << 10) + (mr & 15) * 64 +
                            ((cB & 63) ^ (((mr >> 3) & 1) << 5)));
  };
  auto rdB = [&](int u, int rr, int cB) -> bf16x8 {
    const char* p = &lds[u & 1][1][rr >> 7][0];
    const int mr = rr & 127;
    return *(const bf16x8*)(p + (mr >> 4) * 2048 + ((cB >> 6) << 10) + (mr & 15) * 64 +
                            ((cB & 63) ^ (((mr >> 3) & 1) << 5)));
  };

  // ---- prologue: tile0 (A0,A1,B0,B1) + B halves of tile1; wait tile0 landed
  stageA(0, 0); stageA(0, 1); stageB(0, 0); stageB(0, 1);
  stageB(1, 0); stageB(1, 1);
  asm volatile("s_waitcnt vmcnt(4)" ::: "memory");   // tile0's 8 loads landed; B(1) in flight
  __builtin_amdgcn_s_barrier();

  for (int u = 0; u < nk; ++u) {
    bf16x8 bfr[4][2];
#pragma unroll
    for (int q = 0; q < 4; ++q) {
      // ---- ds reads (B once per K-tile at q0; A quadrant every phase)
      if (q == 0) {
#pragma unroll
        for (int nf = 0; nf < 4; ++nf)
#pragma unroll
          for (int kk = 0; kk < 2; ++kk)
            bfr[nf][kk] = rdB(u, wn * 64 + nf * 16 + lo, kk * 64 + 16 * hi);
      }
      bf16x8 af[2][2];
#pragma unroll
      for (int mf = 0; mf < 2; ++mf)
#pragma unroll
        for (int kk = 0; kk < 2; ++kk)
          af[mf][kk] = rdA(u, wm * 128 + (q * 2 + mf) * 16 + lo, kk * 64 + 16 * hi);

      // ---- stage one half-tile of a future K-tile (targets dead regions)
      if (q == 0) { if (u + 1 < nk) stageA(u + 1, 0); }
      else if (q == 1) { if (u + 1 < nk) stageA(u + 1, 1); }
      else if (q == 2) { if (u + 2 < nk) stageB(u + 2, 0); }
      else             { if (u + 2 < nk) stageB(u + 2, 1); }

      __builtin_amdgcn_s_barrier();
      asm volatile("s_waitcnt lgkmcnt(0)" ::: "memory");
      __builtin_amdgcn_sched_barrier(0);
      __builtin_amdgcn_s_setprio(1);
#pragma unroll
      for (int mf = 0; mf < 2; ++mf)
#pragma unroll
        for (int nf = 0; nf < 4; ++nf)
#pragma unroll
          for (int kk = 0; kk < 2; ++kk)
            acc[q * 2 + mf][nf] = MFMA16(af[mf][kk], bfr[nf][kk], acc[q * 2 + mf][nf]);
      __builtin_amdgcn_s_setprio(0);
      if (q == 3) {
        // counted wait: A(u+1)+B(u+1) landed; B(u+2) (last 4 loads) may stay in flight
        if (u + 2 < nk) asm volatile("s_waitcnt vmcnt(4)" ::: "memory");
        else            asm volatile("s_waitcnt vmcnt(0)" ::: "memory");
      }
      __builtin_amdgcn_s_barrier();
    }
  }

  // ---- epilogue
#pragma unroll
  for (int mf = 0; mf < 8; ++mf) {
#pragma unroll
    for (int nf = 0; nf < 4; ++nf) {
      const int col = (int)brow0 + wn * 64 + nf * 16 + lo;
      const float bb = bias[col];
#pragma unroll
      for (int r = 0; r < 4; ++r) {
        const long row = arow0 + wm * 128 + mf * 16 + hi * 4 + r;
        float vv = acc[mf][nf][r] + bb;
        if constexpr (EPI == EPI_GELU) vv = 0.5f * vv * (1.0f + erff(vv * 0.70710678f));
        out[row * Nl + col] = (OT)vv;
      }
    }
  }
}

// ---------------------------------------------------------------- Flash attention (causal), packed qkv LD=3072
// Causal pairing + double-buffered prefetch + swapped-operand lane-local softmax.
__global__ __launch_bounds__(256) void attn_kernel(
    const __bf16* __restrict__ qkv, __bf16* __restrict__ o) {
  __shared__ __bf16 lsK[2][64 * 64];
  __shared__ __bf16 lsV[2][64 * 64];
  __shared__ __bf16 lsP[4][16 * 64];
  const int tid = threadIdx.x, lane = tid & 63, w = tid >> 6;
  const int hi = lane >> 4, lo = lane & 15;
  const int pi = blockIdx.x;                  // 0..15
  const int qtL = pi, qtH = 31 - pi;
  const int b = blockIdx.z, h = blockIdx.y;
  const int qwL = qtL * 64 + w * 16;
  const int qwH = qtH * 64 + w * 16;
  const long base  = (long)b * 2048 * 3072 + h * 64;
  const long obase = (long)b * 2048 * 1024 + h * 64;
  const __bf16* q    = qkv;
  const __bf16* kmat = qkv + 1024;
  const __bf16* v    = qkv + 2048;

  const int ks_row = (lane >> 3);
  const int ks_scol = (((lane & 7) ^ (lane >> 3)) * 8);
  const int vs_key = tid >> 2, vs_db = (tid & 3) * 16;

  bf16x8 aqL[2], aqH[2];
#pragma unroll
  for (int kk = 0; kk < 2; ++kk) {
    aqL[kk] = *(const bf16x8*)&q[base + (long)(qwL + lo) * 3072 + kk * 32 + 8 * hi];
    aqH[kk] = *(const bf16x8*)&q[base + (long)(qwH + lo) * 3072 + kk * 32 + 8 * hi];
  }

  const f32x4 fz = {0.f, 0.f, 0.f, 0.f};
  f32x4 oaccL[4], oaccH[4];
  float mrunL = -1e30f, lrunL = 0.f, mrunH = -1e30f, lrunH = 0.f;
#pragma unroll
  for (int ni = 0; ni < 4; ++ni) { oaccL[ni] = fz; oaccH[ni] = fz; }

  const int nkt = qtH + 1;   // = 32 - pi

  bf16x8 pv0, pv1;
  {
#pragma unroll
    for (int p = 0; p < 2; ++p) {
      const int seg = p * 4 + w;
      gload16(kmat + base + (long)(seg * 8 + ks_row) * 3072 + ks_scol,
              (char*)lsK[0] + seg * 1024);
    }
    const long gv = base + (long)vs_key * 3072 + vs_db;
    pv0 = *(const bf16x8*)&v[gv];
    pv1 = *(const bf16x8*)&v[gv + 8];
    char* lv = (char*)lsV[0];
#pragma unroll
    for (int j = 0; j < 8; ++j) {
      const int d0 = vs_db + j, d1 = vs_db + 8 + j;
      *(__bf16*)(lv + d0 * 128 + ((vs_key * 2) ^ ((d0 & 7) << 4) ^ (((d0 >> 4) & 3) << 5))) = pv0[j];
      *(__bf16*)(lv + d1 * 128 + ((vs_key * 2) ^ ((d1 & 7) << 4) ^ (((d1 >> 4) & 3) << 5))) = pv1[j];
    }
  }
  __syncthreads();

  auto process = [&](const bf16x8 (&aq)[2], f32x4 (&oacc)[4], float& mrun,
                     float& lrun, const int qw, const int kt, const int cur) {
    f32x4 sacc[4];
#pragma unroll
    for (int ni = 0; ni < 4; ++ni) sacc[ni] = fz;
#pragma unroll
    for (int kk = 0; kk < 2; ++kk) {
      bf16x8 bk[4];
#pragma unroll
      for (int ni = 0; ni < 4; ++ni) {
        const int row = ni * 16 + lo;
        bk[ni] = *(const bf16x8*)((char*)lsK[cur] + row * 128 +
                                  ((kk * 64 + 16 * hi) ^ ((row & 7) << 4)));
      }
#pragma unroll
      for (int ni = 0; ni < 4; ++ni)
        sacc[ni] = MFMA16(bk[ni], aq[kk], sacc[ni]);
    }

    const int rg = qw + lo;
#pragma unroll
    for (int ni = 0; ni < 4; ++ni)
#pragma unroll
      for (int r = 0; r < 4; ++r)
        if (kt * 64 + ni * 16 + hi * 4 + r > rg) sacc[ni][r] = -1e9f;

    float mx = -3.0e38f;
#pragma unroll
    for (int ni = 0; ni < 4; ++ni)
#pragma unroll
      for (int r = 0; r < 4; ++r) mx = fmaxf(mx, sacc[ni][r]);
    mx = fmaxf(mx, __shfl_xor(mx, 16));
    mx = fmaxf(mx, __shfl_xor(mx, 32));
    const float mold = mrun;
    const float mnew = fmaxf(mold, mx);
    const float fac = __expf(mold - mnew);

    float sum = 0.f;
    char* pbase = (char*)lsP[w] + lo * 128;
    const int swz = (lo & 7) << 4;
#pragma unroll
    for (int ni = 0; ni < 4; ++ni)
#pragma unroll
      for (int r = 0; r < 4; ++r) {
        const float pp = __expf(sacc[ni][r] - mnew);
        sum += pp;
        *(__bf16*)(pbase + ((32 * ni + 8 * hi + 2 * r) ^ swz)) = (__bf16)pp;
      }
    sum += __shfl_xor(sum, 16);
    sum += __shfl_xor(sum, 32);
    mrun = mnew;
    lrun = lrun * fac + sum;

    float facr[4];
#pragma unroll
    for (int r = 0; r < 4; ++r) facr[r] = __shfl(fac, hi * 4 + r);
#pragma unroll
    for (int ni = 0; ni < 4; ++ni)
#pragma unroll
      for (int r = 0; r < 4; ++r) oacc[ni][r] *= facr[r];

#pragma unroll
    for (int kk = 0; kk < 2; ++kk) {
      bf16x8 ap, bv[4];
      ap = *(const bf16x8*)(pbase + ((kk * 64 + 16 * hi) ^ swz));
#pragma unroll
      for (int ni = 0; ni < 4; ++ni) {
        const int d = ni * 16 + lo;
        bv[ni] = *(const bf16x8*)((char*)lsV[cur] + d * 128 +
                                  ((kk * 64 + 16 * hi) ^ ((d & 7) << 4) ^ (((d >> 4) & 3) << 5)));
      }
#pragma unroll
      for (int ni = 0; ni < 4; ++ni)
        oacc[ni] = MFMA16(ap, bv[ni], oacc[ni]);
    }
  };

  for (int kt = 0; kt < nkt; ++kt) {
    const int cur = kt & 1;
    const bool more = (kt + 1 < nkt);

    if (more) {
#pragma unroll
      for (int p = 0; p < 2; ++p) {
        const int seg = p * 4 + w;
        gload16(kmat + base + (long)((kt + 1) * 64 + seg * 8 + ks_row) * 3072 + ks_scol,
                (char*)lsK[cur ^ 1] + seg * 1024);
      }
      const long gv = base + (long)((kt + 1) * 64 + vs_key) * 3072 + vs_db;
      pv0 = *(const bf16x8*)&v[gv];
      pv1 = *(const bf16x8*)&v[gv + 8];
    }

    process(aqH, oaccH, mrunH, lrunH, qwH, kt, cur);
    if (kt <= qtL) process(aqL, oaccL, mrunL, lrunL, qwL, kt, cur);

    if (more) {
      char* lv = (char*)lsV[cur ^ 1];
#pragma unroll
      for (int j = 0; j < 8; ++j) {
        const int d0 = vs_db + j, d1 = vs_db + 8 + j;
        *(__bf16*)(lv + d0 * 128 + ((vs_key * 2) ^ ((d0 & 7) << 4) ^ (((d0 >> 4) & 3) << 5))) = pv0[j];
        *(__bf16*)(lv + d1 * 128 + ((vs_key * 2) ^ ((d1 & 7) << 4) ^ (((d1 >> 4) & 3) << 5))) = pv1[j];
      }
    }
    __syncthreads();
  }

  float lprH[4], lprL[4];
#pragma unroll
  for (int r = 0; r < 4; ++r) {
    lprH[r] = __shfl(lrunH, hi * 4 + r);
    lprL[r] = __shfl(lrunL, hi * 4 + r);
  }
#pragma unroll
  for (int ni = 0; ni < 4; ++ni)
#pragma unroll
    for (int r = 0; r < 4; ++r) {
      const int rowH = qwH + hi * 4 + r;
      const int rowL = qwL + hi * 4 + r;
      o[obase + (long)rowH * 1024 + ni * 16 + lo] = (__bf16)(oaccH[ni][r] / lprH[r]);
      o[obase + (long)rowL * 1024 + ni * 16 + lo] = (__bf16)(oaccL[ni][r] / lprL[r]);
    }
}

// ---------------------------------------------------------------- launcher
extern "C" void kernel_launch(void* const* d_in, const int* in_sizes, int n_in,
                              void* d_out, int out_size, void* d_ws, size_t ws_size,
                              hipStream_t stream) {
  const float* x    = (const float*)d_in[0];
  const float* fr   = (const float*)d_in[1];
  const float* ln1g = (const float*)d_in[3];
  const float* ln1b = (const float*)d_in[4];
  const float* Wq   = (const float*)d_in[5];
  const float* bq   = (const float*)d_in[6];
  const float* Wk   = (const float*)d_in[7];
  const float* bk   = (const float*)d_in[8];
  const float* Wv   = (const float*)d_in[9];
  const float* bv   = (const float*)d_in[10];
  const float* Wo   = (const float*)d_in[11];
  const float* bo   = (const float*)d_in[12];
  const float* ln2g = (const float*)d_in[13];
  const float* ln2b = (const float*)d_in[14];
  const float* W1   = (const float*)d_in[15];
  const float* b1   = (const float*)d_in[16];
  const float* W2   = (const float*)d_in[17];
  const float* b2   = (const float*)d_in[18];
  float* out = (float*)d_out;

  char* ws = (char*)d_ws;
  const size_t SZ = 8388608;  // 8 MB
  __bf16* xn   = (__bf16*)(ws + 0);              // 8 MB
  __bf16* qkv  = (__bf16*)(ws + 1 * SZ);         // 24 MB (8..32)
  __bf16* attn = (__bf16*)(ws + 0);              // reuse xn
  float*  bqkv = (float*)(ws + 4 * SZ);          // 12 KB, dead before x2 written
  float*  x2   = (float*)(ws + 4 * SZ);          // 16 MB f32 (32..48)
  __bf16* hin  = (__bf16*)(ws + 6 * SZ);         // 8 MB (48..56)
  __bf16* hmid = (__bf16*)(ws + 0);              // 32 MB (0..32), qkv/attn dead
  char* wb = ws + 7 * SZ;                        // bf16 weights, 24 MB (56..80), contiguous
  __bf16* Wqkvb = (__bf16*)(wb + 0);             // 6 MB: Wq|Wk|Wv packed along N
  __bf16* Wob   = (__bf16*)(wb + 6 * 1048576);
  __bf16* W1b   = (__bf16*)(wb + 8 * 1048576);
  __bf16* W2b   = (__bf16*)(wb + 16 * 1048576);

  const int M = 4096, D = 1024, FF = 4096;
  dim3 blk(256), blk5(512);

  cvt6_kernel<<<6144, blk, 0, stream>>>(Wq, Wk, Wv, Wo, W1, W2, Wqkvb);
  pack3_kernel<<<12, blk, 0, stream>>>(bq, bk, bv, bqkv);

  ln_kernel<<<4096, blk, 0, stream>>>(x, ln1g, ln1b, xn);
  gemm256<EPI_NONE, __bf16><<<dim3(3072 / 256, M / 256), blk5, 0, stream>>>(
      xn, Wqkvb, bqkv, qkv, M, 3072, D);
  rope_kernel<<<dim3(2048, 2), blk, 0, stream>>>(qkv, fr);
  attn_kernel<<<dim3(16, 16, 2), blk, 0, stream>>>(qkv, attn);
  gemm_bt<EPI_RES, float, 64><<<dim3(D / 64, M / 128), blk, 0, stream>>>(
      attn, Wob, bo, x, x2, M, D, D);
  ln_kernel<<<4096, blk, 0, stream>>>(x2, ln2g, ln2b, hin);
  gemm256<EPI_GELU, __bf16><<<dim3(FF / 256, M / 256), blk5, 0, stream>>>(
      hin, W1b, b1, hmid, M, FF, D);
  gemm_bt<EPI_RES, float, 64><<<dim3(D / 64, M / 128), blk, 0, stream>>>(
      hmid, W2b, b2, x2, out, M, D, FF);
}

// Round 12
// 269.542 us; speedup vs baseline: 1.6996x; 1.0016x over previous
//
#include <hip/hip_runtime.h>
#include <hip/hip_bf16.h>

typedef __bf16 bf16x8 __attribute__((ext_vector_type(8)));
typedef __bf16 bf16x4 __attribute__((ext_vector_type(4)));
typedef float  f32x4  __attribute__((ext_vector_type(4)));

#define MFMA16(a, b, c) __builtin_amdgcn_mfma_f32_16x16x32_bf16((a), (b), (c), 0, 0, 0)

__device__ __forceinline__ void gload16(const void* g, void* l) {
  __builtin_amdgcn_global_load_lds(
      (const __attribute__((address_space(1))) unsigned int*)g,
      (__attribute__((address_space(3))) unsigned int*)l, 16, 0, 0);
}

// ---------------------------------------------------------------- f32 -> bf16 pack, all 6 weights in one launch
__global__ __launch_bounds__(256) void cvt6_kernel(
    const float* __restrict__ wq, const float* __restrict__ wk,
    const float* __restrict__ wv, const float* __restrict__ wo,
    const float* __restrict__ w1, const float* __restrict__ w2,
    __bf16* __restrict__ dst) {
  const long i = ((long)blockIdx.x * 256 + threadIdx.x) * 8;  // [0, 12M)
  const long M1 = 1048576;
  const float* src;
  long off;
  if      (i < 1 * M1) { src = wq; off = i; }
  else if (i < 2 * M1) { src = wk; off = i - 1 * M1; }
  else if (i < 3 * M1) { src = wv; off = i - 2 * M1; }
  else if (i < 4 * M1) { src = wo; off = i - 3 * M1; }
  else if (i < 8 * M1) { src = w1; off = i - 4 * M1; }
  else                 { src = w2; off = i - 8 * M1; }
  float4 a = *(const float4*)&src[off];
  float4 b = *(const float4*)&src[off + 4];
  bf16x8 o;
  o[0] = (__bf16)a.x; o[1] = (__bf16)a.y; o[2] = (__bf16)a.z; o[3] = (__bf16)a.w;
  o[4] = (__bf16)b.x; o[5] = (__bf16)b.y; o[6] = (__bf16)b.z; o[7] = (__bf16)b.w;
  *(bf16x8*)&dst[i] = o;
}

// pack 3 bias vectors (1024 each) into one f32[3072]
__global__ __launch_bounds__(256) void pack3_kernel(
    const float* __restrict__ a, const float* __restrict__ b,
    const float* __restrict__ c, float* __restrict__ o) {
  const int i = blockIdx.x * 256 + threadIdx.x;
  o[i] = i < 1024 ? a[i] : (i < 2048 ? b[i - 1024] : c[i - 2048]);
}

// ---------------------------------------------------------------- LayerNorm (f32 in -> bf16 out)
__global__ __launch_bounds__(256) void ln_kernel(
    const float* __restrict__ in, const float* __restrict__ gg,
    const float* __restrict__ bb, __bf16* __restrict__ out) {
  __shared__ float sred[8];
  const long row = blockIdx.x;
  const int tid = threadIdx.x;
  float4 u = *(const float4*)&in[row * 1024 + tid * 4];
  float f[4] = {u.x, u.y, u.z, u.w};
  float s = 0.f, sq = 0.f;
#pragma unroll
  for (int j = 0; j < 4; ++j) { s += f[j]; sq += f[j] * f[j]; }
#pragma unroll
  for (int d = 32; d; d >>= 1) { s += __shfl_xor(s, d); sq += __shfl_xor(sq, d); }
  const int w = tid >> 6;
  if ((tid & 63) == 0) { sred[w * 2] = s; sred[w * 2 + 1] = sq; }
  __syncthreads();
  s  = sred[0] + sred[2] + sred[4] + sred[6];
  sq = sred[1] + sred[3] + sred[5] + sred[7];
  const float mean = s * (1.f / 1024.f);
  const float var  = sq * (1.f / 1024.f) - mean * mean;
  const float rstd = rsqrtf(var + 1e-5f);
  float4 gv = *(const float4*)&gg[tid * 4];
  float4 bv = *(const float4*)&bb[tid * 4];
  bf16x4 ov;
  ov[0] = (__bf16)((f[0] - mean) * rstd * gv.x + bv.x);
  ov[1] = (__bf16)((f[1] - mean) * rstd * gv.y + bv.y);
  ov[2] = (__bf16)((f[2] - mean) * rstd * gv.z + bv.z);
  ov[3] = (__bf16)((f[3] - mean) * rstd * gv.w + bv.w);
  *(bf16x4*)&out[row * 1024 + tid * 4] = ov;
}

// ---------------------------------------------------------------- RoPE (in place on packed qkv, LD=3072), bf16x8
__global__ __launch_bounds__(256) void rope_kernel(
    __bf16* __restrict__ qkv, const float* __restrict__ freqs) {
  const int idx = blockIdx.x * 256 + threadIdx.x;   // [0, 4096*16*8)
  const int isq = (blockIdx.y == 0);
  __bf16* p = qkv + (isq ? 0 : 1024);
  const float scale = isq ? 0.125f : 1.0f;
  const int token = idx >> 7;
  const int wi = idx & 127;
  const int head = wi >> 3, i4 = wi & 7;
  const int spos = token & 2047;
  float4 fv = *(const float4*)&freqs[spos * 32 + i4 * 4];
  const long off = (long)token * 3072 + head * 64 + i4 * 8;
  bf16x8 u = *(bf16x8*)&p[off];
  float sn[4], cs[4];
  sincosf(fv.x, &sn[0], &cs[0]);
  sincosf(fv.y, &sn[1], &cs[1]);
  sincosf(fv.z, &sn[2], &cs[2]);
  sincosf(fv.w, &sn[3], &cs[3]);
  bf16x8 ov;
#pragma unroll
  for (int j = 0; j < 4; ++j) {
    const float x0 = (float)u[2 * j], x1 = (float)u[2 * j + 1];
    ov[2 * j]     = (__bf16)((x0 * cs[j] - x1 * sn[j]) * scale);
    ov[2 * j + 1] = (__bf16)((x1 * cs[j] + x0 * sn[j]) * scale);
  }
  *(bf16x8*)&p[off] = ov;
}

// ---------------------------------------------------------------- GEMM (m97 structure + T3-min dbuf prefetch)
enum { EPI_NONE = 0, EPI_GELU = 1, EPI_RES = 2 };

template <int EPI, typename OT, int BN>
__global__ __launch_bounds__(256) void gemm_bt(
    const __bf16* __restrict__ A, const __bf16* __restrict__ W,
    const float* __restrict__ bias, const float* __restrict__ res,
    OT* __restrict__ out, int M, int N, int K) {
  constexpr int NI = BN / 32;          // fragments per wave along N
  __shared__ __bf16 lsA[2][128 * 64];
  __shared__ __bf16 lsB[2][BN * 64];
  const int tid = threadIdx.x, lane = tid & 63, w = tid >> 6;
  const int bm = blockIdx.y, bn = blockIdx.x;
  const int wm = w >> 1, wn = w & 1;
  const long Kl = K, Nl = N;
  const long a_row0 = (long)bm * 128, b_row0 = (long)bn * BN;
  const int pr_row = lane >> 3;
  const int pr_col = (lane & 7) * 8;

  auto stage = [&](int kt, int buf) {
#pragma unroll
    for (int p = 0; p < 4; ++p) {
      const int seg = p * 4 + w;
      const int row = seg * 8 + pr_row;
      gload16(A + (a_row0 + row) * Kl + kt + pr_col, (char*)lsA[buf] + seg * 1024);
    }
#pragma unroll
    for (int p = 0; p < BN / 32; ++p) {
      const int seg = p * 4 + w;
      const int row = seg * 8 + pr_row;
      gload16(W + (b_row0 + row) * Kl + kt + pr_col, (char*)lsB[buf] + seg * 1024);
    }
  };

  f32x4 acc[4][NI];
  const f32x4 fz = {0.f, 0.f, 0.f, 0.f};
#pragma unroll
  for (int i = 0; i < 4; ++i)
#pragma unroll
    for (int j = 0; j < NI; ++j) acc[i][j] = fz;

  stage(0, 0);
  __syncthreads();   // implicit vmcnt(0) drain: buf0 ready

  for (int kt = 0; kt < K; kt += 64) {
    const int cur = (kt >> 6) & 1;
    if (kt + 64 < K) stage(kt + 64, cur ^ 1);   // prefetch overlaps compute
#pragma unroll
    for (int kk = 0; kk < 2; ++kk) {
      bf16x8 af[4], bfr[NI];
#pragma unroll
      for (int i = 0; i < 4; ++i)
        af[i]  = *(const bf16x8*)&lsA[cur][(wm * 64 + i * 16 + (lane & 15)) * 64 + kk * 32 + 8 * (lane >> 4)];
#pragma unroll
      for (int i = 0; i < NI; ++i)
        bfr[i] = *(const bf16x8*)&lsB[cur][(wn * (BN / 2) + i * 16 + (lane & 15)) * 64 + kk * 32 + 8 * (lane >> 4)];
#pragma unroll
      for (int mi = 0; mi < 4; ++mi)
#pragma unroll
        for (int ni = 0; ni < NI; ++ni)
          acc[mi][ni] = MFMA16(af[mi], bfr[ni], acc[mi][ni]);
    }
    __syncthreads();   // drains prefetch (vmcnt 0) + guards buf reuse
  }

#pragma unroll
  for (int mi = 0; mi < 4; ++mi) {
#pragma unroll
    for (int ni = 0; ni < NI; ++ni) {
      const int col = bn * BN + wn * (BN / 2) + ni * 16 + (lane & 15);
      const float bb = bias[col];
#pragma unroll
      for (int r = 0; r < 4; ++r) {
        const long row = a_row0 + wm * 64 + mi * 16 + (lane >> 4) * 4 + r;
        float vv = acc[mi][ni][r] + bb;
        if constexpr (EPI == EPI_GELU) vv = 0.5f * vv * (1.0f + erff(vv * 0.70710678f));
        if constexpr (EPI == EPI_RES) vv += res[row * Nl + col];
        out[row * Nl + col] = (OT)vv;
      }
    }
  }
}

// ---------------------------------------------------------------- 256x256 8-phase GEMM (m201 template, plain HIP)
template <int EPI, typename OT>
__global__ __launch_bounds__(512) void gemm256(
    const __bf16* __restrict__ A, const __bf16* __restrict__ W,
    const float* __restrict__ bias, OT* __restrict__ out,
    int M, int N, int K) {
  __shared__ char lds[2][2][2][16384];  // [buf][0=A,1=B][half][bytes]
  const int tid = threadIdx.x, l = tid & 63, w = tid >> 6;
  const int wm = w >> 2, wn = w & 3;
  const int lo = l & 15, hi = l >> 4;
  const int bm = blockIdx.y, bn = blockIdx.x;
  const long Kl = K, Nl = N;
  const long arow0 = (long)bm * 256, brow0 = (long)bn * 256;
  const int nk = K >> 6;

  const int st_row = l >> 2;
  const int st_cb  = ((l & 3) ^ (((l >> 5) & 1) << 1)) * 8;  // bf16 units

  f32x4 acc[8][4];
  const f32x4 fz = {0.f, 0.f, 0.f, 0.f};
#pragma unroll
  for (int i = 0; i < 8; ++i)
#pragma unroll
    for (int j = 0; j < 4; ++j) acc[i][j] = fz;

  auto stageA = [&](int u, int h) {
    char* base = &lds[u & 1][0][h][0];
    const __bf16* src = A + (arow0 + h * 128) * Kl + u * 64;
#pragma unroll
    for (int c = 0; c < 2; ++c) {
      const int s = c * 8 + w;
      gload16(src + (long)((s >> 1) * 16 + st_row) * Kl + ((s & 1) * 32 + st_cb),
              base + s * 1024);
    }
  };
  auto stageB = [&](int u, int h) {
    char* base = &lds[u & 1][1][h][0];
    const __bf16* src = W + (brow0 + h * 128) * Kl + u * 64;
#pragma unroll
    for (int c = 0; c < 2; ++c) {
      const int s = c * 8 + w;
      gload16(src + (long)((s >> 1) * 16 + st_row) * Kl + ((s & 1) * 32 + st_cb),
              base + s * 1024);
    }
  };
  auto rdA = [&](int u, int rr, int cB) -> bf16x8 {
    const char* p = &lds[u & 1][0][rr >> 7][0];
    const int mr = rr & 127;
    return *(const bf16x8*)(p + (mr >> 4) * 2048 + ((cB >> 6) << 10) + (mr & 15) * 64 +
                            ((cB & 63) ^ (((mr >> 3) & 1) << 5)));
  };
  auto rdB = [&](int u, int rr, int cB) -> bf16x8 {
    const char* p = &lds[u & 1][1][rr >> 7][0];
    const int mr = rr & 127;
    return *(const bf16x8*)(p + (mr >> 4) * 2048 + ((cB >> 6) << 10) + (mr & 15) * 64 +
                            ((cB & 63) ^ (((mr >> 3) & 1) << 5)));
  };

  stageA(0, 0); stageA(0, 1); stageB(0, 0); stageB(0, 1);
  stageB(1, 0); stageB(1, 1);
  asm volatile("s_waitcnt vmcnt(4)" ::: "memory");
  __builtin_amdgcn_s_barrier();

  for (int u = 0; u < nk; ++u) {
    bf16x8 bfr[4][2];
#pragma unroll
    for (int q = 0; q < 4; ++q) {
      if (q == 0) {
#pragma unroll
        for (int nf = 0; nf < 4; ++nf)
#pragma unroll
          for (int kk = 0; kk < 2; ++kk)
            bfr[nf][kk] = rdB(u, wn * 64 + nf * 16 + lo, kk * 64 + 16 * hi);
      }
      bf16x8 af[2][2];
#pragma unroll
      for (int mf = 0; mf < 2; ++mf)
#pragma unroll
        for (int kk = 0; kk < 2; ++kk)
          af[mf][kk] = rdA(u, wm * 128 + (q * 2 + mf) * 16 + lo, kk * 64 + 16 * hi);

      if (q == 0) { if (u + 1 < nk) stageA(u + 1, 0); }
      else if (q == 1) { if (u + 1 < nk) stageA(u + 1, 1); }
      else if (q == 2) { if (u + 2 < nk) stageB(u + 2, 0); }
      else             { if (u + 2 < nk) stageB(u + 2, 1); }

      __builtin_amdgcn_s_barrier();
      asm volatile("s_waitcnt lgkmcnt(0)" ::: "memory");
      __builtin_amdgcn_sched_barrier(0);
      __builtin_amdgcn_s_setprio(1);
#pragma unroll
      for (int mf = 0; mf < 2; ++mf)
#pragma unroll
        for (int nf = 0; nf < 4; ++nf)
#pragma unroll
          for (int kk = 0; kk < 2; ++kk)
            acc[q * 2 + mf][nf] = MFMA16(af[mf][kk], bfr[nf][kk], acc[q * 2 + mf][nf]);
      __builtin_amdgcn_s_setprio(0);
      if (q == 3) {
        if (u + 2 < nk) asm volatile("s_waitcnt vmcnt(4)" ::: "memory");
        else            asm volatile("s_waitcnt vmcnt(0)" ::: "memory");
      }
      __builtin_amdgcn_s_barrier();
    }
  }

#pragma unroll
  for (int mf = 0; mf < 8; ++mf) {
#pragma unroll
    for (int nf = 0; nf < 4; ++nf) {
      const int col = (int)brow0 + wn * 64 + nf * 16 + lo;
      const float bb = bias[col];
#pragma unroll
      for (int r = 0; r < 4; ++r) {
        const long row = arow0 + wm * 128 + mf * 16 + hi * 4 + r;
        float vv = acc[mf][nf][r] + bb;
        if constexpr (EPI == EPI_GELU) vv = 0.5f * vv * (1.0f + erff(vv * 0.70710678f));
        out[row * Nl + col] = (OT)vv;
      }
    }
  }
}

// ---------------------------------------------------------------- Flash attention (causal), packed qkv LD=3072
__global__ __launch_bounds__(256) void attn_kernel(
    const __bf16* __restrict__ qkv, __bf16* __restrict__ o) {
  __shared__ __bf16 lsK[2][64 * 64];
  __shared__ __bf16 lsV[2][64 * 64];
  __shared__ __bf16 lsP[4][16 * 64];
  const int tid = threadIdx.x, lane = tid & 63, w = tid >> 6;
  const int hi = lane >> 4, lo = lane & 15;
  const int pi = blockIdx.x;                  // 0..15
  const int qtL = pi, qtH = 31 - pi;
  const int b = blockIdx.z, h = blockIdx.y;
  const int qwL = qtL * 64 + w * 16;
  const int qwH = qtH * 64 + w * 16;
  const long base  = (long)b * 2048 * 3072 + h * 64;
  const long obase = (long)b * 2048 * 1024 + h * 64;
  const __bf16* q    = qkv;
  const __bf16* kmat = qkv + 1024;
  const __bf16* v    = qkv + 2048;

  const int ks_row = (lane >> 3);
  const int ks_scol = (((lane & 7) ^ (lane >> 3)) * 8);
  const int vs_key = tid >> 2, vs_db = (tid & 3) * 16;

  bf16x8 aqL[2], aqH[2];
#pragma unroll
  for (int kk = 0; kk < 2; ++kk) {
    aqL[kk] = *(const bf16x8*)&q[base + (long)(qwL + lo) * 3072 + kk * 32 + 8 * hi];
    aqH[kk] = *(const bf16x8*)&q[base + (long)(qwH + lo) * 3072 + kk * 32 + 8 * hi];
  }

  const f32x4 fz = {0.f, 0.f, 0.f, 0.f};
  f32x4 oaccL[4], oaccH[4];
  float mrunL = -1e30f, lrunL = 0.f, mrunH = -1e30f, lrunH = 0.f;
#pragma unroll
  for (int ni = 0; ni < 4; ++ni) { oaccL[ni] = fz; oaccH[ni] = fz; }

  const int nkt = qtH + 1;   // = 32 - pi

  bf16x8 pv0, pv1;
  {
#pragma unroll
    for (int p = 0; p < 2; ++p) {
      const int seg = p * 4 + w;
      gload16(kmat + base + (long)(seg * 8 + ks_row) * 3072 + ks_scol,
              (char*)lsK[0] + seg * 1024);
    }
    const long gv = base + (long)vs_key * 3072 + vs_db;
    pv0 = *(const bf16x8*)&v[gv];
    pv1 = *(const bf16x8*)&v[gv + 8];
    char* lv = (char*)lsV[0];
#pragma unroll
    for (int j = 0; j < 8; ++j) {
      const int d0 = vs_db + j, d1 = vs_db + 8 + j;
      *(__bf16*)(lv + d0 * 128 + ((vs_key * 2) ^ ((d0 & 7) << 4) ^ (((d0 >> 4) & 3) << 5))) = pv0[j];
      *(__bf16*)(lv + d1 * 128 + ((vs_key * 2) ^ ((d1 & 7) << 4) ^ (((d1 >> 4) & 3) << 5))) = pv1[j];
    }
  }
  __syncthreads();

  auto process = [&](const bf16x8 (&aq)[2], f32x4 (&oacc)[4], float& mrun,
                     float& lrun, const int qw, const int kt, const int cur) {
    f32x4 sacc[4];
#pragma unroll
    for (int ni = 0; ni < 4; ++ni) sacc[ni] = fz;
#pragma unroll
    for (int kk = 0; kk < 2; ++kk) {
      bf16x8 bk[4];
#pragma unroll
      for (int ni = 0; ni < 4; ++ni) {
        const int row = ni * 16 + lo;
        bk[ni] = *(const bf16x8*)((char*)lsK[cur] + row * 128 +
                                  ((kk * 64 + 16 * hi) ^ ((row & 7) << 4)));
      }
#pragma unroll
      for (int ni = 0; ni < 4; ++ni)
        sacc[ni] = MFMA16(bk[ni], aq[kk], sacc[ni]);
    }

    const int rg = qw + lo;
#pragma unroll
    for (int ni = 0; ni < 4; ++ni)
#pragma unroll
      for (int r = 0; r < 4; ++r)
        if (kt * 64 + ni * 16 + hi * 4 + r > rg) sacc[ni][r] = -1e9f;

    float mx = -3.0e38f;
#pragma unroll
    for (int ni = 0; ni < 4; ++ni)
#pragma unroll
      for (int r = 0; r < 4; ++r) mx = fmaxf(mx, sacc[ni][r]);
    mx = fmaxf(mx, __shfl_xor(mx, 16));
    mx = fmaxf(mx, __shfl_xor(mx, 32));
    const float mold = mrun;
    const float mnew = fmaxf(mold, mx);
    const float fac = __expf(mold - mnew);

    float sum = 0.f;
    char* pbase = (char*)lsP[w] + lo * 128;
    const int swz = (lo & 7) << 4;
#pragma unroll
    for (int ni = 0; ni < 4; ++ni)
#pragma unroll
      for (int r = 0; r < 4; ++r) {
        const float pp = __expf(sacc[ni][r] - mnew);
        sum += pp;
        *(__bf16*)(pbase + ((32 * ni + 8 * hi + 2 * r) ^ swz)) = (__bf16)pp;
      }
    sum += __shfl_xor(sum, 16);
    sum += __shfl_xor(sum, 32);
    mrun = mnew;
    lrun = lrun * fac + sum;

    float facr[4];
#pragma unroll
    for (int r = 0; r < 4; ++r) facr[r] = __shfl(fac, hi * 4 + r);
#pragma unroll
    for (int ni = 0; ni < 4; ++ni)
#pragma unroll
      for (int r = 0; r < 4; ++r) oacc[ni][r] *= facr[r];

#pragma unroll
    for (int kk = 0; kk < 2; ++kk) {
      bf16x8 ap, bv[4];
      ap = *(const bf16x8*)(pbase + ((kk * 64 + 16 * hi) ^ swz));
#pragma unroll
      for (int ni = 0; ni < 4; ++ni) {
        const int d = ni * 16 + lo;
        bv[ni] = *(const bf16x8*)((char*)lsV[cur] + d * 128 +
                                  ((kk * 64 + 16 * hi) ^ ((d & 7) << 4) ^ (((d >> 4) & 3) << 5)));
      }
#pragma unroll
      for (int ni = 0; ni < 4; ++ni)
        oacc[ni] = MFMA16(ap, bv[ni], oacc[ni]);
    }
  };

  for (int kt = 0; kt < nkt; ++kt) {
    const int cur = kt & 1;
    const bool more = (kt + 1 < nkt);

    if (more) {
#pragma unroll
      for (int p = 0; p < 2; ++p) {
        const int seg = p * 4 + w;
        gload16(kmat + base + (long)((kt + 1) * 64 + seg * 8 + ks_row) * 3072 + ks_scol,
                (char*)lsK[cur ^ 1] + seg * 1024);
      }
      const long gv = base + (long)((kt + 1) * 64 + vs_key) * 3072 + vs_db;
      pv0 = *(const bf16x8*)&v[gv];
      pv1 = *(const bf16x8*)&v[gv + 8];
    }

    process(aqH, oaccH, mrunH, lrunH, qwH, kt, cur);
    if (kt <= qtL) process(aqL, oaccL, mrunL, lrunL, qwL, kt, cur);

    if (more) {
      char* lv = (char*)lsV[cur ^ 1];
#pragma unroll
      for (int j = 0; j < 8; ++j) {
        const int d0 = vs_db + j, d1 = vs_db + 8 + j;
        *(__bf16*)(lv + d0 * 128 + ((vs_key * 2) ^ ((d0 & 7) << 4) ^ (((d0 >> 4) & 3) << 5))) = pv0[j];
        *(__bf16*)(lv + d1 * 128 + ((vs_key * 2) ^ ((d1 & 7) << 4) ^ (((d1 >> 4) & 3) << 5))) = pv1[j];
      }
    }
    __syncthreads();
  }

  float lprH[4], lprL[4];
#pragma unroll
  for (int r = 0; r < 4; ++r) {
    lprH[r] = __shfl(lrunH, hi * 4 + r);
    lprL[r] = __shfl(lrunL, hi * 4 + r);
  }
#pragma unroll
  for (int ni = 0; ni < 4; ++ni)
#pragma unroll
    for (int r = 0; r < 4; ++r) {
      const int rowH = qwH + hi * 4 + r;
      const int rowL = qwL + hi * 4 + r;
      o[obase + (long)rowH * 1024 + ni * 16 + lo] = (__bf16)(oaccH[ni][r] / lprH[r]);
      o[obase + (long)rowL * 1024 + ni * 16 + lo] = (__bf16)(oaccL[ni][r] / lprL[r]);
    }
}

// ---------------------------------------------------------------- launcher
extern "C" void kernel_launch(void* const* d_in, const int* in_sizes, int n_in,
                              void* d_out, int out_size, void* d_ws, size_t ws_size,
                              hipStream_t stream) {
  const float* x    = (const float*)d_in[0];
  const float* fr   = (const float*)d_in[1];
  const float* ln1g = (const float*)d_in[3];
  const float* ln1b = (const float*)d_in[4];
  const float* Wq   = (const float*)d_in[5];
  const float* bq   = (const float*)d_in[6];
  const float* Wk   = (const float*)d_in[7];
  const float* bk   = (const float*)d_in[8];
  const float* Wv   = (const float*)d_in[9];
  const float* bv   = (const float*)d_in[10];
  const float* Wo   = (const float*)d_in[11];
  const float* bo   = (const float*)d_in[12];
  const float* ln2g = (const float*)d_in[13];
  const float* ln2b = (const float*)d_in[14];
  const float* W1   = (const float*)d_in[15];
  const float* b1   = (const float*)d_in[16];
  const float* W2   = (const float*)d_in[17];
  const float* b2   = (const float*)d_in[18];
  float* out = (float*)d_out;

  char* ws = (char*)d_ws;
  const size_t SZ = 8388608;  // 8 MB
  __bf16* xn   = (__bf16*)(ws + 0);              // 8 MB
  __bf16* qkv  = (__bf16*)(ws + 1 * SZ);         // 24 MB (8..32)
  __bf16* attn = (__bf16*)(ws + 0);              // reuse xn
  float*  bqkv = (float*)(ws + 4 * SZ);          // 12 KB, dead before x2 written
  float*  x2   = (float*)(ws + 4 * SZ);          // 16 MB f32 (32..48)
  __bf16* hin  = (__bf16*)(ws + 6 * SZ);         // 8 MB (48..56)
  __bf16* hmid = (__bf16*)(ws + 0);              // 32 MB (0..32), qkv/attn dead
  char* wb = ws + 7 * SZ;                        // bf16 weights, 24 MB (56..80), contiguous
  __bf16* Wqkvb = (__bf16*)(wb + 0);             // 6 MB: Wq|Wk|Wv packed along N
  __bf16* Wob   = (__bf16*)(wb + 6 * 1048576);
  __bf16* W1b   = (__bf16*)(wb + 8 * 1048576);
  __bf16* W2b   = (__bf16*)(wb + 16 * 1048576);

  const int M = 4096, D = 1024, FF = 4096;
  dim3 blk(256), blk5(512);

  cvt6_kernel<<<6144, blk, 0, stream>>>(Wq, Wk, Wv, Wo, W1, W2, Wqkvb);
  pack3_kernel<<<12, blk, 0, stream>>>(bq, bk, bv, bqkv);

  ln_kernel<<<4096, blk, 0, stream>>>(x, ln1g, ln1b, xn);
  gemm256<EPI_NONE, __bf16><<<dim3(3072 / 256, M / 256), blk5, 0, stream>>>(
      xn, Wqkvb, bqkv, qkv, M, 3072, D);
  rope_kernel<<<dim3(2048, 2), blk, 0, stream>>>(qkv, fr);
  attn_kernel<<<dim3(16, 16, 2), blk, 0, stream>>>(qkv, attn);
  gemm_bt<EPI_RES, float, 64><<<dim3(D / 64, M / 128), blk, 0, stream>>>(
      attn, Wob, bo, x, x2, M, D, D);
  ln_kernel<<<4096, blk, 0, stream>>>(x2, ln2g, ln2b, hin);
  gemm256<EPI_GELU, __bf16><<<dim3(FF / 256, M / 256), blk5, 0, stream>>>(
      hin, W1b, b1, hmid, M, FF, D);
  gemm_bt<EPI_RES, float, 64><<<dim3(D / 64, M / 128), blk, 0, stream>>>(
      hmid, W2b, b2, x2, out, M, D, FF);
}